// Round 1
// baseline (4291.645 us; speedup 1.0000x reference)
//
#include <hip/hip_runtime.h>
#include <math.h>

#define TOK_N   4096
#define DMODEL  1024
#define NEXP    8
#define DFFD    4096
#define CAPMAX  1024

__device__ __forceinline__ float wave_sum(float x){
  #pragma unroll
  for (int o=32;o;o>>=1) x += __shfl_down(x,o);
  return x;
}

// ---------------- LayerNorm: one block (256 thr) per row, D=1024 ----------------
__global__ __launch_bounds__(256) void ln_kernel(const float* __restrict__ in,
    const float* __restrict__ g, const float* __restrict__ b, float* __restrict__ out){
  int n = blockIdx.x, t = threadIdx.x;
  const float4* row = (const float4*)(in + (size_t)n*DMODEL);
  float4 v = row[t];
  float s  = v.x+v.y+v.z+v.w;
  float sq = v.x*v.x+v.y*v.y+v.z*v.z+v.w*v.w;
  s = wave_sum(s); sq = wave_sum(sq);
  __shared__ float r1[4], r2[4];
  __shared__ float mean_s, rstd_s;
  int lane = t & 63, wid = t >> 6;
  if (lane==0){ r1[wid]=s; r2[wid]=sq; }
  __syncthreads();
  if (t==0){
    float a = r1[0]+r1[1]+r1[2]+r1[3];
    float c = r2[0]+r2[1]+r2[2]+r2[3];
    float mean = a*(1.0f/DMODEL);
    float var  = c*(1.0f/DMODEL) - mean*mean;
    mean_s = mean; rstd_s = 1.0f/sqrtf(var + 1e-5f);
  }
  __syncthreads();
  float mean = mean_s, rstd = rstd_s;
  float4 g4 = ((const float4*)g)[t];
  float4 b4 = ((const float4*)b)[t];
  float4 o4;
  o4.x = (v.x-mean)*rstd*g4.x + b4.x;
  o4.y = (v.y-mean)*rstd*g4.y + b4.y;
  o4.z = (v.z-mean)*rstd*g4.z + b4.z;
  o4.w = (v.w-mean)*rstd*g4.w + b4.w;
  ((float4*)(out + (size_t)n*DMODEL))[t] = o4;
}

// ---------------- fp32 GEMM, 64x64 tile, BK=16, 4x4 microtile ----------------
// MODE 0: C = A@B                      (QKV)
// MODE 1: C = A@B + bias + resid      (proj)
// MODE 2: C = relu(gather(A)@B + bias) rows gathered via tok (expert up)
// MODE 3: C[tok[row]] += (A@B + bias) * gsel[row]   (expert down, scatter RMW)
template<int MODE>
__global__ __launch_bounds__(256) void gemm64(
    const float* __restrict__ A, const float* __restrict__ B,
    const float* __restrict__ bias, const float* __restrict__ resid,
    float* __restrict__ C, int M, int N, int K,
    const int* __restrict__ tok, const float* __restrict__ gsel)
{
  int m0 = blockIdx.y*64, n0 = blockIdx.x*64;
  if (MODE==2 || MODE==3) { if (tok[m0] >= TOK_N) return; }   // valid slots are a prefix
  __shared__ float As[16][68];
  __shared__ float Bs[16][68];
  int t = threadIdx.x;
  int tx = t & 15, ty = t >> 4;
  int arow = t >> 2, ak4 = (t & 3) * 4;     // A-load role: row, k-quad
  int bk = t >> 4,  bn4 = (t & 15) * 4;     // B-load role
  const float* Aptr;
  if (MODE==2) {
    int token = tok[m0 + arow];
    Aptr = (token < TOK_N) ? (A + (size_t)token*K + ak4) : nullptr;
  } else {
    Aptr = A + (size_t)(m0 + arow)*K + ak4;
  }
  const float* Bptr = B + (size_t)bk*N + n0 + bn4;
  float acc[4][4] = {};
  for (int kt = 0; kt < K; kt += 16) {
    float4 av = Aptr ? *(const float4*)(Aptr + kt) : make_float4(0.f,0.f,0.f,0.f);
    float4 bv = *(const float4*)(Bptr + (size_t)kt*N);
    __syncthreads();
    As[ak4+0][arow]=av.x; As[ak4+1][arow]=av.y; As[ak4+2][arow]=av.z; As[ak4+3][arow]=av.w;
    *(float4*)&Bs[bk][bn4] = bv;
    __syncthreads();
    #pragma unroll
    for (int kk=0;kk<16;kk++){
      const float4 a4 = *(const float4*)&As[kk][ty*4];
      const float4 b4 = *(const float4*)&Bs[kk][tx*4];
      acc[0][0] += a4.x*b4.x; acc[0][1] += a4.x*b4.y; acc[0][2] += a4.x*b4.z; acc[0][3] += a4.x*b4.w;
      acc[1][0] += a4.y*b4.x; acc[1][1] += a4.y*b4.y; acc[1][2] += a4.y*b4.z; acc[1][3] += a4.y*b4.w;
      acc[2][0] += a4.z*b4.x; acc[2][1] += a4.z*b4.y; acc[2][2] += a4.z*b4.z; acc[2][3] += a4.z*b4.w;
      acc[3][0] += a4.w*b4.x; acc[3][1] += a4.w*b4.y; acc[3][2] += a4.w*b4.z; acc[3][3] += a4.w*b4.w;
    }
  }
  int col = n0 + tx*4;
  if (MODE==0) {
    #pragma unroll
    for (int i=0;i<4;i++){
      float4 r; r.x=acc[i][0]; r.y=acc[i][1]; r.z=acc[i][2]; r.w=acc[i][3];
      *(float4*)&C[(size_t)(m0+ty*4+i)*N + col] = r;
    }
  } else if (MODE==1) {
    float4 bs = *(const float4*)&bias[col];
    #pragma unroll
    for (int i=0;i<4;i++){
      float4 rs = *(const float4*)&resid[(size_t)(m0+ty*4+i)*N + col];
      float4 r;
      r.x=acc[i][0]+bs.x+rs.x; r.y=acc[i][1]+bs.y+rs.y;
      r.z=acc[i][2]+bs.z+rs.z; r.w=acc[i][3]+bs.w+rs.w;
      *(float4*)&C[(size_t)(m0+ty*4+i)*N + col] = r;
    }
  } else if (MODE==2) {
    float4 bs = *(const float4*)&bias[col];
    #pragma unroll
    for (int i=0;i<4;i++){
      float4 r;
      r.x=fmaxf(acc[i][0]+bs.x,0.f); r.y=fmaxf(acc[i][1]+bs.y,0.f);
      r.z=fmaxf(acc[i][2]+bs.z,0.f); r.w=fmaxf(acc[i][3]+bs.w,0.f);
      *(float4*)&C[(size_t)(m0+ty*4+i)*N + col] = r;
    }
  } else {
    float4 bs = *(const float4*)&bias[col];
    #pragma unroll
    for (int i=0;i<4;i++){
      int row = m0+ty*4+i;
      int token = tok[row];
      if (token >= TOK_N) continue;
      float gv = gsel[row];
      float* op = C + (size_t)token*N + col;
      float4 o4 = *(float4*)op;
      o4.x += (acc[i][0]+bs.x)*gv; o4.y += (acc[i][1]+bs.y)*gv;
      o4.z += (acc[i][2]+bs.z)*gv; o4.w += (acc[i][3]+bs.w)*gv;
      *(float4*)op = o4;
    }
  }
}

// ---------------- causal flash attention, fp32, HS=64, 64 q-rows/block ----------------
__global__ __launch_bounds__(256) void attn_kernel(const float* __restrict__ q,
    const float* __restrict__ k, const float* __restrict__ v, float* __restrict__ o)
{
  __shared__ float Qs[64][64], Kt[64][64], Vs[64][64], Ps[64][64];
  int qt = blockIdx.x;            // q tile (T/64 = 16)
  int bh = blockIdx.y;            // batch*H + head (64)
  int batch = bh >> 4, head = bh & 15;
  int t = threadIdx.x, lane = t & 63, wid = t >> 6;
  size_t rowbase = (size_t)batch*1024;
  int col0 = head*64;
  for (int idx=t; idx<64*16; idx+=256){
    int r = idx>>4, c4 = (idx&15)*4;
    *(float4*)&Qs[r][c4] = *(const float4*)&q[(rowbase + qt*64 + r)*DMODEL + col0 + c4];
  }
  float m[16], l[16], acc[16], s[16];
  #pragma unroll
  for (int r=0;r<16;r++){ m[r]=-INFINITY; l[r]=0.f; acc[r]=0.f; }
  __syncthreads();
  const float scale = 0.03125f;   // D^-0.5 = 1/32
  for (int kt=0; kt<=qt; kt++){
    __syncthreads();
    for (int idx=t; idx<64*16; idx+=256){
      int r = idx>>4, c4 = (idx&15)*4;
      float4 k4 = *(const float4*)&k[(rowbase + kt*64 + r)*DMODEL + col0 + c4];
      Kt[c4+0][r]=k4.x; Kt[c4+1][r]=k4.y; Kt[c4+2][r]=k4.z; Kt[c4+3][r]=k4.w;
      *(float4*)&Vs[r][c4] = *(const float4*)&v[(rowbase + kt*64 + r)*DMODEL + col0 + c4];
    }
    __syncthreads();
    // phase 1: lane = kv index, s[r] = q_r . k_lane
    #pragma unroll
    for (int r=0;r<16;r++) s[r]=0.f;
    for (int d0=0; d0<64; d0+=4){
      float k0=Kt[d0][lane], k1=Kt[d0+1][lane], k2=Kt[d0+2][lane], k3=Kt[d0+3][lane];
      #pragma unroll
      for (int r=0;r<16;r++){
        const float4 q4 = *(const float4*)&Qs[wid*16+r][d0];
        s[r] += q4.x*k0 + q4.y*k1 + q4.z*k2 + q4.w*k3;
      }
    }
    int jg = kt*64 + lane;
    #pragma unroll
    for (int r=0;r<16;r++){
      int qg = qt*64 + wid*16 + r;
      float sv = s[r]*scale;
      if (jg > qg) sv = -INFINITY;
      float mt = sv;
      #pragma unroll
      for (int o_=32;o_;o_>>=1) mt = fmaxf(mt, __shfl_xor(mt,o_));
      float mn = fmaxf(m[r], mt);
      float p  = expf(sv - mn);
      float sc = expf(m[r] - mn);      // m=-inf first tile -> 0
      float ps = p;
      #pragma unroll
      for (int o_=32;o_;o_>>=1) ps += __shfl_xor(ps,o_);
      l[r] = l[r]*sc + ps;
      acc[r] *= sc;
      m[r] = mn;
      Ps[wid*16+r][lane] = p;
    }
    __syncthreads();
    // phase 2: lane = output dim
    for (int j0=0;j0<64;j0+=4){
      float v0=Vs[j0][lane], v1=Vs[j0+1][lane], v2=Vs[j0+2][lane], v3=Vs[j0+3][lane];
      #pragma unroll
      for (int r=0;r<16;r++){
        const float4 p4 = *(const float4*)&Ps[wid*16+r][j0];
        acc[r] += p4.x*v0 + p4.y*v1 + p4.z*v2 + p4.w*v3;
      }
    }
  }
  #pragma unroll
  for (int r=0;r<16;r++)
    o[(rowbase + qt*64 + wid*16 + r)*DMODEL + col0 + lane] = acc[r] / l[r];
}

// ---------------- router: one block per token ----------------
__global__ __launch_bounds__(256) void router_kernel(const float* __restrict__ h2,
    const float* __restrict__ wr, const float* __restrict__ br,
    const float* __restrict__ wn, const float* __restrict__ bn,
    const float* __restrict__ wsk, const float* __restrict__ bsk,
    const float* __restrict__ noise,
    int* __restrict__ idx2, float* __restrict__ gate2, int* __restrict__ nskv)
{
  int n = blockIdx.x, t = threadIdx.x;
  float4 hv = ((const float4*)(h2 + (size_t)n*DMODEL))[t];
  float hv_[4] = {hv.x,hv.y,hv.z,hv.w};
  int d0 = t*4;
  const float* wrp = wr + (size_t)d0*NEXP;
  const float* wnp = wn + (size_t)d0*NEXP;
  const float* wsp = wsk + d0;
  float vals[17];
  #pragma unroll
  for (int i=0;i<17;i++) vals[i]=0.f;
  #pragma unroll
  for (int i=0;i<4;i++){
    #pragma unroll
    for (int e=0;e<NEXP;e++){
      vals[e]   += hv_[i]*wrp[i*NEXP+e];
      vals[8+e] += hv_[i]*wnp[i*NEXP+e];
    }
    vals[16] += hv_[i]*wsp[i];
  }
  __shared__ float red[4][17];
  int lane = t & 63, wid = t >> 6;
  #pragma unroll
  for (int i=0;i<17;i++){
    float x = wave_sum(vals[i]);
    if (lane==0) red[wid][i] = x;
  }
  __syncthreads();
  if (t==0){
    float noisy[NEXP];
    #pragma unroll
    for (int e=0;e<NEXP;e++){
      float lr = red[0][e]+red[1][e]+red[2][e]+red[3][e] + br[e];
      float pn = red[0][8+e]+red[1][8+e]+red[2][8+e]+red[3][8+e] + bn[e];
      float sp = fmaxf(pn,0.f) + log1pf(expf(-fabsf(pn)));   // softplus
      noisy[e] = lr + noise[(size_t)n*NEXP + e]*sp;
    }
    float sk = red[0][16]+red[1][16]+red[2][16]+red[3][16] + bsk[0];
    nskv[n] = (sk <= 0.f) ? 1 : 0;                           // nsk = !(sigmoid>0.5)
    int i0=0; float v0=noisy[0];
    #pragma unroll
    for (int e=1;e<NEXP;e++) if (noisy[e] > v0){ v0=noisy[e]; i0=e; }
    int i1=-1; float v1=-INFINITY;
    #pragma unroll
    for (int e=0;e<NEXP;e++) if (e!=i0 && noisy[e] > v1){ v1=noisy[e]; i1=e; }
    float tt = expf(v1 - v0);
    float g0 = 1.0f/(1.0f+tt);
    float g1 = tt/(1.0f+tt);
    idx2[n*2+0]=i0; idx2[n*2+1]=i1;
    gate2[n*2+0]=g0; gate2[n*2+1]=g1;
  }
}

// ---------------- capacity scan + slot assignment: ONE block ----------------
__global__ __launch_bounds__(256) void scan_kernel(const int* __restrict__ idx2,
    const float* __restrict__ gate2, const int* __restrict__ nskv,
    int* __restrict__ tok, float* __restrict__ gsel)
{
  int t = threadIdx.x;
  for (int i=t; i<NEXP*CAPMAX; i+=256){ tok[i]=TOK_N; gsel[i]=0.f; }
  __shared__ int cnts[256][NEXP];
  __shared__ int nns_part[256];
  __shared__ int cap_s;
  int loc[NEXP]; 
  #pragma unroll
  for (int e=0;e<NEXP;e++) loc[e]=0;
  int nn=0, base = t*16;
  for (int u=0;u<16;u++){
    int n = base+u;
    if (nskv[n]){ nn++; loc[idx2[n*2]]++; loc[idx2[n*2+1]]++; }
  }
  #pragma unroll
  for (int e=0;e<NEXP;e++) cnts[t][e]=loc[e];
  nns_part[t]=nn;
  __syncthreads();
  if (t < NEXP){ int run=0; for (int i=0;i<256;i++){ int c=cnts[i][t]; cnts[i][t]=run; run+=c; } }
  if (t == NEXP){ int sum=0; for (int i=0;i<256;i++) sum+=nns_part[i]; cap_s = sum/4; } // n_ns*K/E
  __syncthreads();
  int capacity = cap_s;
  int run[NEXP];
  #pragma unroll
  for (int e=0;e<NEXP;e++) run[e]=cnts[t][e];
  for (int u=0;u<16;u++){
    int n = base+u;
    if (!nskv[n]) continue;
    #pragma unroll
    for (int kk=0;kk<2;kk++){
      int e = idx2[n*2+kk];
      int r = run[e]++;
      if (r < capacity){ tok[e*CAPMAX+r]=n; gsel[e*CAPMAX+r]=gate2[n*2+kk]; }
    }
  }
}

// ---------------- out = x1 + (nsk ? 0 : h2)  (experts scatter-add later) ----------------
__global__ __launch_bounds__(256) void out_init_kernel(const float* __restrict__ x1,
    const float* __restrict__ h2, const int* __restrict__ nskv, float* __restrict__ out)
{
  int n = blockIdx.x, t = threadIdx.x;
  float4 a = ((const float4*)(x1 + (size_t)n*DMODEL))[t];
  if (!nskv[n]){
    float4 b = ((const float4*)(h2 + (size_t)n*DMODEL))[t];
    a.x+=b.x; a.y+=b.y; a.z+=b.z; a.w+=b.w;
  }
  ((float4*)(out + (size_t)n*DMODEL))[t] = a;
}

extern "C" void kernel_launch(void* const* d_in, const int* in_sizes, int n_in,
                              void* d_out, int out_size, void* d_ws, size_t ws_size,
                              hipStream_t stream) {
  const float* x      = (const float*)d_in[0];
  const float* noise  = (const float*)d_in[1];
  const float* ln1_g  = (const float*)d_in[2];
  const float* ln1_b  = (const float*)d_in[3];
  const float* wq     = (const float*)d_in[4];
  const float* wk     = (const float*)d_in[5];
  const float* wv     = (const float*)d_in[6];
  const float* w_proj = (const float*)d_in[7];
  const float* b_proj = (const float*)d_in[8];
  const float* ln2_g  = (const float*)d_in[9];
  const float* ln2_b  = (const float*)d_in[10];
  const float* w_rout = (const float*)d_in[11];
  const float* b_rout = (const float*)d_in[12];
  const float* w_noi  = (const float*)d_in[13];
  const float* b_noi  = (const float*)d_in[14];
  const float* w_skip = (const float*)d_in[15];
  const float* b_skip = (const float*)d_in[16];
  const float* ew1    = (const float*)d_in[17];
  const float* eb1    = (const float*)d_in[18];
  const float* ew2    = (const float*)d_in[19];
  const float* eb2    = (const float*)d_in[20];
  float* out = (float*)d_out;

  float* ws = (float*)d_ws;
  const size_t NB = (size_t)TOK_N*DMODEL;       // 4,194,304 floats
  float* h   = ws + 0*NB;                       // h, then h2 (LN2 overwrites)
  float* qb  = ws + 1*NB;                       // q, later reused as mid (1024*4096)
  float* kb  = ws + 2*NB;
  float* vb  = ws + 3*NB;
  float* x1  = ws + 4*NB;
  int*   idx2  = (int*)(ws + 5*NB);
  float* gate2 = ws + 5*NB + 8192;
  int*   nskv  = (int*)(ws + 5*NB + 16384);
  int*   tokb  = (int*)(ws + 5*NB + 20480);
  float* gselb = ws + 5*NB + 28672;
  float* mid = qb;

  dim3 blk(256);
  // LN1
  ln_kernel<<<TOK_N, blk, 0, stream>>>(x, ln1_g, ln1_b, h);
  // QKV
  gemm64<0><<<dim3(16,64), blk, 0, stream>>>(h, wq, nullptr, nullptr, qb, TOK_N, DMODEL, DMODEL, nullptr, nullptr);
  gemm64<0><<<dim3(16,64), blk, 0, stream>>>(h, wk, nullptr, nullptr, kb, TOK_N, DMODEL, DMODEL, nullptr, nullptr);
  gemm64<0><<<dim3(16,64), blk, 0, stream>>>(h, wv, nullptr, nullptr, vb, TOK_N, DMODEL, DMODEL, nullptr, nullptr);
  // attention -> stage in d_out (dead after proj)
  attn_kernel<<<dim3(16,64), blk, 0, stream>>>(qb, kb, vb, out);
  // x1 = x + attn@w_proj + b_proj
  gemm64<1><<<dim3(16,64), blk, 0, stream>>>(out, w_proj, b_proj, x, x1, TOK_N, DMODEL, DMODEL, nullptr, nullptr);
  // LN2 -> h (h2)
  ln_kernel<<<TOK_N, blk, 0, stream>>>(x1, ln2_g, ln2_b, h);
  // router
  router_kernel<<<TOK_N, blk, 0, stream>>>(h, w_rout, b_rout, w_noi, b_noi, w_skip, b_skip,
                                           noise, idx2, gate2, nskv);
  // capacity scan + slot fill
  scan_kernel<<<1, blk, 0, stream>>>(idx2, gate2, nskv, tokb, gselb);
  // out = x1 + (nsk ? 0 : h2)
  out_init_kernel<<<TOK_N, blk, 0, stream>>>(x1, h, nskv, out);
  // experts (sequential launches -> scatter += is race-free, no atomics)
  for (int e=0; e<NEXP; e++){
    gemm64<2><<<dim3(64,16), blk, 0, stream>>>(h, ew1 + (size_t)e*DMODEL*DFFD, eb1 + (size_t)e*DFFD,
        nullptr, mid, CAPMAX, DFFD, DMODEL, tokb + e*CAPMAX, nullptr);
    gemm64<3><<<dim3(16,16), blk, 0, stream>>>(mid, ew2 + (size_t)e*DFFD*DMODEL, eb2 + (size_t)e*DMODEL,
        nullptr, out, CAPMAX, DMODEL, DFFD, tokb + e*CAPMAX, gselb + e*CAPMAX);
  }
}

// Round 2
// 2733.204 us; speedup vs baseline: 1.5702x; 1.5702x over previous
//
#include <hip/hip_runtime.h>
#include <math.h>

#define TOK_N   4096
#define DMODEL  1024
#define NEXP    8
#define DFFD    4096
#define CAPMAX  1024

typedef __bf16 bf16x8 __attribute__((ext_vector_type(8)));
typedef __bf16 bf16x4 __attribute__((ext_vector_type(4)));
typedef float  f32x4  __attribute__((ext_vector_type(4)));

__device__ __forceinline__ f32x4 MFMA16(bf16x8 a, bf16x8 b, f32x4 c){
  return __builtin_amdgcn_mfma_f32_16x16x32_bf16(a, b, c, 0, 0, 0);
}

__device__ __forceinline__ float wave_sum(float x){
  #pragma unroll
  for (int o=32;o;o>>=1) x += __shfl_down(x,o);
  return x;
}

// ---------------- LayerNorm ----------------
__global__ __launch_bounds__(256) void ln_kernel(const float* __restrict__ in,
    const float* __restrict__ g, const float* __restrict__ b, float* __restrict__ out){
  int n = blockIdx.x, t = threadIdx.x;
  const float4* row = (const float4*)(in + (size_t)n*DMODEL);
  float4 v = row[t];
  float s  = v.x+v.y+v.z+v.w;
  float sq = v.x*v.x+v.y*v.y+v.z*v.z+v.w*v.w;
  s = wave_sum(s); sq = wave_sum(sq);
  __shared__ float r1[4], r2[4];
  __shared__ float mean_s, rstd_s;
  int lane = t & 63, wid = t >> 6;
  if (lane==0){ r1[wid]=s; r2[wid]=sq; }
  __syncthreads();
  if (t==0){
    float a = r1[0]+r1[1]+r1[2]+r1[3];
    float c = r2[0]+r2[1]+r2[2]+r2[3];
    float mean = a*(1.0f/DMODEL);
    float var  = c*(1.0f/DMODEL) - mean*mean;
    mean_s = mean; rstd_s = 1.0f/sqrtf(var + 1e-5f);
  }
  __syncthreads();
  float mean = mean_s, rstd = rstd_s;
  float4 g4 = ((const float4*)g)[t];
  float4 b4 = ((const float4*)b)[t];
  float4 o4;
  o4.x = (v.x-mean)*rstd*g4.x + b4.x;
  o4.y = (v.y-mean)*rstd*g4.y + b4.y;
  o4.z = (v.z-mean)*rstd*g4.z + b4.z;
  o4.w = (v.w-mean)*rstd*g4.w + b4.w;
  ((float4*)(out + (size_t)n*DMODEL))[t] = o4;
}

// ---------------- MFMA GEMM, 128x128 tile, BK=32, bf16 (optionally split-bf16) ----------------
// MODE 0: C = A@B
// MODE 1: C = A@B + bias + resid
// MODE 2: C = relu(gather(A via tok)@B + bias)
// MODE 3: C[tok[row]] += (A@B + bias) * gsel[row]
// SPLIT: A,B decomposed hi+lo bf16; acc = Ah*Bh + Ah*Bl + Al*Bh  (~fp32 precision)
template<int MODE, bool SPLIT>
__global__ __launch_bounds__(256) void mgemm(
    const float* __restrict__ A, const float* __restrict__ B,
    const float* __restrict__ bias, const float* __restrict__ resid,
    float* __restrict__ C, int M, int N, int K,
    const int* __restrict__ tok, const float* __restrict__ gsel)
{
  int m0 = blockIdx.y*128, n0 = blockIdx.x*128;
  if ((MODE==2 || MODE==3) && tok[m0] >= TOK_N) return;   // valid slots are a prefix
  __shared__ __bf16 As[128][40];                 // [row][k], pad 40 (80B rows)
  __shared__ __bf16 Bs[128][40];                 // [col][k]
  __shared__ __bf16 Al[SPLIT?128:1][40];
  __shared__ __bf16 Bl[SPLIT?128:1][40];
  int t = threadIdx.x;
  int lane = t & 63, wid = t >> 6;
  int wr = wid >> 1, wc = wid & 1;
  int fr = lane & 15, kb = lane >> 4;
  // A staging role: thread -> (row, k-half)
  int arow = t >> 1, aseg = t & 1;
  const float* Ap = nullptr;
  if (MODE==2){
    int token = tok[m0 + arow];
    if (token < TOK_N) Ap = A + (size_t)token*K;
  } else {
    Ap = A + (size_t)(m0 + arow)*K;
  }
  // B staging role: thread -> (n-quad, k-quad)
  int bnq = t & 31, bkq = t >> 5;
  f32x4 acc[4][4];
  #pragma unroll
  for (int mt=0;mt<4;mt++)
    #pragma unroll
    for (int nt=0;nt<4;nt++) acc[mt][nt] = (f32x4){0.f,0.f,0.f,0.f};

  for (int kt=0; kt<K; kt+=32){
    // ---- global loads (fp32) ----
    float a_f[16];
    #pragma unroll
    for (int i=0;i<16;i++) a_f[i]=0.f;
    if (Ap){
      const float* base = Ap + kt + aseg*16;
      #pragma unroll
      for (int q=0;q<4;q++){
        float4 f = *(const float4*)(base + q*4);
        a_f[q*4+0]=f.x; a_f[q*4+1]=f.y; a_f[q*4+2]=f.z; a_f[q*4+3]=f.w;
      }
    }
    float b_f[4][4];
    #pragma unroll
    for (int dk=0; dk<4; dk++){
      float4 f = *(const float4*)&B[(size_t)(kt + bkq*4 + dk)*N + n0 + bnq*4];
      b_f[dk][0]=f.x; b_f[dk][1]=f.y; b_f[dk][2]=f.z; b_f[dk][3]=f.w;
    }
    __syncthreads();   // previous compute done before overwriting LDS
    // ---- convert + LDS write ----
    #pragma unroll
    for (int hf=0; hf<2; hf++){
      bf16x8 hv, lv;
      #pragma unroll
      for (int i=0;i<8;i++){
        float xv = a_f[hf*8+i];
        __bf16 hb = (__bf16)xv;
        hv[i] = hb;
        if constexpr (SPLIT) lv[i] = (__bf16)(xv - (float)hb);
      }
      *(bf16x8*)&As[arow][aseg*16 + hf*8] = hv;
      if constexpr (SPLIT) *(bf16x8*)&Al[arow][aseg*16 + hf*8] = lv;
    }
    #pragma unroll
    for (int dn=0; dn<4; dn++){
      bf16x4 wv, lv;
      #pragma unroll
      for (int dk=0; dk<4; dk++){
        float xv = b_f[dk][dn];
        __bf16 hb = (__bf16)xv;
        wv[dk] = hb;
        if constexpr (SPLIT) lv[dk] = (__bf16)(xv - (float)hb);
      }
      *(bf16x4*)&Bs[bnq*4+dn][bkq*4] = wv;
      if constexpr (SPLIT) *(bf16x4*)&Bl[bnq*4+dn][bkq*4] = lv;
    }
    __syncthreads();
    // ---- fragments + MFMA ----
    bf16x8 aF[4], bF[4];
    #pragma unroll
    for (int mt=0;mt<4;mt++) aF[mt] = *(const bf16x8*)&As[wr*64+mt*16+fr][kb*8];
    #pragma unroll
    for (int nt=0;nt<4;nt++) bF[nt] = *(const bf16x8*)&Bs[wc*64+nt*16+fr][kb*8];
    #pragma unroll
    for (int mt=0;mt<4;mt++)
      #pragma unroll
      for (int nt=0;nt<4;nt++)
        acc[mt][nt] = MFMA16(aF[mt], bF[nt], acc[mt][nt]);
    if constexpr (SPLIT){
      bf16x8 aL[4], bL[4];
      #pragma unroll
      for (int mt=0;mt<4;mt++) aL[mt] = *(const bf16x8*)&Al[wr*64+mt*16+fr][kb*8];
      #pragma unroll
      for (int nt=0;nt<4;nt++) bL[nt] = *(const bf16x8*)&Bl[wc*64+nt*16+fr][kb*8];
      #pragma unroll
      for (int mt=0;mt<4;mt++)
        #pragma unroll
        for (int nt=0;nt<4;nt++){
          acc[mt][nt] = MFMA16(aF[mt], bL[nt], acc[mt][nt]);
          acc[mt][nt] = MFMA16(aL[mt], bF[nt], acc[mt][nt]);
        }
    }
  }
  // ---- epilogue ----
  #pragma unroll
  for (int mt=0; mt<4; mt++){
    int r0 = m0 + wr*64 + mt*16 + (lane>>4)*4;
    int tk4[4]; float g4[4];
    if constexpr (MODE==3){
      #pragma unroll
      for (int j=0;j<4;j++){ tk4[j]=tok[r0+j]; g4[j]=gsel[r0+j]; }
    }
    #pragma unroll
    for (int nt=0; nt<4; nt++){
      int col = n0 + wc*64 + nt*16 + fr;
      f32x4 v = acc[mt][nt];
      if constexpr (MODE==0){
        #pragma unroll
        for (int j=0;j<4;j++) C[(size_t)(r0+j)*N + col] = v[j];
      } else if constexpr (MODE==1){
        float bs = bias[col];
        #pragma unroll
        for (int j=0;j<4;j++){
          size_t idx = (size_t)(r0+j)*N + col;
          C[idx] = v[j] + bs + resid[idx];
        }
      } else if constexpr (MODE==2){
        float bs = bias[col];
        #pragma unroll
        for (int j=0;j<4;j++) C[(size_t)(r0+j)*N + col] = fmaxf(v[j] + bs, 0.f);
      } else {
        float bs = bias[col];
        #pragma unroll
        for (int j=0;j<4;j++){
          if (tk4[j] < TOK_N){
            C[(size_t)tk4[j]*N + col] += (v[j] + bs) * g4[j];
          }
        }
      }
    }
  }
}

// ---------------- causal flash attention, fp32, HS=64, 64 q-rows/block ----------------
__global__ __launch_bounds__(256) void attn_kernel(const float* __restrict__ q,
    const float* __restrict__ k, const float* __restrict__ v, float* __restrict__ o)
{
  __shared__ float Qs[64][68], Kt[64][68], Vs[64][68], Ps[64][68];  // pad 68: kills bank conflicts
  int qt = blockIdx.x;
  int bh = blockIdx.y;
  int batch = bh >> 4, head = bh & 15;
  int t = threadIdx.x, lane = t & 63, wid = t >> 6;
  size_t rowbase = (size_t)batch*1024;
  int col0 = head*64;
  for (int idx=t; idx<64*16; idx+=256){
    int r = idx>>4, c4 = (idx&15)*4;
    *(float4*)&Qs[r][c4] = *(const float4*)&q[(rowbase + qt*64 + r)*DMODEL + col0 + c4];
  }
  float m[16], l[16], acc[16], s[16];
  #pragma unroll
  for (int r=0;r<16;r++){ m[r]=-INFINITY; l[r]=0.f; acc[r]=0.f; }
  __syncthreads();
  const float scale = 0.03125f;   // D^-0.5 = 1/32
  for (int kt=0; kt<=qt; kt++){
    __syncthreads();
    for (int idx=t; idx<64*16; idx+=256){
      int r = idx>>4, c4 = (idx&15)*4;
      float4 k4 = *(const float4*)&k[(rowbase + kt*64 + r)*DMODEL + col0 + c4];
      Kt[c4+0][r]=k4.x; Kt[c4+1][r]=k4.y; Kt[c4+2][r]=k4.z; Kt[c4+3][r]=k4.w;
      *(float4*)&Vs[r][c4] = *(const float4*)&v[(rowbase + kt*64 + r)*DMODEL + col0 + c4];
    }
    __syncthreads();
    #pragma unroll
    for (int r=0;r<16;r++) s[r]=0.f;
    for (int d0=0; d0<64; d0+=4){
      float k0=Kt[d0][lane], k1=Kt[d0+1][lane], k2=Kt[d0+2][lane], k3=Kt[d0+3][lane];
      #pragma unroll
      for (int r=0;r<16;r++){
        const float4 q4 = *(const float4*)&Qs[wid*16+r][d0];
        s[r] += q4.x*k0 + q4.y*k1 + q4.z*k2 + q4.w*k3;
      }
    }
    int jg = kt*64 + lane;
    #pragma unroll
    for (int r=0;r<16;r++){
      int qg = qt*64 + wid*16 + r;
      float sv = s[r]*scale;
      if (jg > qg) sv = -INFINITY;
      float mt = sv;
      #pragma unroll
      for (int o_=32;o_;o_>>=1) mt = fmaxf(mt, __shfl_xor(mt,o_));
      float mn = fmaxf(m[r], mt);
      float p  = expf(sv - mn);
      float sc = expf(m[r] - mn);
      float ps = p;
      #pragma unroll
      for (int o_=32;o_;o_>>=1) ps += __shfl_xor(ps,o_);
      l[r] = l[r]*sc + ps;
      acc[r] *= sc;
      m[r] = mn;
      Ps[wid*16+r][lane] = p;
    }
    __syncthreads();
    for (int j0=0;j0<64;j0+=4){
      float v0=Vs[j0][lane], v1=Vs[j0+1][lane], v2=Vs[j0+2][lane], v3=Vs[j0+3][lane];
      #pragma unroll
      for (int r=0;r<16;r++){
        const float4 p4 = *(const float4*)&Ps[wid*16+r][j0];
        acc[r] += p4.x*v0 + p4.y*v1 + p4.z*v2 + p4.w*v3;
      }
    }
  }
  #pragma unroll
  for (int r=0;r<16;r++)
    o[(rowbase + qt*64 + wid*16 + r)*DMODEL + col0 + lane] = acc[r] / l[r];
}

// ---------------- router ----------------
__global__ __launch_bounds__(256) void router_kernel(const float* __restrict__ h2,
    const float* __restrict__ wr, const float* __restrict__ br,
    const float* __restrict__ wn, const float* __restrict__ bn,
    const float* __restrict__ wsk, const float* __restrict__ bsk,
    const float* __restrict__ noise,
    int* __restrict__ idx2, float* __restrict__ gate2, int* __restrict__ nskv)
{
  int n = blockIdx.x, t = threadIdx.x;
  float4 hv = ((const float4*)(h2 + (size_t)n*DMODEL))[t];
  float hv_[4] = {hv.x,hv.y,hv.z,hv.w};
  int d0 = t*4;
  const float* wrp = wr + (size_t)d0*NEXP;
  const float* wnp = wn + (size_t)d0*NEXP;
  const float* wsp = wsk + d0;
  float vals[17];
  #pragma unroll
  for (int i=0;i<17;i++) vals[i]=0.f;
  #pragma unroll
  for (int i=0;i<4;i++){
    #pragma unroll
    for (int e=0;e<NEXP;e++){
      vals[e]   += hv_[i]*wrp[i*NEXP+e];
      vals[8+e] += hv_[i]*wnp[i*NEXP+e];
    }
    vals[16] += hv_[i]*wsp[i];
  }
  __shared__ float red[4][17];
  int lane = t & 63, wid = t >> 6;
  #pragma unroll
  for (int i=0;i<17;i++){
    float x = wave_sum(vals[i]);
    if (lane==0) red[wid][i] = x;
  }
  __syncthreads();
  if (t==0){
    float noisy[NEXP];
    #pragma unroll
    for (int e=0;e<NEXP;e++){
      float lr = red[0][e]+red[1][e]+red[2][e]+red[3][e] + br[e];
      float pn = red[0][8+e]+red[1][8+e]+red[2][8+e]+red[3][8+e] + bn[e];
      float sp = fmaxf(pn,0.f) + log1pf(expf(-fabsf(pn)));
      noisy[e] = lr + noise[(size_t)n*NEXP + e]*sp;
    }
    float sk = red[0][16]+red[1][16]+red[2][16]+red[3][16] + bsk[0];
    nskv[n] = (sk <= 0.f) ? 1 : 0;
    int i0=0; float v0=noisy[0];
    #pragma unroll
    for (int e=1;e<NEXP;e++) if (noisy[e] > v0){ v0=noisy[e]; i0=e; }
    int i1=-1; float v1=-INFINITY;
    #pragma unroll
    for (int e=0;e<NEXP;e++) if (e!=i0 && noisy[e] > v1){ v1=noisy[e]; i1=e; }
    float tt = expf(v1 - v0);
    float g0 = 1.0f/(1.0f+tt);
    float g1 = tt/(1.0f+tt);
    idx2[n*2+0]=i0; idx2[n*2+1]=i1;
    gate2[n*2+0]=g0; gate2[n*2+1]=g1;
  }
}

// ---------------- capacity scan + slot assignment ----------------
__global__ __launch_bounds__(256) void scan_kernel(const int* __restrict__ idx2,
    const float* __restrict__ gate2, const int* __restrict__ nskv,
    int* __restrict__ tok, float* __restrict__ gsel)
{
  int t = threadIdx.x;
  for (int i=t; i<NEXP*CAPMAX; i+=256){ tok[i]=TOK_N; gsel[i]=0.f; }
  __shared__ int cnts[256][NEXP];
  __shared__ int nns_part[256];
  __shared__ int cap_s;
  int loc[NEXP];
  #pragma unroll
  for (int e=0;e<NEXP;e++) loc[e]=0;
  int nn=0, base = t*16;
  for (int u=0;u<16;u++){
    int n = base+u;
    if (nskv[n]){ nn++; loc[idx2[n*2]]++; loc[idx2[n*2+1]]++; }
  }
  #pragma unroll
  for (int e=0;e<NEXP;e++) cnts[t][e]=loc[e];
  nns_part[t]=nn;
  __syncthreads();
  if (t < NEXP){ int run=0; for (int i=0;i<256;i++){ int c=cnts[i][t]; cnts[i][t]=run; run+=c; } }
  if (t == NEXP){ int sum=0; for (int i=0;i<256;i++) sum+=nns_part[i]; cap_s = sum/4; }
  __syncthreads();
  int capacity = cap_s;
  int run[NEXP];
  #pragma unroll
  for (int e=0;e<NEXP;e++) run[e]=cnts[t][e];
  for (int u=0;u<16;u++){
    int n = base+u;
    if (!nskv[n]) continue;
    #pragma unroll
    for (int kk=0;kk<2;kk++){
      int e = idx2[n*2+kk];
      int r = run[e]++;
      if (r < capacity){ tok[e*CAPMAX+r]=n; gsel[e*CAPMAX+r]=gate2[n*2+kk]; }
    }
  }
}

// ---------------- out = x1 + (nsk ? 0 : h2) ----------------
__global__ __launch_bounds__(256) void out_init_kernel(const float* __restrict__ x1,
    const float* __restrict__ h2, const int* __restrict__ nskv, float* __restrict__ out)
{
  int n = blockIdx.x, t = threadIdx.x;
  float4 a = ((const float4*)(x1 + (size_t)n*DMODEL))[t];
  if (!nskv[n]){
    float4 b = ((const float4*)(h2 + (size_t)n*DMODEL))[t];
    a.x+=b.x; a.y+=b.y; a.z+=b.z; a.w+=b.w;
  }
  ((float4*)(out + (size_t)n*DMODEL))[t] = a;
}

extern "C" void kernel_launch(void* const* d_in, const int* in_sizes, int n_in,
                              void* d_out, int out_size, void* d_ws, size_t ws_size,
                              hipStream_t stream) {
  const float* x      = (const float*)d_in[0];
  const float* noise  = (const float*)d_in[1];
  const float* ln1_g  = (const float*)d_in[2];
  const float* ln1_b  = (const float*)d_in[3];
  const float* wq     = (const float*)d_in[4];
  const float* wk     = (const float*)d_in[5];
  const float* wv     = (const float*)d_in[6];
  const float* w_proj = (const float*)d_in[7];
  const float* b_proj = (const float*)d_in[8];
  const float* ln2_g  = (const float*)d_in[9];
  const float* ln2_b  = (const float*)d_in[10];
  const float* w_rout = (const float*)d_in[11];
  const float* b_rout = (const float*)d_in[12];
  const float* w_noi  = (const float*)d_in[13];
  const float* b_noi  = (const float*)d_in[14];
  const float* w_skip = (const float*)d_in[15];
  const float* b_skip = (const float*)d_in[16];
  const float* ew1    = (const float*)d_in[17];
  const float* eb1    = (const float*)d_in[18];
  const float* ew2    = (const float*)d_in[19];
  const float* eb2    = (const float*)d_in[20];
  float* out = (float*)d_out;

  float* ws = (float*)d_ws;
  const size_t NB = (size_t)TOK_N*DMODEL;
  float* h   = ws + 0*NB;
  float* qb  = ws + 1*NB;      // q, later reused as mid
  float* kb  = ws + 2*NB;
  float* vb  = ws + 3*NB;
  float* x1  = ws + 4*NB;
  int*   idx2  = (int*)(ws + 5*NB);
  float* gate2 = ws + 5*NB + 8192;
  int*   nskv  = (int*)(ws + 5*NB + 16384);
  int*   tokb  = (int*)(ws + 5*NB + 20480);
  float* gselb = ws + 5*NB + 28672;
  float* mid = qb;

  dim3 blk(256);
  ln_kernel<<<TOK_N, blk, 0, stream>>>(x, ln1_g, ln1_b, h);
  // QKV: split-bf16 MFMA (fp32-accurate — protects downstream router decisions)
  mgemm<0,true><<<dim3(8,32), blk, 0, stream>>>(h, wq, nullptr, nullptr, qb, TOK_N, DMODEL, DMODEL, nullptr, nullptr);
  mgemm<0,true><<<dim3(8,32), blk, 0, stream>>>(h, wk, nullptr, nullptr, kb, TOK_N, DMODEL, DMODEL, nullptr, nullptr);
  mgemm<0,true><<<dim3(8,32), blk, 0, stream>>>(h, wv, nullptr, nullptr, vb, TOK_N, DMODEL, DMODEL, nullptr, nullptr);
  attn_kernel<<<dim3(16,64), blk, 0, stream>>>(qb, kb, vb, out);
  mgemm<1,true><<<dim3(8,32), blk, 0, stream>>>(out, w_proj, b_proj, x, x1, TOK_N, DMODEL, DMODEL, nullptr, nullptr);
  ln_kernel<<<TOK_N, blk, 0, stream>>>(x1, ln2_g, ln2_b, h);
  router_kernel<<<TOK_N, blk, 0, stream>>>(h, w_rout, b_rout, w_noi, b_noi, w_skip, b_skip,
                                           noise, idx2, gate2, nskv);
  scan_kernel<<<1, blk, 0, stream>>>(idx2, gate2, nskv, tokb, gselb);
  out_init_kernel<<<TOK_N, blk, 0, stream>>>(x1, h, nskv, out);
  // experts: plain bf16 MFMA (post-decision, continuous error only)
  for (int e=0; e<NEXP; e++){
    mgemm<2,false><<<dim3(32,8), blk, 0, stream>>>(h, ew1 + (size_t)e*DMODEL*DFFD, eb1 + (size_t)e*DFFD,
        nullptr, mid, CAPMAX, DFFD, DMODEL, tokb + e*CAPMAX, nullptr);
    mgemm<3,false><<<dim3(8,8), blk, 0, stream>>>(mid, ew2 + (size_t)e*DFFD*DMODEL, eb2 + (size_t)e*DMODEL,
        nullptr, out, CAPMAX, DMODEL, DFFD, tokb + e*CAPMAX, gselb + e*CAPMAX);
  }
}

// Round 3
// 2016.756 us; speedup vs baseline: 2.1280x; 1.3552x over previous
//
#include <hip/hip_runtime.h>
#include <math.h>

#define TOK_N   4096
#define DMODEL  1024
#define NEXP    8
#define DFFD    4096
#define CAPMAX  1024

typedef __bf16 bf16x8 __attribute__((ext_vector_type(8)));
typedef __bf16 bf16x4 __attribute__((ext_vector_type(4)));
typedef float  f32x4  __attribute__((ext_vector_type(4)));

__device__ __forceinline__ f32x4 MFMA16(bf16x8 a, bf16x8 b, f32x4 c){
  return __builtin_amdgcn_mfma_f32_16x16x32_bf16(a, b, c, 0, 0, 0);
}

// async global->LDS, 16B per lane; lds ptr must be wave-uniform base (HW adds lane*16)
__device__ __forceinline__ void gl16(const __bf16* g, __bf16* l){
  __builtin_amdgcn_global_load_lds(
      (const __attribute__((address_space(1))) unsigned int*)g,
      (__attribute__((address_space(3))) unsigned int*)l, 16, 0, 0);
}

__device__ __forceinline__ float wave_sum(float x){
  #pragma unroll
  for (int o=32;o;o>>=1) x += __shfl_down(x,o);
  return x;
}

// ---------------- LayerNorm -> hi/lo bf16 ----------------
__global__ __launch_bounds__(256) void ln_split_kernel(const float* __restrict__ in,
    const float* __restrict__ g, const float* __restrict__ b,
    __bf16* __restrict__ oh, __bf16* __restrict__ ol){
  int n = blockIdx.x, t = threadIdx.x;
  const float4* row = (const float4*)(in + (size_t)n*DMODEL);
  float4 v = row[t];
  float s  = v.x+v.y+v.z+v.w;
  float sq = v.x*v.x+v.y*v.y+v.z*v.z+v.w*v.w;
  s = wave_sum(s); sq = wave_sum(sq);
  __shared__ float r1[4], r2[4];
  __shared__ float mean_s, rstd_s;
  int lane = t & 63, wid = t >> 6;
  if (lane==0){ r1[wid]=s; r2[wid]=sq; }
  __syncthreads();
  if (t==0){
    float a = r1[0]+r1[1]+r1[2]+r1[3];
    float c = r2[0]+r2[1]+r2[2]+r2[3];
    float mean = a*(1.0f/DMODEL);
    float var  = c*(1.0f/DMODEL) - mean*mean;
    mean_s = mean; rstd_s = 1.0f/sqrtf(var + 1e-5f);
  }
  __syncthreads();
  float mean = mean_s, rstd = rstd_s;
  float4 g4 = ((const float4*)g)[t];
  float4 b4 = ((const float4*)b)[t];
  float o_[4];
  o_[0] = (v.x-mean)*rstd*g4.x + b4.x;
  o_[1] = (v.y-mean)*rstd*g4.y + b4.y;
  o_[2] = (v.z-mean)*rstd*g4.z + b4.z;
  o_[3] = (v.w-mean)*rstd*g4.w + b4.w;
  bf16x4 h4, l4;
  #pragma unroll
  for (int i=0;i<4;i++){ __bf16 hb=(__bf16)o_[i]; h4[i]=hb; l4[i]=(__bf16)(o_[i]-(float)hb); }
  *(bf16x4*)&oh[(size_t)n*DMODEL + t*4] = h4;
  *(bf16x4*)&ol[(size_t)n*DMODEL + t*4] = l4;
}

// ---------------- transpose-convert: in[K][N] f32 -> oh/ol [N][K] bf16 ----------------
template<bool SPLIT>
__global__ __launch_bounds__(256) void tconv_kernel(const float* __restrict__ in,
    __bf16* __restrict__ oh, __bf16* __restrict__ ol, int K, int N){
  __shared__ float tile[64][65];
  int k0 = blockIdx.x*64, n0 = blockIdx.y*64;
  int t = threadIdx.x;
  #pragma unroll
  for (int i=0;i<4;i++){
    int row = (t>>4) + i*16;
    int col = (t&15)*4;
    float4 f = *(const float4*)&in[(size_t)(k0+row)*N + n0 + col];
    tile[row][col]=f.x; tile[row][col+1]=f.y; tile[row][col+2]=f.z; tile[row][col+3]=f.w;
  }
  __syncthreads();
  #pragma unroll
  for (int i=0;i<2;i++){
    int c = t + i*256;           // 0..511
    int orow = c>>3, kg = (c&7)*8;
    bf16x8 hv, lv;
    #pragma unroll
    for (int u=0;u<8;u++){
      float x = tile[kg+u][orow];
      __bf16 hb = (__bf16)x;
      hv[u]=hb;
      if constexpr (SPLIT) lv[u]=(__bf16)(x-(float)hb);
    }
    *(bf16x8*)&oh[(size_t)(n0+orow)*K + k0 + kg] = hv;
    if constexpr (SPLIT) *(bf16x8*)&ol[(size_t)(n0+orow)*K + k0 + kg] = lv;
  }
}

// ---------------- MFMA GEMM, 128x128, BK=32, global_load_lds staging ----------------
// A: [M][K] bf16 (hi/lo), B: [N][K] bf16 (hi/lo, pre-transposed)
// MODE 0: QKV   -> Ch/Cl hi/lo bf16
// MODE 1: PROJ  -> Cf = acc + bias + resid (f32)
// MODE 2: UP    -> Ch = bf16(relu(acc+bias)), A rows gathered via tok (invalid -> zbuf)
// MODE 3: DN    -> Cf[tok[row]] += (acc+bias)*gsel[row]
template<int MODE, bool SPLIT>
__global__ __launch_bounds__(256) void mgemm(
    const __bf16* __restrict__ Ah, const __bf16* __restrict__ Al,
    const __bf16* __restrict__ Bh, const __bf16* __restrict__ Bl,
    const float* __restrict__ bias, const float* __restrict__ resid,
    float* __restrict__ Cf, __bf16* __restrict__ Ch, __bf16* __restrict__ Cl,
    int N, int K,
    const int* __restrict__ tok, const float* __restrict__ gsel,
    const __bf16* __restrict__ zbuf)
{
  int m0 = blockIdx.y*128, n0 = blockIdx.x*128;
  if ((MODE==2||MODE==3) && tok[m0] >= TOK_N) return;   // valid slots are a prefix
  __shared__ __bf16 sAh[128*32], sBh[128*32];
  __shared__ __bf16 sAl[SPLIT?128*32:8], sBl[SPLIT?128*32:8];
  int t = threadIdx.x, lane = t&63, w = t>>6;
  int wr = w>>1, wc = w&1, fr = lane&15, kb = lane>>4;

  // staging roles: instr j covers chunks [j*256 + w*64 + lane]; chunk=16B; row=c>>2, grp=c&3
  const __bf16* aB[2]; const __bf16* aBl[2]; bool aval[2];
  const __bf16* bB[2]; const __bf16* bBl[2];
  #pragma unroll
  for (int j=0;j<2;j++){
    int c = j*256 + w*64 + lane;
    int row = c>>2, grp = c&3;
    if (MODE==2){
      int token = tok[m0+row];
      if (token < TOK_N){ aB[j] = Ah + (size_t)token*K + grp*8; aval[j]=true; }
      else              { aB[j] = zbuf + grp*8;                 aval[j]=false; }
    } else {
      aB[j] = Ah + (size_t)(m0+row)*K + grp*8; aval[j]=true;
      if (SPLIT) aBl[j] = Al + (size_t)(m0+row)*K + grp*8;
    }
    bB[j] = Bh + (size_t)(n0+row)*K + grp*8;
    if (SPLIT) bBl[j] = Bl + (size_t)(n0+row)*K + grp*8;
  }

  f32x4 acc[4][4];
  #pragma unroll
  for (int mt=0;mt<4;mt++)
    #pragma unroll
    for (int nt=0;nt<4;nt++) acc[mt][nt] = (f32x4){0.f,0.f,0.f,0.f};

  for (int kt=0; kt<K; kt+=32){
    __syncthreads();                       // previous frag reads done
    #pragma unroll
    for (int j=0;j<2;j++){
      int cb8 = (j*256 + w*64)*8;          // LDS element offset (wave-uniform)
      gl16(aval[j] ? aB[j]+kt : aB[j], &sAh[cb8]);
      gl16(bB[j]+kt, &sBh[cb8]);
      if constexpr (SPLIT){
        gl16(aBl[j]+kt, &sAl[cb8]);
        gl16(bBl[j]+kt, &sBl[cb8]);
      }
    }
    __syncthreads();                       // drains vmcnt -> tiles visible
    bf16x8 aFh[4], bFh[4];
    #pragma unroll
    for (int mt=0;mt<4;mt++) aFh[mt] = *(const bf16x8*)&sAh[(wr*64+mt*16+fr)*32 + kb*8];
    #pragma unroll
    for (int nt=0;nt<4;nt++) bFh[nt] = *(const bf16x8*)&sBh[(wc*64+nt*16+fr)*32 + kb*8];
    #pragma unroll
    for (int mt=0;mt<4;mt++)
      #pragma unroll
      for (int nt=0;nt<4;nt++)
        acc[mt][nt] = MFMA16(aFh[mt], bFh[nt], acc[mt][nt]);
    if constexpr (SPLIT){
      bf16x8 aFl[4], bFl[4];
      #pragma unroll
      for (int mt=0;mt<4;mt++) aFl[mt] = *(const bf16x8*)&sAl[(wr*64+mt*16+fr)*32 + kb*8];
      #pragma unroll
      for (int nt=0;nt<4;nt++) bFl[nt] = *(const bf16x8*)&sBl[(wc*64+nt*16+fr)*32 + kb*8];
      #pragma unroll
      for (int mt=0;mt<4;mt++)
        #pragma unroll
        for (int nt=0;nt<4;nt++){
          acc[mt][nt] = MFMA16(aFh[mt], bFl[nt], acc[mt][nt]);
          acc[mt][nt] = MFMA16(aFl[mt], bFh[nt], acc[mt][nt]);
        }
    }
  }
  // epilogue (C/D: col=lane&15, row=(lane>>4)*4+j — verified layout from round 2)
  #pragma unroll
  for (int mt=0; mt<4; mt++){
    int r0 = m0 + wr*64 + mt*16 + (lane>>4)*4;
    int tk4[4]; float g4[4];
    if constexpr (MODE==3){
      #pragma unroll
      for (int jj=0;jj<4;jj++){ tk4[jj]=tok[r0+jj]; g4[jj]=gsel[r0+jj]; }
    }
    #pragma unroll
    for (int nt=0; nt<4; nt++){
      int col = n0 + wc*64 + nt*16 + fr;
      f32x4 v = acc[mt][nt];
      if constexpr (MODE==0){
        #pragma unroll
        for (int jj=0;jj<4;jj++){
          float val = v[jj];
          __bf16 hb = (__bf16)val;
          size_t idx = (size_t)(r0+jj)*N + col;
          Ch[idx] = hb; Cl[idx] = (__bf16)(val-(float)hb);
        }
      } else if constexpr (MODE==1){
        float bs = bias[col];
        #pragma unroll
        for (int jj=0;jj<4;jj++){
          size_t idx = (size_t)(r0+jj)*N + col;
          Cf[idx] = v[jj] + bs + resid[idx];
        }
      } else if constexpr (MODE==2){
        float bs = bias[col];
        #pragma unroll
        for (int jj=0;jj<4;jj++)
          Ch[(size_t)(r0+jj)*N + col] = (__bf16)fmaxf(v[jj]+bs, 0.f);
      } else {
        float bs = bias[col];
        #pragma unroll
        for (int jj=0;jj<4;jj++){
          if (tk4[jj] < TOK_N)
            Cf[(size_t)tk4[jj]*N + col] += (v[jj]+bs)*g4[jj];
        }
      }
    }
  }
}

// ---------------- causal flash attention, fp32 compute, hi/lo bf16 I/O ----------------
__global__ __launch_bounds__(256) void attn_kernel(
    const __bf16* __restrict__ qh, const __bf16* __restrict__ ql,
    const __bf16* __restrict__ kh, const __bf16* __restrict__ kl,
    const __bf16* __restrict__ vh, const __bf16* __restrict__ vl,
    __bf16* __restrict__ oh, __bf16* __restrict__ ol)
{
  __shared__ float Qs[64][68], Kt[64][68], Vs[64][68], Ps[64][68];
  int qt = blockIdx.x;
  int bh = blockIdx.y;
  int batch = bh >> 4, head = bh & 15;
  int t = threadIdx.x, lane = t & 63, wid = t >> 6;
  size_t rowbase = (size_t)batch*1024;
  int col0 = head*64;
  for (int idx=t; idx<64*16; idx+=256){
    int r = idx>>4, c4 = (idx&15)*4;
    size_t gofs = (rowbase + qt*64 + r)*DMODEL + col0 + c4;
    bf16x4 h4 = *(const bf16x4*)&qh[gofs];
    bf16x4 l4 = *(const bf16x4*)&ql[gofs];
    float4 f;
    f.x=(float)h4[0]+(float)l4[0]; f.y=(float)h4[1]+(float)l4[1];
    f.z=(float)h4[2]+(float)l4[2]; f.w=(float)h4[3]+(float)l4[3];
    *(float4*)&Qs[r][c4] = f;
  }
  float m[16], l[16], acc[16], s[16];
  #pragma unroll
  for (int r=0;r<16;r++){ m[r]=-INFINITY; l[r]=0.f; acc[r]=0.f; }
  __syncthreads();
  const float scale = 0.03125f;   // D^-0.5 = 1/32
  for (int kt=0; kt<=qt; kt++){
    __syncthreads();
    for (int idx=t; idx<64*16; idx+=256){
      int r = idx>>4, c4 = (idx&15)*4;
      size_t gofs = (rowbase + kt*64 + r)*DMODEL + col0 + c4;
      bf16x4 h4 = *(const bf16x4*)&kh[gofs];
      bf16x4 l4 = *(const bf16x4*)&kl[gofs];
      Kt[c4+0][r]=(float)h4[0]+(float)l4[0]; Kt[c4+1][r]=(float)h4[1]+(float)l4[1];
      Kt[c4+2][r]=(float)h4[2]+(float)l4[2]; Kt[c4+3][r]=(float)h4[3]+(float)l4[3];
      bf16x4 vh4 = *(const bf16x4*)&vh[gofs];
      bf16x4 vl4 = *(const bf16x4*)&vl[gofs];
      float4 f;
      f.x=(float)vh4[0]+(float)vl4[0]; f.y=(float)vh4[1]+(float)vl4[1];
      f.z=(float)vh4[2]+(float)vl4[2]; f.w=(float)vh4[3]+(float)vl4[3];
      *(float4*)&Vs[r][c4] = f;
    }
    __syncthreads();
    #pragma unroll
    for (int r=0;r<16;r++) s[r]=0.f;
    for (int d0=0; d0<64; d0+=4){
      float k0=Kt[d0][lane], k1=Kt[d0+1][lane], k2=Kt[d0+2][lane], k3=Kt[d0+3][lane];
      #pragma unroll
      for (int r=0;r<16;r++){
        const float4 q4 = *(const float4*)&Qs[wid*16+r][d0];
        s[r] += q4.x*k0 + q4.y*k1 + q4.z*k2 + q4.w*k3;
      }
    }
    int jg = kt*64 + lane;
    #pragma unroll
    for (int r=0;r<16;r++){
      int qg = qt*64 + wid*16 + r;
      float sv = s[r]*scale;
      if (jg > qg) sv = -INFINITY;
      float mt = sv;
      #pragma unroll
      for (int o_=32;o_;o_>>=1) mt = fmaxf(mt, __shfl_xor(mt,o_));
      float mn = fmaxf(m[r], mt);
      float p  = expf(sv - mn);
      float sc = expf(m[r] - mn);
      float ps = p;
      #pragma unroll
      for (int o_=32;o_;o_>>=1) ps += __shfl_xor(ps,o_);
      l[r] = l[r]*sc + ps;
      acc[r] *= sc;
      m[r] = mn;
      Ps[wid*16+r][lane] = p;
    }
    __syncthreads();
    for (int j0=0;j0<64;j0+=4){
      float v0=Vs[j0][lane], v1=Vs[j0+1][lane], v2=Vs[j0+2][lane], v3=Vs[j0+3][lane];
      #pragma unroll
      for (int r=0;r<16;r++){
        const float4 p4 = *(const float4*)&Ps[wid*16+r][j0];
        acc[r] += p4.x*v0 + p4.y*v1 + p4.z*v2 + p4.w*v3;
      }
    }
  }
  #pragma unroll
  for (int r=0;r<16;r++){
    float val = acc[r]/l[r];
    size_t ofs = (rowbase + qt*64 + wid*16 + r)*DMODEL + col0 + lane;
    __bf16 hb = (__bf16)val;
    oh[ofs]=hb; ol[ofs]=(__bf16)(val-(float)hb);
  }
}

// ---------------- router (h2 from hi/lo) ----------------
__global__ __launch_bounds__(256) void router_kernel(
    const __bf16* __restrict__ h2h, const __bf16* __restrict__ h2l,
    const float* __restrict__ wr, const float* __restrict__ br,
    const float* __restrict__ wn, const float* __restrict__ bn,
    const float* __restrict__ wsk, const float* __restrict__ bsk,
    const float* __restrict__ noise,
    int* __restrict__ idx2, float* __restrict__ gate2, int* __restrict__ nskv)
{
  int n = blockIdx.x, t = threadIdx.x;
  bf16x4 h4 = *(const bf16x4*)&h2h[(size_t)n*DMODEL + t*4];
  bf16x4 l4 = *(const bf16x4*)&h2l[(size_t)n*DMODEL + t*4];
  float hv_[4];
  #pragma unroll
  for (int i=0;i<4;i++) hv_[i] = (float)h4[i] + (float)l4[i];
  int d0 = t*4;
  const float* wrp = wr + (size_t)d0*NEXP;
  const float* wnp = wn + (size_t)d0*NEXP;
  const float* wsp = wsk + d0;
  float vals[17];
  #pragma unroll
  for (int i=0;i<17;i++) vals[i]=0.f;
  #pragma unroll
  for (int i=0;i<4;i++){
    #pragma unroll
    for (int e=0;e<NEXP;e++){
      vals[e]   += hv_[i]*wrp[i*NEXP+e];
      vals[8+e] += hv_[i]*wnp[i*NEXP+e];
    }
    vals[16] += hv_[i]*wsp[i];
  }
  __shared__ float red[4][17];
  int lane = t & 63, wid = t >> 6;
  #pragma unroll
  for (int i=0;i<17;i++){
    float x = wave_sum(vals[i]);
    if (lane==0) red[wid][i] = x;
  }
  __syncthreads();
  if (t==0){
    float noisy[NEXP];
    #pragma unroll
    for (int e=0;e<NEXP;e++){
      float lr = red[0][e]+red[1][e]+red[2][e]+red[3][e] + br[e];
      float pn = red[0][8+e]+red[1][8+e]+red[2][8+e]+red[3][8+e] + bn[e];
      float sp = fmaxf(pn,0.f) + log1pf(expf(-fabsf(pn)));
      noisy[e] = lr + noise[(size_t)n*NEXP + e]*sp;
    }
    float sk = red[0][16]+red[1][16]+red[2][16]+red[3][16] + bsk[0];
    nskv[n] = (sk <= 0.f) ? 1 : 0;
    int i0=0; float v0=noisy[0];
    #pragma unroll
    for (int e=1;e<NEXP;e++) if (noisy[e] > v0){ v0=noisy[e]; i0=e; }
    int i1=-1; float v1=-INFINITY;
    #pragma unroll
    for (int e=0;e<NEXP;e++) if (e!=i0 && noisy[e] > v1){ v1=noisy[e]; i1=e; }
    float tt = expf(v1 - v0);
    idx2[n*2+0]=i0; idx2[n*2+1]=i1;
    gate2[n*2+0]=1.0f/(1.0f+tt); gate2[n*2+1]=tt/(1.0f+tt);
  }
}

// ---------------- capacity scan + slot assignment (+ zero pad buffer) ----------------
__global__ __launch_bounds__(256) void scan_kernel(const int* __restrict__ idx2,
    const float* __restrict__ gate2, const int* __restrict__ nskv,
    int* __restrict__ tok, float* __restrict__ gsel, float* __restrict__ zbuf)
{
  int t = threadIdx.x;
  for (int i=t; i<NEXP*CAPMAX; i+=256){ tok[i]=TOK_N; gsel[i]=0.f; }
  zbuf[t] = 0.f;                          // 1KB zero pad for gather OOB
  __shared__ int cnts[256][NEXP];
  __shared__ int nns_part[256];
  __shared__ int cap_s;
  int loc[NEXP];
  #pragma unroll
  for (int e=0;e<NEXP;e++) loc[e]=0;
  int nn=0, base = t*16;
  for (int u=0;u<16;u++){
    int n = base+u;
    if (nskv[n]){ nn++; loc[idx2[n*2]]++; loc[idx2[n*2+1]]++; }
  }
  #pragma unroll
  for (int e=0;e<NEXP;e++) cnts[t][e]=loc[e];
  nns_part[t]=nn;
  __syncthreads();
  if (t < NEXP){ int run=0; for (int i=0;i<256;i++){ int c=cnts[i][t]; cnts[i][t]=run; run+=c; } }
  if (t == NEXP){ int sum=0; for (int i=0;i<256;i++) sum+=nns_part[i]; cap_s = sum/4; }
  __syncthreads();
  int capacity = cap_s;
  int run[NEXP];
  #pragma unroll
  for (int e=0;e<NEXP;e++) run[e]=cnts[t][e];
  for (int u=0;u<16;u++){
    int n = base+u;
    if (!nskv[n]) continue;
    #pragma unroll
    for (int kk=0;kk<2;kk++){
      int e = idx2[n*2+kk];
      int r = run[e]++;
      if (r < capacity){ tok[e*CAPMAX+r]=n; gsel[e*CAPMAX+r]=gate2[n*2+kk]; }
    }
  }
}

// ---------------- out = x1 + (nsk ? 0 : h2), in-place on d_out ----------------
__global__ __launch_bounds__(256) void out_init_kernel(
    const __bf16* __restrict__ h2h, const __bf16* __restrict__ h2l,
    const int* __restrict__ nskv, float* __restrict__ out)
{
  int n = blockIdx.x, t = threadIdx.x;
  float4 a = ((const float4*)(out + (size_t)n*DMODEL))[t];
  if (!nskv[n]){
    bf16x4 h4 = *(const bf16x4*)&h2h[(size_t)n*DMODEL + t*4];
    bf16x4 l4 = *(const bf16x4*)&h2l[(size_t)n*DMODEL + t*4];
    a.x += (float)h4[0]+(float)l4[0]; a.y += (float)h4[1]+(float)l4[1];
    a.z += (float)h4[2]+(float)l4[2]; a.w += (float)h4[3]+(float)l4[3];
  }
  ((float4*)(out + (size_t)n*DMODEL))[t] = a;
}

extern "C" void kernel_launch(void* const* d_in, const int* in_sizes, int n_in,
                              void* d_out, int out_size, void* d_ws, size_t ws_size,
                              hipStream_t stream) {
  const float* x      = (const float*)d_in[0];
  const float* noise  = (const float*)d_in[1];
  const float* ln1_g  = (const float*)d_in[2];
  const float* ln1_b  = (const float*)d_in[3];
  const float* wq     = (const float*)d_in[4];
  const float* wk     = (const float*)d_in[5];
  const float* wv     = (const float*)d_in[6];
  const float* w_proj = (const float*)d_in[7];
  const float* b_proj = (const float*)d_in[8];
  const float* ln2_g  = (const float*)d_in[9];
  const float* ln2_b  = (const float*)d_in[10];
  const float* w_rout = (const float*)d_in[11];
  const float* b_rout = (const float*)d_in[12];
  const float* w_noi  = (const float*)d_in[13];
  const float* b_noi  = (const float*)d_in[14];
  const float* w_skip = (const float*)d_in[15];
  const float* b_skip = (const float*)d_in[16];
  const float* ew1    = (const float*)d_in[17];
  const float* eb1    = (const float*)d_in[18];
  const float* ew2    = (const float*)d_in[19];
  const float* eb2    = (const float*)d_in[20];
  float* out = (float*)d_out;

  char* ws = (char*)d_ws;
  const size_t MB = 1024*1024;
  // bf16 buffers, [4096][1024] unless noted
  __bf16* h_hi = (__bf16*)(ws + 0*MB);     // also attn-out hi (h dead after QKV)
  __bf16* h_lo = (__bf16*)(ws + 8*MB);
  __bf16* q_hi = (__bf16*)(ws + 16*MB);    // expert e1T reuses q_hi region later
  __bf16* q_lo = (__bf16*)(ws + 24*MB);
  __bf16* k_hi = (__bf16*)(ws + 32*MB);    // mid reuses k_hi region later
  __bf16* k_lo = (__bf16*)(ws + 40*MB);
  __bf16* v_hi = (__bf16*)(ws + 48*MB);
  __bf16* v_lo = (__bf16*)(ws + 56*MB);
  __bf16* wqT_h = (__bf16*)(ws + 64*MB);   // [N][K] 1024x1024 -> 2MB each
  __bf16* wqT_l = (__bf16*)(ws + 66*MB);
  __bf16* wkT_h = (__bf16*)(ws + 68*MB);
  __bf16* wkT_l = (__bf16*)(ws + 70*MB);
  __bf16* wvT_h = (__bf16*)(ws + 72*MB);
  __bf16* wvT_l = (__bf16*)(ws + 74*MB);
  __bf16* wpT_h = (__bf16*)(ws + 76*MB);
  __bf16* wpT_l = (__bf16*)(ws + 78*MB);
  int*   idx2  = (int*)  (ws + 80*MB);
  float* gate2 = (float*)(ws + 80*MB + 32*1024);
  int*   nskv  = (int*)  (ws + 80*MB + 64*1024);
  int*   tokb  = (int*)  (ws + 80*MB + 80*1024);
  float* gselb = (float*)(ws + 80*MB + 112*1024);
  float* zbuf  = (float*)(ws + 80*MB + 144*1024);
  // expert-phase reuse (q/k dead after attention)
  __bf16* e1T = q_hi;                       // [DFF][D] bf16 = 8MB
  __bf16* e2T = q_lo;                       // [D][DFF] bf16 = 8MB
  __bf16* mid = k_hi;                       // [CAPMAX][DFF] bf16 = 8MB
  __bf16* ao_hi = h_hi, *ao_lo = h_lo;

  dim3 blk(256);
  // weight transpose-converts (split)
  tconv_kernel<true><<<dim3(16,16), blk, 0, stream>>>(wq,     wqT_h, wqT_l, DMODEL, DMODEL);
  tconv_kernel<true><<<dim3(16,16), blk, 0, stream>>>(wk,     wkT_h, wkT_l, DMODEL, DMODEL);
  tconv_kernel<true><<<dim3(16,16), blk, 0, stream>>>(wv,     wvT_h, wvT_l, DMODEL, DMODEL);
  tconv_kernel<true><<<dim3(16,16), blk, 0, stream>>>(w_proj, wpT_h, wpT_l, DMODEL, DMODEL);
  // LN1
  ln_split_kernel<<<TOK_N, blk, 0, stream>>>(x, ln1_g, ln1_b, h_hi, h_lo);
  // QKV (split)
  mgemm<0,true><<<dim3(8,32), blk, 0, stream>>>(h_hi, h_lo, wqT_h, wqT_l, nullptr, nullptr,
      nullptr, q_hi, q_lo, DMODEL, DMODEL, nullptr, nullptr, nullptr);
  mgemm<0,true><<<dim3(8,32), blk, 0, stream>>>(h_hi, h_lo, wkT_h, wkT_l, nullptr, nullptr,
      nullptr, k_hi, k_lo, DMODEL, DMODEL, nullptr, nullptr, nullptr);
  mgemm<0,true><<<dim3(8,32), blk, 0, stream>>>(h_hi, h_lo, wvT_h, wvT_l, nullptr, nullptr,
      nullptr, v_hi, v_lo, DMODEL, DMODEL, nullptr, nullptr, nullptr);
  // attention (fp32 compute, hi/lo I/O) -> ao in h region (h dead)
  attn_kernel<<<dim3(16,64), blk, 0, stream>>>(q_hi,q_lo,k_hi,k_lo,v_hi,v_lo, ao_hi, ao_lo);
  // x1 = x + attn@w_proj + b  -> d_out
  mgemm<1,true><<<dim3(8,32), blk, 0, stream>>>(ao_hi, ao_lo, wpT_h, wpT_l, b_proj, x,
      out, nullptr, nullptr, DMODEL, DMODEL, nullptr, nullptr, nullptr);
  // LN2 -> h2 hi/lo (overwrites ao, dead)
  ln_split_kernel<<<TOK_N, blk, 0, stream>>>(out, ln2_g, ln2_b, h_hi, h_lo);
  // router + scan
  router_kernel<<<TOK_N, blk, 0, stream>>>(h_hi, h_lo, w_rout, b_rout, w_noi, b_noi,
                                           w_skip, b_skip, noise, idx2, gate2, nskv);
  scan_kernel<<<1, blk, 0, stream>>>(idx2, gate2, nskv, tokb, gselb, zbuf);
  // out = x1 + (nsk?0:h2), in place on d_out
  out_init_kernel<<<TOK_N, blk, 0, stream>>>(h_hi, h_lo, nskv, out);
  // experts: per-expert transpose-convert then plain-bf16 MFMA GEMMs
  for (int e=0; e<NEXP; e++){
    tconv_kernel<false><<<dim3(16,64), blk, 0, stream>>>(ew1 + (size_t)e*DMODEL*DFFD,
        e1T, nullptr, DMODEL, DFFD);                       // [D][DFF] -> [DFF][D]
    tconv_kernel<false><<<dim3(64,16), blk, 0, stream>>>(ew2 + (size_t)e*DFFD*DMODEL,
        e2T, nullptr, DFFD, DMODEL);                       // [DFF][D] -> [D][DFF]
    mgemm<2,false><<<dim3(32,8), blk, 0, stream>>>(h_hi, nullptr, e1T, nullptr,
        eb1 + (size_t)e*DFFD, nullptr, nullptr, mid, nullptr, DFFD, DMODEL,
        tokb + e*CAPMAX, nullptr, (const __bf16*)zbuf);
    mgemm<3,false><<<dim3(8,8), blk, 0, stream>>>(mid, nullptr, e2T, nullptr,
        eb2 + (size_t)e*DMODEL, nullptr, out, nullptr, nullptr, DMODEL, DFFD,
        tokb + e*CAPMAX, gselb + e*CAPMAX, nullptr);
  }
}

// Round 4
// 1506.809 us; speedup vs baseline: 2.8482x; 1.3384x over previous
//
#include <hip/hip_runtime.h>
#include <math.h>

#define TOK_N   4096
#define DMODEL  1024
#define NEXP    8
#define DFFD    4096
#define CAPMAX  1024

typedef __bf16 bf16x8 __attribute__((ext_vector_type(8)));
typedef __bf16 bf16x4 __attribute__((ext_vector_type(4)));
typedef float  f32x4  __attribute__((ext_vector_type(4)));

__device__ __forceinline__ f32x4 MFMA16(bf16x8 a, bf16x8 b, f32x4 c){
  return __builtin_amdgcn_mfma_f32_16x16x32_bf16(a, b, c, 0, 0, 0);
}

// async global->LDS, 16B per lane; lds ptr must be wave-uniform base (HW adds lane*16)
__device__ __forceinline__ void gl16(const __bf16* g, __bf16* l){
  __builtin_amdgcn_global_load_lds(
      (const __attribute__((address_space(1))) unsigned int*)g,
      (__attribute__((address_space(3))) unsigned int*)l, 16, 0, 0);
}

__device__ __forceinline__ float wave_sum(float x){
  #pragma unroll
  for (int o=32;o;o>>=1) x += __shfl_down(x,o);
  return x;
}

// ---------------- LayerNorm -> hi/lo bf16 ----------------
__global__ __launch_bounds__(256) void ln_split_kernel(const float* __restrict__ in,
    const float* __restrict__ g, const float* __restrict__ b,
    __bf16* __restrict__ oh, __bf16* __restrict__ ol){
  int n = blockIdx.x, t = threadIdx.x;
  const float4* row = (const float4*)(in + (size_t)n*DMODEL);
  float4 v = row[t];
  float s  = v.x+v.y+v.z+v.w;
  float sq = v.x*v.x+v.y*v.y+v.z*v.z+v.w*v.w;
  s = wave_sum(s); sq = wave_sum(sq);
  __shared__ float r1[4], r2[4];
  __shared__ float mean_s, rstd_s;
  int lane = t & 63, wid = t >> 6;
  if (lane==0){ r1[wid]=s; r2[wid]=sq; }
  __syncthreads();
  if (t==0){
    float a = r1[0]+r1[1]+r1[2]+r1[3];
    float c = r2[0]+r2[1]+r2[2]+r2[3];
    float mean = a*(1.0f/DMODEL);
    float var  = c*(1.0f/DMODEL) - mean*mean;
    mean_s = mean; rstd_s = 1.0f/sqrtf(var + 1e-5f);
  }
  __syncthreads();
  float mean = mean_s, rstd = rstd_s;
  float4 g4 = ((const float4*)g)[t];
  float4 b4 = ((const float4*)b)[t];
  float o_[4];
  o_[0] = (v.x-mean)*rstd*g4.x + b4.x;
  o_[1] = (v.y-mean)*rstd*g4.y + b4.y;
  o_[2] = (v.z-mean)*rstd*g4.z + b4.z;
  o_[3] = (v.w-mean)*rstd*g4.w + b4.w;
  bf16x4 h4, l4;
  #pragma unroll
  for (int i=0;i<4;i++){ __bf16 hb=(__bf16)o_[i]; h4[i]=hb; l4[i]=(__bf16)(o_[i]-(float)hb); }
  *(bf16x4*)&oh[(size_t)n*DMODEL + t*4] = h4;
  *(bf16x4*)&ol[(size_t)n*DMODEL + t*4] = l4;
}

// ---------------- transpose-convert: in[K][N] f32 -> oh/ol [N][K] bf16 ----------------
template<bool SPLIT>
__global__ __launch_bounds__(256) void tconv_kernel(const float* __restrict__ in,
    __bf16* __restrict__ oh, __bf16* __restrict__ ol, int K, int N){
  __shared__ float tile[64][65];
  int k0 = blockIdx.x*64, n0 = blockIdx.y*64;
  int t = threadIdx.x;
  #pragma unroll
  for (int i=0;i<4;i++){
    int row = (t>>4) + i*16;
    int col = (t&15)*4;
    float4 f = *(const float4*)&in[(size_t)(k0+row)*N + n0 + col];
    tile[row][col]=f.x; tile[row][col+1]=f.y; tile[row][col+2]=f.z; tile[row][col+3]=f.w;
  }
  __syncthreads();
  #pragma unroll
  for (int i=0;i<2;i++){
    int c = t + i*256;           // 0..511
    int orow = c>>3, kg = (c&7)*8;
    bf16x8 hv, lv;
    #pragma unroll
    for (int u=0;u<8;u++){
      float x = tile[kg+u][orow];
      __bf16 hb = (__bf16)x;
      hv[u]=hb;
      if constexpr (SPLIT) lv[u]=(__bf16)(x-(float)hb);
    }
    *(bf16x8*)&oh[(size_t)(n0+orow)*K + k0 + kg] = hv;
    if constexpr (SPLIT) *(bf16x8*)&ol[(size_t)(n0+orow)*K + k0 + kg] = lv;
  }
}

// ---------------- bf16-pair transpose: in[4096][1024] -> out[1024][4096] ----------------
__global__ __launch_bounds__(256) void btrans_kernel(
    const __bf16* __restrict__ ih, const __bf16* __restrict__ il,
    __bf16* __restrict__ oh, __bf16* __restrict__ ol){
  __shared__ __bf16 th[64][72], tl[64][72];
  int r0 = blockIdx.x*64, c0 = blockIdx.y*64;
  int t = threadIdx.x;
  {
    int r = t>>2, cg = (t&3)*16;
    size_t go = (size_t)(r0+r)*DMODEL + c0 + cg;
    *(bf16x8*)&th[r][cg]   = *(const bf16x8*)&ih[go];
    *(bf16x8*)&th[r][cg+8] = *(const bf16x8*)&ih[go+8];
    *(bf16x8*)&tl[r][cg]   = *(const bf16x8*)&il[go];
    *(bf16x8*)&tl[r][cg+8] = *(const bf16x8*)&il[go+8];
  }
  __syncthreads();
  {
    int c = t>>2, rg = (t&3)*16;
    bf16x8 a,b,e,f;
    #pragma unroll
    for (int u=0;u<8;u++){ a[u]=th[rg+u][c]; b[u]=th[rg+8+u][c]; e[u]=tl[rg+u][c]; f[u]=tl[rg+8+u][c]; }
    size_t go = (size_t)(c0+c)*TOK_N + r0 + rg;
    *(bf16x8*)&oh[go]   = a;
    *(bf16x8*)&oh[go+8] = b;
    *(bf16x8*)&ol[go]   = e;
    *(bf16x8*)&ol[go+8] = f;
  }
}

// ---------------- MFMA GEMM, 128x128, BK=32, global_load_lds staging ----------------
// A: [M][K] bf16 (hi/lo), B: [N][K] bf16 (hi/lo, pre-transposed)
// MODE 0: QKV   -> Ch/Cl hi/lo bf16
// MODE 1: PROJ  -> Cf = acc + bias + resid (f32)
// MODE 2: UP    -> Ch = bf16(relu(acc+bias)), A rows gathered via tok (invalid -> zbuf)
// MODE 3: DN    -> Cf[tok[row]] += (acc+bias)*gsel[row]
template<int MODE, bool SPLIT>
__global__ __launch_bounds__(256) void mgemm(
    const __bf16* __restrict__ Ah, const __bf16* __restrict__ Al,
    const __bf16* __restrict__ Bh, const __bf16* __restrict__ Bl,
    const float* __restrict__ bias, const float* __restrict__ resid,
    float* __restrict__ Cf, __bf16* __restrict__ Ch, __bf16* __restrict__ Cl,
    int N, int K,
    const int* __restrict__ tok, const float* __restrict__ gsel,
    const __bf16* __restrict__ zbuf)
{
  int m0 = blockIdx.y*128, n0 = blockIdx.x*128;
  if ((MODE==2||MODE==3) && tok[m0] >= TOK_N) return;   // valid slots are a prefix
  __shared__ __bf16 sAh[128*32], sBh[128*32];
  __shared__ __bf16 sAl[SPLIT?128*32:8], sBl[SPLIT?128*32:8];
  int t = threadIdx.x, lane = t&63, w = t>>6;
  int wr = w>>1, wc = w&1, fr = lane&15, kb = lane>>4;

  const __bf16* aB[2]; const __bf16* aBl[2]; bool aval[2];
  const __bf16* bB[2]; const __bf16* bBl[2];
  #pragma unroll
  for (int j=0;j<2;j++){
    int c = j*256 + w*64 + lane;
    int row = c>>2, grp = c&3;
    if (MODE==2){
      int token = tok[m0+row];
      if (token < TOK_N){ aB[j] = Ah + (size_t)token*K + grp*8; aval[j]=true; }
      else              { aB[j] = zbuf + grp*8;                 aval[j]=false; }
    } else {
      aB[j] = Ah + (size_t)(m0+row)*K + grp*8; aval[j]=true;
      if (SPLIT) aBl[j] = Al + (size_t)(m0+row)*K + grp*8;
    }
    bB[j] = Bh + (size_t)(n0+row)*K + grp*8;
    if (SPLIT) bBl[j] = Bl + (size_t)(n0+row)*K + grp*8;
  }

  f32x4 acc[4][4];
  #pragma unroll
  for (int mt=0;mt<4;mt++)
    #pragma unroll
    for (int nt=0;nt<4;nt++) acc[mt][nt] = (f32x4){0.f,0.f,0.f,0.f};

  for (int kt=0; kt<K; kt+=32){
    __syncthreads();
    #pragma unroll
    for (int j=0;j<2;j++){
      int cb8 = (j*256 + w*64)*8;
      gl16(aval[j] ? aB[j]+kt : aB[j], &sAh[cb8]);
      gl16(bB[j]+kt, &sBh[cb8]);
      if constexpr (SPLIT){
        gl16(aBl[j]+kt, &sAl[cb8]);
        gl16(bBl[j]+kt, &sBl[cb8]);
      }
    }
    __syncthreads();
    bf16x8 aFh[4], bFh[4];
    #pragma unroll
    for (int mt=0;mt<4;mt++) aFh[mt] = *(const bf16x8*)&sAh[(wr*64+mt*16+fr)*32 + kb*8];
    #pragma unroll
    for (int nt=0;nt<4;nt++) bFh[nt] = *(const bf16x8*)&sBh[(wc*64+nt*16+fr)*32 + kb*8];
    #pragma unroll
    for (int mt=0;mt<4;mt++)
      #pragma unroll
      for (int nt=0;nt<4;nt++)
        acc[mt][nt] = MFMA16(aFh[mt], bFh[nt], acc[mt][nt]);
    if constexpr (SPLIT){
      bf16x8 aFl[4], bFl[4];
      #pragma unroll
      for (int mt=0;mt<4;mt++) aFl[mt] = *(const bf16x8*)&sAl[(wr*64+mt*16+fr)*32 + kb*8];
      #pragma unroll
      for (int nt=0;nt<4;nt++) bFl[nt] = *(const bf16x8*)&sBl[(wc*64+nt*16+fr)*32 + kb*8];
      #pragma unroll
      for (int mt=0;mt<4;mt++)
        #pragma unroll
        for (int nt=0;nt<4;nt++){
          acc[mt][nt] = MFMA16(aFh[mt], bFl[nt], acc[mt][nt]);
          acc[mt][nt] = MFMA16(aFl[mt], bFh[nt], acc[mt][nt]);
        }
    }
  }
  #pragma unroll
  for (int mt=0; mt<4; mt++){
    int r0 = m0 + wr*64 + mt*16 + (lane>>4)*4;
    int tk4[4]; float g4[4];
    if constexpr (MODE==3){
      #pragma unroll
      for (int jj=0;jj<4;jj++){ tk4[jj]=tok[r0+jj]; g4[jj]=gsel[r0+jj]; }
    }
    #pragma unroll
    for (int nt=0; nt<4; nt++){
      int col = n0 + wc*64 + nt*16 + fr;
      f32x4 v = acc[mt][nt];
      if constexpr (MODE==0){
        #pragma unroll
        for (int jj=0;jj<4;jj++){
          float val = v[jj];
          __bf16 hb = (__bf16)val;
          size_t idx = (size_t)(r0+jj)*N + col;
          Ch[idx] = hb; Cl[idx] = (__bf16)(val-(float)hb);
        }
      } else if constexpr (MODE==1){
        float bs = bias[col];
        #pragma unroll
        for (int jj=0;jj<4;jj++){
          size_t idx = (size_t)(r0+jj)*N + col;
          Cf[idx] = v[jj] + bs + resid[idx];
        }
      } else if constexpr (MODE==2){
        float bs = bias[col];
        #pragma unroll
        for (int jj=0;jj<4;jj++)
          Ch[(size_t)(r0+jj)*N + col] = (__bf16)fmaxf(v[jj]+bs, 0.f);
      } else {
        float bs = bias[col];
        #pragma unroll
        for (int jj=0;jj<4;jj++){
          if (tk4[jj] < TOK_N)
            Cf[(size_t)tk4[jj]*N + col] += (v[jj]+bs)*g4[jj];
        }
      }
    }
  }
}

// ---------------- MFMA causal flash attention, split-bf16 (~fp32 exact) ----------------
// Per block: 64 q-rows of one (batch,head); 4 waves, wave w owns rows w*16..w*16+15.
// LDS tiles linear [64][64] bf16, XOR-swizzled via global source (seg^(row&7)).
__global__ __launch_bounds__(256) void attn_mfma_kernel(
    const __bf16* __restrict__ qh, const __bf16* __restrict__ ql,
    const __bf16* __restrict__ kh, const __bf16* __restrict__ kl,
    const __bf16* __restrict__ vth, const __bf16* __restrict__ vtl,  // vT[1024][4096]
    __bf16* __restrict__ oh, __bf16* __restrict__ ol)
{
  __shared__ __bf16 Qh[64*64], Ql[64*64], Kh[64*64], Kl[64*64], Vh[64*64], Vl[64*64];
  __shared__ __bf16 Ps[2][4][16*64];
  int qt = blockIdx.x, bh = blockIdx.y;
  int batch = bh>>4, head = bh&15;
  int t = threadIdx.x, lane = t&63, w = t>>6;
  int g = lane>>4, fr = lane&15;
  int col0 = head*64;
  size_t qbase = (size_t)(batch*1024 + qt*64);
  const float scale = 0.03125f;              // D^-0.5 = 1/32

  // stage Q (swizzled source)
  #pragma unroll
  for (int j=0;j<2;j++){
    int c = j*256 + t, row = c>>3, seg = c&7;
    size_t go = (qbase+row)*DMODEL + col0 + ((seg^(row&7))*8);
    int lb = (j*256 + w*64)*8;
    gl16(qh+go, &Qh[lb]);
    gl16(ql+go, &Ql[lb]);
  }
  __syncthreads();
  bf16x8 aQh[2], aQl[2];
  #pragma unroll
  for (int ks=0; ks<2; ks++){
    int row = w*16 + fr;
    int sc_ = (ks*4 + g) ^ (row&7);
    aQh[ks] = *(const bf16x8*)&Qh[row*64 + sc_*8];
    aQl[ks] = *(const bf16x8*)&Ql[row*64 + sc_*8];
  }

  float m_[4], l_[4];
  f32x4 o_[4];
  #pragma unroll
  for (int j=0;j<4;j++){ m_[j]=-INFINITY; l_[j]=0.f; }
  #pragma unroll
  for (int nt=0;nt<4;nt++) o_[nt]=(f32x4){0.f,0.f,0.f,0.f};

  for (int kt=0; kt<=qt; kt++){
    __syncthreads();                         // all waves done with prev K/V
    size_t kbase = (size_t)(batch*1024 + kt*64);
    #pragma unroll
    for (int j=0;j<2;j++){
      int c = j*256 + t, row = c>>3, seg = c&7;
      int lb = (j*256 + w*64)*8;
      size_t gk = (kbase+row)*DMODEL + col0 + ((seg^(row&7))*8);
      gl16(kh+gk, &Kh[lb]);
      gl16(kl+gk, &Kl[lb]);
      size_t gv = (size_t)(col0+row)*TOK_N + (size_t)(batch*1024 + kt*64) + ((seg^(row&7))*8);
      gl16(vth+gv, &Vh[lb]);
      gl16(vtl+gv, &Vl[lb]);
    }
    __syncthreads();                         // tiles visible
    // ---- S = Q K^T (split, 3 passes) ----
    f32x4 s[4];
    #pragma unroll
    for (int nt=0;nt<4;nt++) s[nt]=(f32x4){0.f,0.f,0.f,0.f};
    #pragma unroll
    for (int ks=0; ks<2; ks++){
      #pragma unroll
      for (int nt=0; nt<4; nt++){
        int kvr = nt*16 + fr;
        int sc_ = (ks*4 + g) ^ (kvr&7);
        bf16x8 bKh = *(const bf16x8*)&Kh[kvr*64 + sc_*8];
        bf16x8 bKl = *(const bf16x8*)&Kl[kvr*64 + sc_*8];
        s[nt] = MFMA16(aQh[ks], bKh, s[nt]);
        s[nt] = MFMA16(aQh[ks], bKl, s[nt]);
        s[nt] = MFMA16(aQl[ks], bKh, s[nt]);
      }
    }
    // ---- online softmax (wave-parallel; row = g*4+j in 16-lane group) ----
    bool diag = (kt==qt);
    #pragma unroll
    for (int j=0;j<4;j++){
      int rowg = qt*64 + w*16 + g*4 + j;
      float sv[4];
      #pragma unroll
      for (int nt=0;nt<4;nt++){
        float x = s[nt][j]*scale;
        if (diag && (kt*64 + nt*16 + fr) > rowg) x = -INFINITY;
        sv[nt] = x;
      }
      float mx = fmaxf(fmaxf(sv[0],sv[1]), fmaxf(sv[2],sv[3]));
      #pragma unroll
      for (int o2=1;o2<16;o2<<=1) mx = fmaxf(mx, __shfl_xor(mx,o2));
      float nm = fmaxf(m_[j], mx);
      float scf = __expf(m_[j]-nm);
      float p[4], ps=0.f;
      #pragma unroll
      for (int nt=0;nt<4;nt++){ p[nt]=__expf(sv[nt]-nm); ps+=p[nt]; }
      #pragma unroll
      for (int o2=1;o2<16;o2<<=1) ps += __shfl_xor(ps,o2);
      l_[j] = l_[j]*scf + ps;
      m_[j] = nm;
      o_[0][j]*=scf; o_[1][j]*=scf; o_[2][j]*=scf; o_[3][j]*=scf;
      int prow = g*4 + j;
      #pragma unroll
      for (int nt=0;nt<4;nt++){
        int col = nt*16 + fr;
        int el = prow*64 + (((col>>3)^(prow&7))*8) + (col&7);
        __bf16 phb = (__bf16)p[nt];
        Ps[0][w][el] = phb;
        Ps[1][w][el] = (__bf16)(p[nt]-(float)phb);
      }
    }
    // ---- O += P V (split, 3 passes) ----
    #pragma unroll
    for (int ks=0; ks<2; ks++){
      int pc = (ks*4 + g) ^ (fr&7);
      bf16x8 aPh = *(const bf16x8*)&Ps[0][w][fr*64 + pc*8];
      bf16x8 aPl = *(const bf16x8*)&Ps[1][w][fr*64 + pc*8];
      #pragma unroll
      for (int nt=0; nt<4; nt++){
        int vr = nt*16 + fr;
        int vc = (ks*4 + g) ^ (vr&7);
        bf16x8 bVh = *(const bf16x8*)&Vh[vr*64 + vc*8];
        bf16x8 bVl = *(const bf16x8*)&Vl[vr*64 + vc*8];
        o_[nt] = MFMA16(aPh, bVh, o_[nt]);
        o_[nt] = MFMA16(aPh, bVl, o_[nt]);
        o_[nt] = MFMA16(aPl, bVh, o_[nt]);
      }
    }
  }
  // epilogue: O/l -> hi/lo bf16
  #pragma unroll
  for (int j=0;j<4;j++){
    float inv = 1.0f/l_[j];
    size_t rofs = (qbase + w*16 + g*4 + j)*DMODEL + col0;
    #pragma unroll
    for (int nt=0;nt<4;nt++){
      float val = o_[nt][j]*inv;
      __bf16 hb = (__bf16)val;
      oh[rofs + nt*16 + fr] = hb;
      ol[rofs + nt*16 + fr] = (__bf16)(val-(float)hb);
    }
  }
}

// ---------------- router (h2 from hi/lo) ----------------
__global__ __launch_bounds__(256) void router_kernel(
    const __bf16* __restrict__ h2h, const __bf16* __restrict__ h2l,
    const float* __restrict__ wr, const float* __restrict__ br,
    const float* __restrict__ wn, const float* __restrict__ bn,
    const float* __restrict__ wsk, const float* __restrict__ bsk,
    const float* __restrict__ noise,
    int* __restrict__ idx2, float* __restrict__ gate2, int* __restrict__ nskv)
{
  int n = blockIdx.x, t = threadIdx.x;
  bf16x4 h4 = *(const bf16x4*)&h2h[(size_t)n*DMODEL + t*4];
  bf16x4 l4 = *(const bf16x4*)&h2l[(size_t)n*DMODEL + t*4];
  float hv_[4];
  #pragma unroll
  for (int i=0;i<4;i++) hv_[i] = (float)h4[i] + (float)l4[i];
  int d0 = t*4;
  const float* wrp = wr + (size_t)d0*NEXP;
  const float* wnp = wn + (size_t)d0*NEXP;
  const float* wsp = wsk + d0;
  float vals[17];
  #pragma unroll
  for (int i=0;i<17;i++) vals[i]=0.f;
  #pragma unroll
  for (int i=0;i<4;i++){
    #pragma unroll
    for (int e=0;e<NEXP;e++){
      vals[e]   += hv_[i]*wrp[i*NEXP+e];
      vals[8+e] += hv_[i]*wnp[i*NEXP+e];
    }
    vals[16] += hv_[i]*wsp[i];
  }
  __shared__ float red[4][17];
  int lane = t & 63, wid = t >> 6;
  #pragma unroll
  for (int i=0;i<17;i++){
    float x = wave_sum(vals[i]);
    if (lane==0) red[wid][i] = x;
  }
  __syncthreads();
  if (t==0){
    float noisy[NEXP];
    #pragma unroll
    for (int e=0;e<NEXP;e++){
      float lr = red[0][e]+red[1][e]+red[2][e]+red[3][e] + br[e];
      float pn = red[0][8+e]+red[1][8+e]+red[2][8+e]+red[3][8+e] + bn[e];
      float sp = fmaxf(pn,0.f) + log1pf(expf(-fabsf(pn)));
      noisy[e] = lr + noise[(size_t)n*NEXP + e]*sp;
    }
    float sk = red[0][16]+red[1][16]+red[2][16]+red[3][16] + bsk[0];
    nskv[n] = (sk <= 0.f) ? 1 : 0;
    int i0=0; float v0=noisy[0];
    #pragma unroll
    for (int e=1;e<NEXP;e++) if (noisy[e] > v0){ v0=noisy[e]; i0=e; }
    int i1=-1; float v1=-INFINITY;
    #pragma unroll
    for (int e=0;e<NEXP;e++) if (e!=i0 && noisy[e] > v1){ v1=noisy[e]; i1=e; }
    float tt = expf(v1 - v0);
    idx2[n*2+0]=i0; idx2[n*2+1]=i1;
    gate2[n*2+0]=1.0f/(1.0f+tt); gate2[n*2+1]=tt/(1.0f+tt);
  }
}

// ---------------- capacity scan + slot assignment (+ zero pad buffer) ----------------
__global__ __launch_bounds__(256) void scan_kernel(const int* __restrict__ idx2,
    const float* __restrict__ gate2, const int* __restrict__ nskv,
    int* __restrict__ tok, float* __restrict__ gsel, float* __restrict__ zbuf)
{
  int t = threadIdx.x;
  for (int i=t; i<NEXP*CAPMAX; i+=256){ tok[i]=TOK_N; gsel[i]=0.f; }
  zbuf[t] = 0.f;
  __shared__ int cnts[256][NEXP];
  __shared__ int nns_part[256];
  __shared__ int cap_s;
  int loc[NEXP];
  #pragma unroll
  for (int e=0;e<NEXP;e++) loc[e]=0;
  int nn=0, base = t*16;
  for (int u=0;u<16;u++){
    int n = base+u;
    if (nskv[n]){ nn++; loc[idx2[n*2]]++; loc[idx2[n*2+1]]++; }
  }
  #pragma unroll
  for (int e=0;e<NEXP;e++) cnts[t][e]=loc[e];
  nns_part[t]=nn;
  __syncthreads();
  if (t < NEXP){ int run=0; for (int i=0;i<256;i++){ int c=cnts[i][t]; cnts[i][t]=run; run+=c; } }
  if (t == NEXP){ int sum=0; for (int i=0;i<256;i++) sum+=nns_part[i]; cap_s = sum/4; }
  __syncthreads();
  int capacity = cap_s;
  int run[NEXP];
  #pragma unroll
  for (int e=0;e<NEXP;e++) run[e]=cnts[t][e];
  for (int u=0;u<16;u++){
    int n = base+u;
    if (!nskv[n]) continue;
    #pragma unroll
    for (int kk=0;kk<2;kk++){
      int e = idx2[n*2+kk];
      int r = run[e]++;
      if (r < capacity){ tok[e*CAPMAX+r]=n; gsel[e*CAPMAX+r]=gate2[n*2+kk]; }
    }
  }
}

// ---------------- out = x1 + (nsk ? 0 : h2), in-place on d_out ----------------
__global__ __launch_bounds__(256) void out_init_kernel(
    const __bf16* __restrict__ h2h, const __bf16* __restrict__ h2l,
    const int* __restrict__ nskv, float* __restrict__ out)
{
  int n = blockIdx.x, t = threadIdx.x;
  float4 a = ((const float4*)(out + (size_t)n*DMODEL))[t];
  if (!nskv[n]){
    bf16x4 h4 = *(const bf16x4*)&h2h[(size_t)n*DMODEL + t*4];
    bf16x4 l4 = *(const bf16x4*)&h2l[(size_t)n*DMODEL + t*4];
    a.x += (float)h4[0]+(float)l4[0]; a.y += (float)h4[1]+(float)l4[1];
    a.z += (float)h4[2]+(float)l4[2]; a.w += (float)h4[3]+(float)l4[3];
  }
  ((float4*)(out + (size_t)n*DMODEL))[t] = a;
}

extern "C" void kernel_launch(void* const* d_in, const int* in_sizes, int n_in,
                              void* d_out, int out_size, void* d_ws, size_t ws_size,
                              hipStream_t stream) {
  const float* x      = (const float*)d_in[0];
  const float* noise  = (const float*)d_in[1];
  const float* ln1_g  = (const float*)d_in[2];
  const float* ln1_b  = (const float*)d_in[3];
  const float* wq     = (const float*)d_in[4];
  const float* wk     = (const float*)d_in[5];
  const float* wv     = (const float*)d_in[6];
  const float* w_proj = (const float*)d_in[7];
  const float* b_proj = (const float*)d_in[8];
  const float* ln2_g  = (const float*)d_in[9];
  const float* ln2_b  = (const float*)d_in[10];
  const float* w_rout = (const float*)d_in[11];
  const float* b_rout = (const float*)d_in[12];
  const float* w_noi  = (const float*)d_in[13];
  const float* b_noi  = (const float*)d_in[14];
  const float* w_skip = (const float*)d_in[15];
  const float* b_skip = (const float*)d_in[16];
  const float* ew1    = (const float*)d_in[17];
  const float* eb1    = (const float*)d_in[18];
  const float* ew2    = (const float*)d_in[19];
  const float* eb2    = (const float*)d_in[20];
  float* out = (float*)d_out;

  char* ws = (char*)d_ws;
  const size_t MB = 1024*1024;
  __bf16* h_hi = (__bf16*)(ws + 0*MB);     // also attn-out hi
  __bf16* h_lo = (__bf16*)(ws + 8*MB);
  __bf16* q_hi = (__bf16*)(ws + 16*MB);    // expert e1T reuses later
  __bf16* q_lo = (__bf16*)(ws + 24*MB);
  __bf16* k_hi = (__bf16*)(ws + 32*MB);    // mid reuses later
  __bf16* k_lo = (__bf16*)(ws + 40*MB);
  __bf16* v_hi = (__bf16*)(ws + 48*MB);
  __bf16* v_lo = (__bf16*)(ws + 56*MB);
  __bf16* wqT_h = (__bf16*)(ws + 64*MB);
  __bf16* wqT_l = (__bf16*)(ws + 66*MB);
  __bf16* wkT_h = (__bf16*)(ws + 68*MB);
  __bf16* wkT_l = (__bf16*)(ws + 70*MB);
  __bf16* wvT_h = (__bf16*)(ws + 72*MB);
  __bf16* wvT_l = (__bf16*)(ws + 74*MB);
  __bf16* wpT_h = (__bf16*)(ws + 76*MB);
  __bf16* wpT_l = (__bf16*)(ws + 78*MB);
  int*   idx2  = (int*)  (ws + 80*MB);
  float* gate2 = (float*)(ws + 80*MB + 32*1024);
  int*   nskv  = (int*)  (ws + 80*MB + 64*1024);
  int*   tokb  = (int*)  (ws + 80*MB + 80*1024);
  float* gselb = (float*)(ws + 80*MB + 112*1024);
  float* zbuf  = (float*)(ws + 80*MB + 144*1024);
  __bf16* vt_hi = (__bf16*)(ws + 81*MB);   // vT [1024][4096] bf16 = 8MB
  __bf16* vt_lo = (__bf16*)(ws + 89*MB);
  __bf16* e1T = q_hi;
  __bf16* e2T = q_lo;
  __bf16* mid = k_hi;
  __bf16* ao_hi = h_hi, *ao_lo = h_lo;

  dim3 blk(256);
  tconv_kernel<true><<<dim3(16,16), blk, 0, stream>>>(wq,     wqT_h, wqT_l, DMODEL, DMODEL);
  tconv_kernel<true><<<dim3(16,16), blk, 0, stream>>>(wk,     wkT_h, wkT_l, DMODEL, DMODEL);
  tconv_kernel<true><<<dim3(16,16), blk, 0, stream>>>(wv,     wvT_h, wvT_l, DMODEL, DMODEL);
  tconv_kernel<true><<<dim3(16,16), blk, 0, stream>>>(w_proj, wpT_h, wpT_l, DMODEL, DMODEL);
  ln_split_kernel<<<TOK_N, blk, 0, stream>>>(x, ln1_g, ln1_b, h_hi, h_lo);
  mgemm<0,true><<<dim3(8,32), blk, 0, stream>>>(h_hi, h_lo, wqT_h, wqT_l, nullptr, nullptr,
      nullptr, q_hi, q_lo, DMODEL, DMODEL, nullptr, nullptr, nullptr);
  mgemm<0,true><<<dim3(8,32), blk, 0, stream>>>(h_hi, h_lo, wkT_h, wkT_l, nullptr, nullptr,
      nullptr, k_hi, k_lo, DMODEL, DMODEL, nullptr, nullptr, nullptr);
  mgemm<0,true><<<dim3(8,32), blk, 0, stream>>>(h_hi, h_lo, wvT_h, wvT_l, nullptr, nullptr,
      nullptr, v_hi, v_lo, DMODEL, DMODEL, nullptr, nullptr, nullptr);
  // v -> vT for PV B-operand
  btrans_kernel<<<dim3(64,16), blk, 0, stream>>>(v_hi, v_lo, vt_hi, vt_lo);
  // MFMA attention -> ao in h region (h dead after QKV)
  attn_mfma_kernel<<<dim3(16,64), blk, 0, stream>>>(q_hi,q_lo,k_hi,k_lo,vt_hi,vt_lo, ao_hi, ao_lo);
  mgemm<1,true><<<dim3(8,32), blk, 0, stream>>>(ao_hi, ao_lo, wpT_h, wpT_l, b_proj, x,
      out, nullptr, nullptr, DMODEL, DMODEL, nullptr, nullptr, nullptr);
  ln_split_kernel<<<TOK_N, blk, 0, stream>>>(out, ln2_g, ln2_b, h_hi, h_lo);
  router_kernel<<<TOK_N, blk, 0, stream>>>(h_hi, h_lo, w_rout, b_rout, w_noi, b_noi,
                                           w_skip, b_skip, noise, idx2, gate2, nskv);
  scan_kernel<<<1, blk, 0, stream>>>(idx2, gate2, nskv, tokb, gselb, zbuf);
  out_init_kernel<<<TOK_N, blk, 0, stream>>>(h_hi, h_lo, nskv, out);
  for (int e=0; e<NEXP; e++){
    tconv_kernel<false><<<dim3(16,64), blk, 0, stream>>>(ew1 + (size_t)e*DMODEL*DFFD,
        e1T, nullptr, DMODEL, DFFD);
    tconv_kernel<false><<<dim3(64,16), blk, 0, stream>>>(ew2 + (size_t)e*DFFD*DMODEL,
        e2T, nullptr, DFFD, DMODEL);
    mgemm<2,false><<<dim3(32,8), blk, 0, stream>>>(h_hi, nullptr, e1T, nullptr,
        eb1 + (size_t)e*DFFD, nullptr, nullptr, mid, nullptr, DFFD, DMODEL,
        tokb + e*CAPMAX, nullptr, (const __bf16*)zbuf);
    mgemm<3,false><<<dim3(8,8), blk, 0, stream>>>(mid, nullptr, e2T, nullptr,
        eb2 + (size_t)e*DMODEL, nullptr, out, nullptr, nullptr, DMODEL, DFFD,
        tokb + e*CAPMAX, gselb + e*CAPMAX, nullptr);
  }
}

// Round 5
// 872.178 us; speedup vs baseline: 4.9206x; 1.7276x over previous
//
#include <hip/hip_runtime.h>
#include <math.h>

#define TOK_N   4096
#define DMODEL  1024
#define NEXP    8
#define DFFD    4096
#define CAPMAX  1024

typedef __bf16 bf16x8 __attribute__((ext_vector_type(8)));
typedef __bf16 bf16x4 __attribute__((ext_vector_type(4)));
typedef float  f32x4  __attribute__((ext_vector_type(4)));

__device__ __forceinline__ f32x4 MFMA16(bf16x8 a, bf16x8 b, f32x4 c){
  return __builtin_amdgcn_mfma_f32_16x16x32_bf16(a, b, c, 0, 0, 0);
}

// async global->LDS, 16B per lane; lds ptr must be wave-uniform base (HW adds lane*16)
__device__ __forceinline__ void gl16(const __bf16* g, __bf16* l){
  __builtin_amdgcn_global_load_lds(
      (const __attribute__((address_space(1))) unsigned int*)g,
      (__attribute__((address_space(3))) unsigned int*)l, 16, 0, 0);
}

__device__ __forceinline__ float wave_sum(float x){
  #pragma unroll
  for (int o=32;o;o>>=1) x += __shfl_down(x,o);
  return x;
}

// ---------------- LayerNorm -> hi/lo bf16 ----------------
__global__ __launch_bounds__(256) void ln_split_kernel(const float* __restrict__ in,
    const float* __restrict__ g, const float* __restrict__ b,
    __bf16* __restrict__ oh, __bf16* __restrict__ ol){
  int n = blockIdx.x, t = threadIdx.x;
  const float4* row = (const float4*)(in + (size_t)n*DMODEL);
  float4 v = row[t];
  float s  = v.x+v.y+v.z+v.w;
  float sq = v.x*v.x+v.y*v.y+v.z*v.z+v.w*v.w;
  s = wave_sum(s); sq = wave_sum(sq);
  __shared__ float r1[4], r2[4];
  __shared__ float mean_s, rstd_s;
  int lane = t & 63, wid = t >> 6;
  if (lane==0){ r1[wid]=s; r2[wid]=sq; }
  __syncthreads();
  if (t==0){
    float a = r1[0]+r1[1]+r1[2]+r1[3];
    float c = r2[0]+r2[1]+r2[2]+r2[3];
    float mean = a*(1.0f/DMODEL);
    float var  = c*(1.0f/DMODEL) - mean*mean;
    mean_s = mean; rstd_s = 1.0f/sqrtf(var + 1e-5f);
  }
  __syncthreads();
  float mean = mean_s, rstd = rstd_s;
  float4 g4 = ((const float4*)g)[t];
  float4 b4 = ((const float4*)b)[t];
  float o_[4];
  o_[0] = (v.x-mean)*rstd*g4.x + b4.x;
  o_[1] = (v.y-mean)*rstd*g4.y + b4.y;
  o_[2] = (v.z-mean)*rstd*g4.z + b4.z;
  o_[3] = (v.w-mean)*rstd*g4.w + b4.w;
  bf16x4 h4, l4;
  #pragma unroll
  for (int i=0;i<4;i++){ __bf16 hb=(__bf16)o_[i]; h4[i]=hb; l4[i]=(__bf16)(o_[i]-(float)hb); }
  *(bf16x4*)&oh[(size_t)n*DMODEL + t*4] = h4;
  *(bf16x4*)&ol[(size_t)n*DMODEL + t*4] = l4;
}

// ---------------- transpose-convert: in[K][N] f32 -> oh/ol [N][K] bf16 ----------------
template<bool SPLIT>
__global__ __launch_bounds__(256) void tconv_kernel(const float* __restrict__ in,
    __bf16* __restrict__ oh, __bf16* __restrict__ ol, int K, int N){
  __shared__ float tile[64][65];
  int k0 = blockIdx.x*64, n0 = blockIdx.y*64;
  int t = threadIdx.x;
  #pragma unroll
  for (int i=0;i<4;i++){
    int row = (t>>4) + i*16;
    int col = (t&15)*4;
    float4 f = *(const float4*)&in[(size_t)(k0+row)*N + n0 + col];
    tile[row][col]=f.x; tile[row][col+1]=f.y; tile[row][col+2]=f.z; tile[row][col+3]=f.w;
  }
  __syncthreads();
  #pragma unroll
  for (int i=0;i<2;i++){
    int c = t + i*256;
    int orow = c>>3, kg = (c&7)*8;
    bf16x8 hv, lv;
    #pragma unroll
    for (int u=0;u<8;u++){
      float x = tile[kg+u][orow];
      __bf16 hb = (__bf16)x;
      hv[u]=hb;
      if constexpr (SPLIT) lv[u]=(__bf16)(x-(float)hb);
    }
    *(bf16x8*)&oh[(size_t)(n0+orow)*K + k0 + kg] = hv;
    if constexpr (SPLIT) *(bf16x8*)&ol[(size_t)(n0+orow)*K + k0 + kg] = lv;
  }
}

// ------- bf16-pair transpose: in rows 4096 x 64-col slice (stride istride, offset icol0)
//         -> out[1024][4096] at row block c0 -------
__global__ __launch_bounds__(256) void btrans_kernel(
    const __bf16* __restrict__ ih, const __bf16* __restrict__ il, int istride, int icol0,
    __bf16* __restrict__ oh, __bf16* __restrict__ ol){
  __shared__ __bf16 th[64][72], tl[64][72];
  int r0 = blockIdx.x*64, c0 = blockIdx.y*64;
  int t = threadIdx.x;
  {
    int r = t>>2, cg = (t&3)*16;
    size_t go = (size_t)(r0+r)*istride + icol0 + c0 + cg;
    *(bf16x8*)&th[r][cg]   = *(const bf16x8*)&ih[go];
    *(bf16x8*)&th[r][cg+8] = *(const bf16x8*)&ih[go+8];
    *(bf16x8*)&tl[r][cg]   = *(const bf16x8*)&il[go];
    *(bf16x8*)&tl[r][cg+8] = *(const bf16x8*)&il[go+8];
  }
  __syncthreads();
  {
    int c = t>>2, rg = (t&3)*16;
    bf16x8 a,b,e,f;
    #pragma unroll
    for (int u=0;u<8;u++){ a[u]=th[rg+u][c]; b[u]=th[rg+8+u][c]; e[u]=tl[rg+u][c]; f[u]=tl[rg+8+u][c]; }
    size_t go = (size_t)(c0+c)*TOK_N + r0 + rg;
    *(bf16x8*)&oh[go]   = a;
    *(bf16x8*)&oh[go+8] = b;
    *(bf16x8*)&ol[go]   = e;
    *(bf16x8*)&ol[go+8] = f;
  }
}

// ---------------- MFMA GEMM, 128x128, BK=32, dbuf-prefetch, global_load_lds ----------------
// A: rows via Astride; B: [N][K] via Bstride (pre-transposed)
// MODE 0: QKV  -> Ch/Cl hi/lo bf16 (N=3072 fused)
// MODE 1: PROJ -> Cf = acc + bias + resid
// MODE 2: UP   -> Ch = bf16(relu(acc+bias)), A rows gathered via tok (invalid -> zbuf)
// MODE 4: DOWNK-> Cf[z] partial (K-chunk z = blockIdx.z), no bias
template<int MODE, bool SPLIT>
__global__ __launch_bounds__(256) void mgemm(
    const __bf16* __restrict__ Ah, const __bf16* __restrict__ Al, int Astride,
    const __bf16* __restrict__ Bh, const __bf16* __restrict__ Bl, int Bstride,
    const float* __restrict__ bias, const float* __restrict__ resid,
    float* __restrict__ Cf, __bf16* __restrict__ Ch, __bf16* __restrict__ Cl,
    int N, int K,
    const int* __restrict__ tok, const __bf16* __restrict__ zbuf)
{
  int m0 = blockIdx.y*128, n0 = blockIdx.x*128;
  if ((MODE==2||MODE==4) && tok[m0] >= TOK_N) return;   // valid slots are a prefix
  if constexpr (MODE==4){
    int kofs = blockIdx.z*K;
    Ah += kofs; Bh += kofs;
    Cf += (size_t)blockIdx.z*CAPMAX*DMODEL;
  }
  __shared__ __align__(16) __bf16 sAh[2*128*32], sBh[2*128*32];
  __shared__ __align__(16) __bf16 sAl[SPLIT?2*128*32:8], sBl[SPLIT?2*128*32:8];
  int t = threadIdx.x, lane = t&63, w = t>>6;
  int wr = w>>1, wc = w&1, fr = lane&15, kb = lane>>4;

  const __bf16* aB[2]; const __bf16* aBl[2]; bool aval[2];
  const __bf16* bB[2]; const __bf16* bBl[2];
  #pragma unroll
  for (int j=0;j<2;j++){
    int c = j*256 + w*64 + lane;
    int row = c>>2, grp = c&3;
    if (MODE==2){
      int token = tok[m0+row];
      if (token < TOK_N){ aB[j] = Ah + (size_t)token*Astride + grp*8; aval[j]=true; }
      else              { aB[j] = zbuf + grp*8;                       aval[j]=false; }
    } else {
      aB[j] = Ah + (size_t)(m0+row)*Astride + grp*8; aval[j]=true;
      if (SPLIT) aBl[j] = Al + (size_t)(m0+row)*Astride + grp*8;
    }
    bB[j] = Bh + (size_t)(n0+row)*Bstride + grp*8;
    if (SPLIT) bBl[j] = Bl + (size_t)(n0+row)*Bstride + grp*8;
  }

  auto stage = [&](int buf, int kt){
    int base = buf*(128*32);
    #pragma unroll
    for (int j=0;j<2;j++){
      int cb8 = base + (j*256 + w*64)*8;
      gl16(aB[j] + (aval[j]? kt : 0), &sAh[cb8]);
      gl16(bB[j] + kt, &sBh[cb8]);
      if constexpr (SPLIT){
        gl16(aBl[j] + kt, &sAl[cb8]);
        gl16(bBl[j] + kt, &sBl[cb8]);
      }
    }
  };

  f32x4 acc[4][4];
  #pragma unroll
  for (int mt=0;mt<4;mt++)
    #pragma unroll
    for (int nt=0;nt<4;nt++) acc[mt][nt] = (f32x4){0.f,0.f,0.f,0.f};

  stage(0, 0);
  __syncthreads();                          // vmcnt(0) drain: tile 0 visible
  int nk = K >> 5;
  for (int ik=0; ik<nk; ik++){
    int cur = ik & 1;
    if (ik+1 < nk) stage(cur^1, (ik+1)<<5); // prefetch next while computing cur
    int fb = cur*(128*32);
    bf16x8 aFh[4], bFh[4];
    #pragma unroll
    for (int mt=0;mt<4;mt++) aFh[mt] = *(const bf16x8*)&sAh[fb + (wr*64+mt*16+fr)*32 + kb*8];
    #pragma unroll
    for (int nt=0;nt<4;nt++) bFh[nt] = *(const bf16x8*)&sBh[fb + (wc*64+nt*16+fr)*32 + kb*8];
    #pragma unroll
    for (int mt=0;mt<4;mt++)
      #pragma unroll
      for (int nt=0;nt<4;nt++)
        acc[mt][nt] = MFMA16(aFh[mt], bFh[nt], acc[mt][nt]);
    if constexpr (SPLIT){
      bf16x8 aFl[4], bFl[4];
      #pragma unroll
      for (int mt=0;mt<4;mt++) aFl[mt] = *(const bf16x8*)&sAl[fb + (wr*64+mt*16+fr)*32 + kb*8];
      #pragma unroll
      for (int nt=0;nt<4;nt++) bFl[nt] = *(const bf16x8*)&sBl[fb + (wc*64+nt*16+fr)*32 + kb*8];
      #pragma unroll
      for (int mt=0;mt<4;mt++)
        #pragma unroll
        for (int nt=0;nt<4;nt++){
          acc[mt][nt] = MFMA16(aFh[mt], bFl[nt], acc[mt][nt]);
          acc[mt][nt] = MFMA16(aFl[mt], bFh[nt], acc[mt][nt]);
        }
    }
    __syncthreads();                        // drains prefetch vmcnt + guards LDS reuse
  }

  #pragma unroll
  for (int mt=0; mt<4; mt++){
    int r0 = m0 + wr*64 + mt*16 + (lane>>4)*4;
    #pragma unroll
    for (int nt=0; nt<4; nt++){
      int col = n0 + wc*64 + nt*16 + fr;
      f32x4 v = acc[mt][nt];
      if constexpr (MODE==0){
        #pragma unroll
        for (int jj=0;jj<4;jj++){
          float val = v[jj];
          __bf16 hb = (__bf16)val;
          size_t idx = (size_t)(r0+jj)*N + col;
          Ch[idx] = hb; Cl[idx] = (__bf16)(val-(float)hb);
        }
      } else if constexpr (MODE==1){
        float bs = bias[col];
        #pragma unroll
        for (int jj=0;jj<4;jj++){
          size_t idx = (size_t)(r0+jj)*N + col;
          Cf[idx] = v[jj] + bs + resid[idx];
        }
      } else if constexpr (MODE==2){
        float bs = bias[col];
        #pragma unroll
        for (int jj=0;jj<4;jj++)
          Ch[(size_t)(r0+jj)*N + col] = (__bf16)fmaxf(v[jj]+bs, 0.f);
      } else {  // MODE 4: raw partial
        #pragma unroll
        for (int jj=0;jj<4;jj++)
          Cf[(size_t)(r0+jj)*N + col] = v[jj];
      }
    }
  }
}

// ------- per-expert scatter-reduce: out[tok[r]] += gsel[r]*(sum_z yk[z][r] + eb2) -------
__global__ __launch_bounds__(256) void sred_kernel(const float* __restrict__ yk,
    const int* __restrict__ tok, const float* __restrict__ gsel,
    const float* __restrict__ eb2, float* __restrict__ out)
{
  int r = blockIdx.x, t = threadIdx.x;
  int token = tok[r];
  if (token >= TOK_N) return;
  float g = gsel[r];
  float4 acc = ((const float4*)eb2)[t];
  #pragma unroll
  for (int z=0;z<4;z++){
    float4 p = ((const float4*)(yk + (size_t)z*CAPMAX*DMODEL + (size_t)r*DMODEL))[t];
    acc.x+=p.x; acc.y+=p.y; acc.z+=p.z; acc.w+=p.w;
  }
  float* op = out + (size_t)token*DMODEL;
  float4 o = ((float4*)op)[t];
  o.x += g*acc.x; o.y += g*acc.y; o.z += g*acc.z; o.w += g*acc.w;
  ((float4*)op)[t] = o;
}

// ---------------- MFMA causal flash attention, split-bf16 (~fp32 exact) ----------------
// qkv fused layout [4096][3072] hi/lo: q at col0=head*64, k at 1024+col0; vT[1024][4096].
__global__ __launch_bounds__(256) void attn_mfma_kernel(
    const __bf16* __restrict__ qkvh, const __bf16* __restrict__ qkvl,
    const __bf16* __restrict__ vth, const __bf16* __restrict__ vtl,
    __bf16* __restrict__ oh, __bf16* __restrict__ ol)
{
  __shared__ __align__(16) __bf16 Qh[64*64], Ql[64*64], Kh[64*64], Kl[64*64], Vh[64*64], Vl[64*64];
  __shared__ __align__(16) __bf16 Ps[2][4][16*64];
  int qt = blockIdx.x, bh = blockIdx.y;
  int batch = bh>>4, head = bh&15;
  int t = threadIdx.x, lane = t&63, w = t>>6;
  int g = lane>>4, fr = lane&15;
  int col0 = head*64;
  size_t qbase = (size_t)(batch*1024 + qt*64);
  const int QKS = 3*DMODEL;
  const float scale = 0.03125f;              // D^-0.5 = 1/32

  #pragma unroll
  for (int j=0;j<2;j++){
    int c = j*256 + t, row = c>>3, seg = c&7;
    size_t go = (qbase+row)*QKS + col0 + ((seg^(row&7))*8);
    int lb = (j*256 + w*64)*8;
    gl16(qkvh+go, &Qh[lb]);
    gl16(qkvl+go, &Ql[lb]);
  }
  __syncthreads();
  bf16x8 aQh[2], aQl[2];
  #pragma unroll
  for (int ks=0; ks<2; ks++){
    int row = w*16 + fr;
    int sc_ = (ks*4 + g) ^ (row&7);
    aQh[ks] = *(const bf16x8*)&Qh[row*64 + sc_*8];
    aQl[ks] = *(const bf16x8*)&Ql[row*64 + sc_*8];
  }

  float m_[4], l_[4];
  f32x4 o_[4];
  #pragma unroll
  for (int j=0;j<4;j++){ m_[j]=-INFINITY; l_[j]=0.f; }
  #pragma unroll
  for (int nt=0;nt<4;nt++) o_[nt]=(f32x4){0.f,0.f,0.f,0.f};

  for (int kt=0; kt<=qt; kt++){
    __syncthreads();
    size_t kbase = (size_t)(batch*1024 + kt*64);
    #pragma unroll
    for (int j=0;j<2;j++){
      int c = j*256 + t, row = c>>3, seg = c&7;
      int lb = (j*256 + w*64)*8;
      size_t gk = (kbase+row)*QKS + 1024 + col0 + ((seg^(row&7))*8);
      gl16(qkvh+gk, &Kh[lb]);
      gl16(qkvl+gk, &Kl[lb]);
      size_t gv = (size_t)(col0+row)*TOK_N + (size_t)(batch*1024 + kt*64) + ((seg^(row&7))*8);
      gl16(vth+gv, &Vh[lb]);
      gl16(vtl+gv, &Vl[lb]);
    }
    __syncthreads();
    f32x4 s[4];
    #pragma unroll
    for (int nt=0;nt<4;nt++) s[nt]=(f32x4){0.f,0.f,0.f,0.f};
    #pragma unroll
    for (int ks=0; ks<2; ks++){
      #pragma unroll
      for (int nt=0; nt<4; nt++){
        int kvr = nt*16 + fr;
        int sc_ = (ks*4 + g) ^ (kvr&7);
        bf16x8 bKh = *(const bf16x8*)&Kh[kvr*64 + sc_*8];
        bf16x8 bKl = *(const bf16x8*)&Kl[kvr*64 + sc_*8];
        s[nt] = MFMA16(aQh[ks], bKh, s[nt]);
        s[nt] = MFMA16(aQh[ks], bKl, s[nt]);
        s[nt] = MFMA16(aQl[ks], bKh, s[nt]);
      }
    }
    bool diag = (kt==qt);
    #pragma unroll
    for (int j=0;j<4;j++){
      int rowg = qt*64 + w*16 + g*4 + j;
      float sv[4];
      #pragma unroll
      for (int nt=0;nt<4;nt++){
        float x = s[nt][j]*scale;
        if (diag && (kt*64 + nt*16 + fr) > rowg) x = -INFINITY;
        sv[nt] = x;
      }
      float mx = fmaxf(fmaxf(sv[0],sv[1]), fmaxf(sv[2],sv[3]));
      #pragma unroll
      for (int o2=1;o2<16;o2<<=1) mx = fmaxf(mx, __shfl_xor(mx,o2));
      float nm = fmaxf(m_[j], mx);
      float scf = __expf(m_[j]-nm);
      float p[4], ps=0.f;
      #pragma unroll
      for (int nt=0;nt<4;nt++){ p[nt]=__expf(sv[nt]-nm); ps+=p[nt]; }
      #pragma unroll
      for (int o2=1;o2<16;o2<<=1) ps += __shfl_xor(ps,o2);
      l_[j] = l_[j]*scf + ps;
      m_[j] = nm;
      o_[0][j]*=scf; o_[1][j]*=scf; o_[2][j]*=scf; o_[3][j]*=scf;
      int prow = g*4 + j;
      #pragma unroll
      for (int nt=0;nt<4;nt++){
        int col = nt*16 + fr;
        int el = prow*64 + (((col>>3)^(prow&7))*8) + (col&7);
        __bf16 phb = (__bf16)p[nt];
        Ps[0][w][el] = phb;
        Ps[1][w][el] = (__bf16)(p[nt]-(float)phb);
      }
    }
    #pragma unroll
    for (int ks=0; ks<2; ks++){
      int pc = (ks*4 + g) ^ (fr&7);
      bf16x8 aPh = *(const bf16x8*)&Ps[0][w][fr*64 + pc*8];
      bf16x8 aPl = *(const bf16x8*)&Ps[1][w][fr*64 + pc*8];
      #pragma unroll
      for (int nt=0; nt<4; nt++){
        int vr = nt*16 + fr;
        int vc = (ks*4 + g) ^ (vr&7);
        bf16x8 bVh = *(const bf16x8*)&Vh[vr*64 + vc*8];
        bf16x8 bVl = *(const bf16x8*)&Vl[vr*64 + vc*8];
        o_[nt] = MFMA16(aPh, bVh, o_[nt]);
        o_[nt] = MFMA16(aPh, bVl, o_[nt]);
        o_[nt] = MFMA16(aPl, bVh, o_[nt]);
      }
    }
  }
  #pragma unroll
  for (int j=0;j<4;j++){
    float inv = 1.0f/l_[j];
    size_t rofs = (qbase + w*16 + g*4 + j)*DMODEL + col0;
    #pragma unroll
    for (int nt=0;nt<4;nt++){
      float val = o_[nt][j]*inv;
      __bf16 hb = (__bf16)val;
      oh[rofs + nt*16 + fr] = hb;
      ol[rofs + nt*16 + fr] = (__bf16)(val-(float)hb);
    }
  }
}

// ---------------- router (h2 from hi/lo) ----------------
__global__ __launch_bounds__(256) void router_kernel(
    const __bf16* __restrict__ h2h, const __bf16* __restrict__ h2l,
    const float* __restrict__ wr, const float* __restrict__ br,
    const float* __restrict__ wn, const float* __restrict__ bn,
    const float* __restrict__ wsk, const float* __restrict__ bsk,
    const float* __restrict__ noise,
    int* __restrict__ idx2, float* __restrict__ gate2, int* __restrict__ nskv)
{
  int n = blockIdx.x, t = threadIdx.x;
  bf16x4 h4 = *(const bf16x4*)&h2h[(size_t)n*DMODEL + t*4];
  bf16x4 l4 = *(const bf16x4*)&h2l[(size_t)n*DMODEL + t*4];
  float hv_[4];
  #pragma unroll
  for (int i=0;i<4;i++) hv_[i] = (float)h4[i] + (float)l4[i];
  int d0 = t*4;
  const float* wrp = wr + (size_t)d0*NEXP;
  const float* wnp = wn + (size_t)d0*NEXP;
  const float* wsp = wsk + d0;
  float vals[17];
  #pragma unroll
  for (int i=0;i<17;i++) vals[i]=0.f;
  #pragma unroll
  for (int i=0;i<4;i++){
    #pragma unroll
    for (int e=0;e<NEXP;e++){
      vals[e]   += hv_[i]*wrp[i*NEXP+e];
      vals[8+e] += hv_[i]*wnp[i*NEXP+e];
    }
    vals[16] += hv_[i]*wsp[i];
  }
  __shared__ float red[4][17];
  int lane = t & 63, wid = t >> 6;
  #pragma unroll
  for (int i=0;i<17;i++){
    float x = wave_sum(vals[i]);
    if (lane==0) red[wid][i] = x;
  }
  __syncthreads();
  if (t==0){
    float noisy[NEXP];
    #pragma unroll
    for (int e=0;e<NEXP;e++){
      float lr = red[0][e]+red[1][e]+red[2][e]+red[3][e] + br[e];
      float pn = red[0][8+e]+red[1][8+e]+red[2][8+e]+red[3][8+e] + bn[e];
      float sp = fmaxf(pn,0.f) + log1pf(expf(-fabsf(pn)));
      noisy[e] = lr + noise[(size_t)n*NEXP + e]*sp;
    }
    float sk = red[0][16]+red[1][16]+red[2][16]+red[3][16] + bsk[0];
    nskv[n] = (sk <= 0.f) ? 1 : 0;
    int i0=0; float v0=noisy[0];
    #pragma unroll
    for (int e=1;e<NEXP;e++) if (noisy[e] > v0){ v0=noisy[e]; i0=e; }
    int i1=-1; float v1=-INFINITY;
    #pragma unroll
    for (int e=0;e<NEXP;e++) if (e!=i0 && noisy[e] > v1){ v1=noisy[e]; i1=e; }
    float tt = expf(v1 - v0);
    idx2[n*2+0]=i0; idx2[n*2+1]=i1;
    gate2[n*2+0]=1.0f/(1.0f+tt); gate2[n*2+1]=tt/(1.0f+tt);
  }
}

// ---------------- capacity scan + slot assignment (+ zero pad buffer) ----------------
__global__ __launch_bounds__(256) void scan_kernel(const int* __restrict__ idx2,
    const float* __restrict__ gate2, const int* __restrict__ nskv,
    int* __restrict__ tok, float* __restrict__ gsel, float* __restrict__ zbuf)
{
  int t = threadIdx.x;
  for (int i=t; i<NEXP*CAPMAX; i+=256){ tok[i]=TOK_N; gsel[i]=0.f; }
  for (int i=t; i<1024; i+=256) zbuf[i]=0.f;     // 4KB zero pad for gather OOB
  __shared__ int cnts[256][NEXP];
  __shared__ int nns_part[256];
  __shared__ int cap_s;
  int loc[NEXP];
  #pragma unroll
  for (int e=0;e<NEXP;e++) loc[e]=0;
  int nn=0, base = t*16;
  for (int u=0;u<16;u++){
    int n = base+u;
    if (nskv[n]){ nn++; loc[idx2[n*2]]++; loc[idx2[n*2+1]]++; }
  }
  #pragma unroll
  for (int e=0;e<NEXP;e++) cnts[t][e]=loc[e];
  nns_part[t]=nn;
  __syncthreads();
  if (t < NEXP){ int run=0; for (int i=0;i<256;i++){ int c=cnts[i][t]; cnts[i][t]=run; run+=c; } }
  if (t == NEXP){ int sum=0; for (int i=0;i<256;i++) sum+=nns_part[i]; cap_s = sum/4; }
  __syncthreads();
  int capacity = cap_s;
  int run[NEXP];
  #pragma unroll
  for (int e=0;e<NEXP;e++) run[e]=cnts[t][e];
  for (int u=0;u<16;u++){
    int n = base+u;
    if (!nskv[n]) continue;
    #pragma unroll
    for (int kk=0;kk<2;kk++){
      int e = idx2[n*2+kk];
      int r = run[e]++;
      if (r < capacity){ tok[e*CAPMAX+r]=n; gsel[e*CAPMAX+r]=gate2[n*2+kk]; }
    }
  }
}

// ---------------- out = x1 + (nsk ? 0 : h2), in-place on d_out ----------------
__global__ __launch_bounds__(256) void out_init_kernel(
    const __bf16* __restrict__ h2h, const __bf16* __restrict__ h2l,
    const int* __restrict__ nskv, float* __restrict__ out)
{
  int n = blockIdx.x, t = threadIdx.x;
  float4 a = ((const float4*)(out + (size_t)n*DMODEL))[t];
  if (!nskv[n]){
    bf16x4 h4 = *(const bf16x4*)&h2h[(size_t)n*DMODEL + t*4];
    bf16x4 l4 = *(const bf16x4*)&h2l[(size_t)n*DMODEL + t*4];
    a.x += (float)h4[0]+(float)l4[0]; a.y += (float)h4[1]+(float)l4[1];
    a.z += (float)h4[2]+(float)l4[2]; a.w += (float)h4[3]+(float)l4[3];
  }
  ((float4*)(out + (size_t)n*DMODEL))[t] = a;
}

extern "C" void kernel_launch(void* const* d_in, const int* in_sizes, int n_in,
                              void* d_out, int out_size, void* d_ws, size_t ws_size,
                              hipStream_t stream) {
  const float* x      = (const float*)d_in[0];
  const float* noise  = (const float*)d_in[1];
  const float* ln1_g  = (const float*)d_in[2];
  const float* ln1_b  = (const float*)d_in[3];
  const float* wq     = (const float*)d_in[4];
  const float* wk     = (const float*)d_in[5];
  const float* wv     = (const float*)d_in[6];
  const float* w_proj = (const float*)d_in[7];
  const float* b_proj = (const float*)d_in[8];
  const float* ln2_g  = (const float*)d_in[9];
  const float* ln2_b  = (const float*)d_in[10];
  const float* w_rout = (const float*)d_in[11];
  const float* b_rout = (const float*)d_in[12];
  const float* w_noi  = (const float*)d_in[13];
  const float* b_noi  = (const float*)d_in[14];
  const float* w_skip = (const float*)d_in[15];
  const float* b_skip = (const float*)d_in[16];
  const float* ew1    = (const float*)d_in[17];
  const float* eb1    = (const float*)d_in[18];
  const float* ew2    = (const float*)d_in[19];
  const float* eb2    = (const float*)d_in[20];
  float* out = (float*)d_out;

  char* ws = (char*)d_ws;
  const size_t MB = 1024*1024;
  __bf16* h_hi   = (__bf16*)(ws + 0*MB);     // LN out; attn out; h2
  __bf16* h_lo   = (__bf16*)(ws + 8*MB);
  __bf16* qkv_hi = (__bf16*)(ws + 16*MB);    // [4096][3072] 24MB
  __bf16* qkv_lo = (__bf16*)(ws + 40*MB);
  __bf16* wqkvT_h= (__bf16*)(ws + 64*MB);    // [3072][1024] 6MB
  __bf16* wqkvT_l= (__bf16*)(ws + 70*MB);
  __bf16* wpT_h  = (__bf16*)(ws + 76*MB);
  __bf16* wpT_l  = (__bf16*)(ws + 78*MB);
  int*   idx2  = (int*)  (ws + 80*MB);
  float* gate2 = (float*)(ws + 80*MB + 32*1024);
  int*   nskv  = (int*)  (ws + 80*MB + 64*1024);
  int*   tokb  = (int*)  (ws + 80*MB + 80*1024);
  float* gselb = (float*)(ws + 80*MB + 112*1024);
  float* zbuf  = (float*)(ws + 80*MB + 144*1024);
  __bf16* vt_hi = (__bf16*)(ws + 81*MB);     // vT [1024][4096] 8MB
  __bf16* vt_lo = (__bf16*)(ws + 89*MB);
  // expert phase reuse (qkv region dead after attention/proj)
  __bf16* e1T = (__bf16*)(ws + 16*MB);       // [4096][1024] 8MB
  __bf16* e2T = (__bf16*)(ws + 24*MB);       // [1024][4096] 8MB
  __bf16* mid = (__bf16*)(ws + 32*MB);       // [1024][4096] 8MB
  float*  yk  = (float*) (ws + 40*MB);       // [4][1024][1024] f32 16MB
  __bf16* ao_hi = h_hi, *ao_lo = h_lo;

  dim3 blk(256);
  // weight transpose-converts (split): wq/wk/wv -> fused wqkvT rows 0/1024/2048
  tconv_kernel<true><<<dim3(16,16), blk, 0, stream>>>(wq, wqkvT_h,              wqkvT_l,              DMODEL, DMODEL);
  tconv_kernel<true><<<dim3(16,16), blk, 0, stream>>>(wk, wqkvT_h+1024*1024,    wqkvT_l+1024*1024,    DMODEL, DMODEL);
  tconv_kernel<true><<<dim3(16,16), blk, 0, stream>>>(wv, wqkvT_h+2*1024*1024,  wqkvT_l+2*1024*1024,  DMODEL, DMODEL);
  tconv_kernel<true><<<dim3(16,16), blk, 0, stream>>>(w_proj, wpT_h, wpT_l, DMODEL, DMODEL);
  ln_split_kernel<<<TOK_N, blk, 0, stream>>>(x, ln1_g, ln1_b, h_hi, h_lo);
  // fused QKV: [4096][1024] @ [1024][3072] -> qkv [4096][3072]
  mgemm<0,true><<<dim3(24,32), blk, 0, stream>>>(h_hi, h_lo, DMODEL, wqkvT_h, wqkvT_l, DMODEL,
      nullptr, nullptr, nullptr, qkv_hi, qkv_lo, 3*DMODEL, DMODEL, nullptr, nullptr);
  // v columns (2048..3071) -> vT
  btrans_kernel<<<dim3(64,16), blk, 0, stream>>>(qkv_hi, qkv_lo, 3*DMODEL, 2048, vt_hi, vt_lo);
  // MFMA attention -> ao in h region
  attn_mfma_kernel<<<dim3(16,64), blk, 0, stream>>>(qkv_hi, qkv_lo, vt_hi, vt_lo, ao_hi, ao_lo);
  // x1 = x + attn@w_proj + b -> d_out
  mgemm<1,true><<<dim3(8,32), blk, 0, stream>>>(ao_hi, ao_lo, DMODEL, wpT_h, wpT_l, DMODEL,
      b_proj, x, out, nullptr, nullptr, DMODEL, DMODEL, nullptr, nullptr);
  ln_split_kernel<<<TOK_N, blk, 0, stream>>>(out, ln2_g, ln2_b, h_hi, h_lo);
  router_kernel<<<TOK_N, blk, 0, stream>>>(h_hi, h_lo, w_rout, b_rout, w_noi, b_noi,
                                           w_skip, b_skip, noise, idx2, gate2, nskv);
  scan_kernel<<<1, blk, 0, stream>>>(idx2, gate2, nskv, tokb, gselb, zbuf);
  out_init_kernel<<<TOK_N, blk, 0, stream>>>(h_hi, h_lo, nskv, out);
  // experts: tconv -> up -> down(split-K z=4) -> scatter-reduce (sequential: deterministic)
  for (int e=0; e<NEXP; e++){
    tconv_kernel<false><<<dim3(16,64), blk, 0, stream>>>(ew1 + (size_t)e*DMODEL*DFFD,
        e1T, nullptr, DMODEL, DFFD);
    tconv_kernel<false><<<dim3(64,16), blk, 0, stream>>>(ew2 + (size_t)e*DFFD*DMODEL,
        e2T, nullptr, DFFD, DMODEL);
    mgemm<2,false><<<dim3(32,8), blk, 0, stream>>>(h_hi, nullptr, DMODEL, e1T, nullptr, DMODEL,
        eb1 + (size_t)e*DFFD, nullptr, nullptr, mid, nullptr, DFFD, DMODEL,
        tokb + e*CAPMAX, (const __bf16*)zbuf);
    mgemm<4,false><<<dim3(8,8,4), blk, 0, stream>>>(mid, nullptr, DFFD, e2T, nullptr, DFFD,
        nullptr, nullptr, yk, nullptr, nullptr, DMODEL, DMODEL,
        tokb + e*CAPMAX, nullptr);
    sred_kernel<<<CAPMAX, blk, 0, stream>>>(yk, tokb + e*CAPMAX, gselb + e*CAPMAX,
        eb2 + (size_t)e*DMODEL, out);
  }
}

// Round 6
// 681.417 us; speedup vs baseline: 6.2981x; 1.2799x over previous
//
#include <hip/hip_runtime.h>
#include <math.h>

#define TOK_N   4096
#define DMODEL  1024
#define NEXP    8
#define DFFD    4096
#define CAPMAX  1024

typedef __bf16 bf16x8 __attribute__((ext_vector_type(8)));
typedef __bf16 bf16x4 __attribute__((ext_vector_type(4)));
typedef float  f32x4  __attribute__((ext_vector_type(4)));

__device__ __forceinline__ f32x4 MFMA16(bf16x8 a, bf16x8 b, f32x4 c){
  return __builtin_amdgcn_mfma_f32_16x16x32_bf16(a, b, c, 0, 0, 0);
}

// async global->LDS, 16B per lane; lds ptr must be wave-uniform base (HW adds lane*16)
__device__ __forceinline__ void gl16(const __bf16* g, __bf16* l){
  __builtin_amdgcn_global_load_lds(
      (const __attribute__((address_space(1))) unsigned int*)g,
      (__attribute__((address_space(3))) unsigned int*)l, 16, 0, 0);
}

__device__ __forceinline__ float wave_sum(float x){
  #pragma unroll
  for (int o=32;o;o>>=1) x += __shfl_down(x,o);
  return x;
}

// ---------------- LayerNorm -> hi/lo bf16 (LN1) ----------------
__global__ __launch_bounds__(256) void ln_split_kernel(const float* __restrict__ in,
    const float* __restrict__ g, const float* __restrict__ b,
    __bf16* __restrict__ oh, __bf16* __restrict__ ol){
  int n = blockIdx.x, t = threadIdx.x;
  const float4* row = (const float4*)(in + (size_t)n*DMODEL);
  float4 v = row[t];
  float s  = v.x+v.y+v.z+v.w;
  float sq = v.x*v.x+v.y*v.y+v.z*v.z+v.w*v.w;
  s = wave_sum(s); sq = wave_sum(sq);
  __shared__ float r1[4], r2[4];
  __shared__ float mean_s, rstd_s;
  int lane = t & 63, wid = t >> 6;
  if (lane==0){ r1[wid]=s; r2[wid]=sq; }
  __syncthreads();
  if (t==0){
    float a = r1[0]+r1[1]+r1[2]+r1[3];
    float c = r2[0]+r2[1]+r2[2]+r2[3];
    float mean = a*(1.0f/DMODEL);
    float var  = c*(1.0f/DMODEL) - mean*mean;
    mean_s = mean; rstd_s = 1.0f/sqrtf(var + 1e-5f);
  }
  __syncthreads();
  float mean = mean_s, rstd = rstd_s;
  float4 g4 = ((const float4*)g)[t];
  float4 b4 = ((const float4*)b)[t];
  float o_[4];
  o_[0] = (v.x-mean)*rstd*g4.x + b4.x;
  o_[1] = (v.y-mean)*rstd*g4.y + b4.y;
  o_[2] = (v.z-mean)*rstd*g4.z + b4.z;
  o_[3] = (v.w-mean)*rstd*g4.w + b4.w;
  bf16x4 h4, l4;
  #pragma unroll
  for (int i=0;i<4;i++){ __bf16 hb=(__bf16)o_[i]; h4[i]=hb; l4[i]=(__bf16)(o_[i]-(float)hb); }
  *(bf16x4*)&oh[(size_t)n*DMODEL + t*4] = h4;
  *(bf16x4*)&ol[(size_t)n*DMODEL + t*4] = l4;
}

// -------- LN2 + router fused: h2 hi/lo out + top-2/gates/skip from exact f32 h2 --------
__global__ __launch_bounds__(256) void ln_router_kernel(const float* __restrict__ in,
    const float* __restrict__ g, const float* __restrict__ b,
    __bf16* __restrict__ oh, __bf16* __restrict__ ol,
    const float* __restrict__ wr, const float* __restrict__ br,
    const float* __restrict__ wn, const float* __restrict__ bn,
    const float* __restrict__ wsk, const float* __restrict__ bsk,
    const float* __restrict__ noise,
    int* __restrict__ idx2, float* __restrict__ gate2, int* __restrict__ nskv)
{
  int n = blockIdx.x, t = threadIdx.x;
  const float4* row = (const float4*)(in + (size_t)n*DMODEL);
  float4 v = row[t];
  float s  = v.x+v.y+v.z+v.w;
  float sq = v.x*v.x+v.y*v.y+v.z*v.z+v.w*v.w;
  s = wave_sum(s); sq = wave_sum(sq);
  __shared__ float r1[4], r2[4];
  __shared__ float mean_s, rstd_s;
  int lane = t & 63, wid = t >> 6;
  if (lane==0){ r1[wid]=s; r2[wid]=sq; }
  __syncthreads();
  if (t==0){
    float a = r1[0]+r1[1]+r1[2]+r1[3];
    float c = r2[0]+r2[1]+r2[2]+r2[3];
    float mean = a*(1.0f/DMODEL);
    float var  = c*(1.0f/DMODEL) - mean*mean;
    mean_s = mean; rstd_s = 1.0f/sqrtf(var + 1e-5f);
  }
  __syncthreads();
  float mean = mean_s, rstd = rstd_s;
  float4 g4 = ((const float4*)g)[t];
  float4 b4 = ((const float4*)b)[t];
  float o_[4];
  o_[0] = (v.x-mean)*rstd*g4.x + b4.x;
  o_[1] = (v.y-mean)*rstd*g4.y + b4.y;
  o_[2] = (v.z-mean)*rstd*g4.z + b4.z;
  o_[3] = (v.w-mean)*rstd*g4.w + b4.w;
  bf16x4 h4, l4;
  #pragma unroll
  for (int i=0;i<4;i++){ __bf16 hb=(__bf16)o_[i]; h4[i]=hb; l4[i]=(__bf16)(o_[i]-(float)hb); }
  *(bf16x4*)&oh[(size_t)n*DMODEL + t*4] = h4;
  *(bf16x4*)&ol[(size_t)n*DMODEL + t*4] = l4;
  // ---- router on exact f32 h2 row ----
  int d0 = t*4;
  const float* wrp = wr + (size_t)d0*NEXP;
  const float* wnp = wn + (size_t)d0*NEXP;
  const float* wsp = wsk + d0;
  float vals[17];
  #pragma unroll
  for (int i=0;i<17;i++) vals[i]=0.f;
  #pragma unroll
  for (int i=0;i<4;i++){
    #pragma unroll
    for (int e=0;e<NEXP;e++){
      vals[e]   += o_[i]*wrp[i*NEXP+e];
      vals[8+e] += o_[i]*wnp[i*NEXP+e];
    }
    vals[16] += o_[i]*wsp[i];
  }
  __shared__ float red[4][17];
  #pragma unroll
  for (int i=0;i<17;i++){
    float x = wave_sum(vals[i]);
    if (lane==0) red[wid][i] = x;
  }
  __syncthreads();
  if (t==0){
    float noisy[NEXP];
    #pragma unroll
    for (int e=0;e<NEXP;e++){
      float lr = red[0][e]+red[1][e]+red[2][e]+red[3][e] + br[e];
      float pn = red[0][8+e]+red[1][8+e]+red[2][8+e]+red[3][8+e] + bn[e];
      float sp = fmaxf(pn,0.f) + log1pf(expf(-fabsf(pn)));
      noisy[e] = lr + noise[(size_t)n*NEXP + e]*sp;
    }
    float sk = red[0][16]+red[1][16]+red[2][16]+red[3][16] + bsk[0];
    nskv[n] = (sk <= 0.f) ? 1 : 0;
    int i0=0; float v0=noisy[0];
    #pragma unroll
    for (int e=1;e<NEXP;e++) if (noisy[e] > v0){ v0=noisy[e]; i0=e; }
    int i1=-1; float v1=-INFINITY;
    #pragma unroll
    for (int e=0;e<NEXP;e++) if (e!=i0 && noisy[e] > v1){ v1=noisy[e]; i1=e; }
    float tt = expf(v1 - v0);
    idx2[n*2+0]=i0; idx2[n*2+1]=i1;
    gate2[n*2+0]=1.0f/(1.0f+tt); gate2[n*2+1]=tt/(1.0f+tt);
  }
}

// ---------------- transpose-convert: in[K][N] f32 -> oh/ol [N][K] bf16 (z-batched) ----------------
template<bool SPLIT>
__global__ __launch_bounds__(256) void tconv_kernel(const float* __restrict__ in,
    __bf16* __restrict__ oh, __bf16* __restrict__ ol, int K, int N,
    size_t zin, size_t zout){
  in += (size_t)blockIdx.z*zin;
  oh += (size_t)blockIdx.z*zout;
  if (SPLIT) ol += (size_t)blockIdx.z*zout;
  __shared__ float tile[64][65];
  int k0 = blockIdx.x*64, n0 = blockIdx.y*64;
  int t = threadIdx.x;
  #pragma unroll
  for (int i=0;i<4;i++){
    int row = (t>>4) + i*16;
    int col = (t&15)*4;
    float4 f = *(const float4*)&in[(size_t)(k0+row)*N + n0 + col];
    tile[row][col]=f.x; tile[row][col+1]=f.y; tile[row][col+2]=f.z; tile[row][col+3]=f.w;
  }
  __syncthreads();
  #pragma unroll
  for (int i=0;i<2;i++){
    int c = t + i*256;
    int orow = c>>3, kg = (c&7)*8;
    bf16x8 hv, lv;
    #pragma unroll
    for (int u=0;u<8;u++){
      float x = tile[kg+u][orow];
      __bf16 hb = (__bf16)x;
      hv[u]=hb;
      if constexpr (SPLIT) lv[u]=(__bf16)(x-(float)hb);
    }
    *(bf16x8*)&oh[(size_t)(n0+orow)*K + k0 + kg] = hv;
    if constexpr (SPLIT) *(bf16x8*)&ol[(size_t)(n0+orow)*K + k0 + kg] = lv;
  }
}

// -------- 4 trunk weights (wq,wk,wv,wproj) -> wAllT rows 0/1024/2048/3072, split --------
__global__ __launch_bounds__(256) void tconv4_kernel(
    const float* __restrict__ s0, const float* __restrict__ s1,
    const float* __restrict__ s2, const float* __restrict__ s3,
    __bf16* __restrict__ dh, __bf16* __restrict__ dl){
  const float* in = blockIdx.z==0 ? s0 : blockIdx.z==1 ? s1 : blockIdx.z==2 ? s2 : s3;
  dh += (size_t)blockIdx.z*DMODEL*DMODEL;
  dl += (size_t)blockIdx.z*DMODEL*DMODEL;
  __shared__ float tile[64][65];
  int k0 = blockIdx.x*64, n0 = blockIdx.y*64;
  int t = threadIdx.x;
  #pragma unroll
  for (int i=0;i<4;i++){
    int row = (t>>4) + i*16;
    int col = (t&15)*4;
    float4 f = *(const float4*)&in[(size_t)(k0+row)*DMODEL + n0 + col];
    tile[row][col]=f.x; tile[row][col+1]=f.y; tile[row][col+2]=f.z; tile[row][col+3]=f.w;
  }
  __syncthreads();
  #pragma unroll
  for (int i=0;i<2;i++){
    int c = t + i*256;
    int orow = c>>3, kg = (c&7)*8;
    bf16x8 hv, lv;
    #pragma unroll
    for (int u=0;u<8;u++){
      float x = tile[kg+u][orow];
      __bf16 hb = (__bf16)x;
      hv[u]=hb; lv[u]=(__bf16)(x-(float)hb);
    }
    *(bf16x8*)&dh[(size_t)(n0+orow)*DMODEL + k0 + kg] = hv;
    *(bf16x8*)&dl[(size_t)(n0+orow)*DMODEL + k0 + kg] = lv;
  }
}

// ------- bf16-pair transpose: qkv v-slice -> vT[1024][4096] -------
__global__ __launch_bounds__(256) void btrans_kernel(
    const __bf16* __restrict__ ih, const __bf16* __restrict__ il, int istride, int icol0,
    __bf16* __restrict__ oh, __bf16* __restrict__ ol){
  __shared__ __bf16 th[64][72], tl[64][72];
  int r0 = blockIdx.x*64, c0 = blockIdx.y*64;
  int t = threadIdx.x;
  {
    int r = t>>2, cg = (t&3)*16;
    size_t go = (size_t)(r0+r)*istride + icol0 + c0 + cg;
    *(bf16x8*)&th[r][cg]   = *(const bf16x8*)&ih[go];
    *(bf16x8*)&th[r][cg+8] = *(const bf16x8*)&ih[go+8];
    *(bf16x8*)&tl[r][cg]   = *(const bf16x8*)&il[go];
    *(bf16x8*)&tl[r][cg+8] = *(const bf16x8*)&il[go+8];
  }
  __syncthreads();
  {
    int c = t>>2, rg = (t&3)*16;
    bf16x8 a,b,e,f;
    #pragma unroll
    for (int u=0;u<8;u++){ a[u]=th[rg+u][c]; b[u]=th[rg+8+u][c]; e[u]=tl[rg+u][c]; f[u]=tl[rg+8+u][c]; }
    size_t go = (size_t)(c0+c)*TOK_N + r0 + rg;
    *(bf16x8*)&oh[go]   = a;
    *(bf16x8*)&oh[go+8] = b;
    *(bf16x8*)&ol[go]   = e;
    *(bf16x8*)&ol[go+8] = f;
  }
}

// ---------------- MFMA GEMM, 128x128, BK=32, dbuf-prefetch, global_load_lds ----------------
// MODE 0: QKV  -> Ch/Cl hi/lo bf16 (N=3072 fused)
// MODE 1: PROJ -> Cf = acc + bias + resid
// MODE 2: UP   -> Ch = bf16(relu(acc+bias)); A gathered via tok; z = expert-in-pair
// MODE 4: DOWN -> Cf partial; z = (pair-expert<<2)|kchunk
template<int MODE, bool SPLIT>
__global__ __launch_bounds__(256) void mgemm(
    const __bf16* __restrict__ Ah, const __bf16* __restrict__ Al, int Astride,
    const __bf16* __restrict__ Bh, const __bf16* __restrict__ Bl, int Bstride,
    const float* __restrict__ bias, const float* __restrict__ resid,
    float* __restrict__ Cf, __bf16* __restrict__ Ch, __bf16* __restrict__ Cl,
    int N, int K,
    const int* __restrict__ tok, const __bf16* __restrict__ zbuf)
{
  if constexpr (MODE==2){
    int z = blockIdx.z;
    Bh  += (size_t)z*((size_t)DFFD*DMODEL);
    bias+= (size_t)z*DFFD;
    Ch  += (size_t)z*((size_t)CAPMAX*DFFD);
    tok += z*CAPMAX;
  }
  if constexpr (MODE==4){
    int pe = blockIdx.z>>2, kz = blockIdx.z&3;
    Ah  += (size_t)pe*((size_t)CAPMAX*DFFD) + kz*1024;
    Bh  += (size_t)pe*((size_t)DMODEL*DFFD) + kz*1024;
    Cf  += (size_t)blockIdx.z*((size_t)CAPMAX*DMODEL);
    tok += pe*CAPMAX;
  }
  int m0 = blockIdx.y*128, n0 = blockIdx.x*128;
  if ((MODE==2||MODE==4) && tok[m0] >= TOK_N) return;   // valid slots are a prefix
  __shared__ __align__(16) __bf16 sAh[2*128*32], sBh[2*128*32];
  __shared__ __align__(16) __bf16 sAl[SPLIT?2*128*32:8], sBl[SPLIT?2*128*32:8];
  int t = threadIdx.x, lane = t&63, w = t>>6;
  int wr = w>>1, wc = w&1, fr = lane&15, kb = lane>>4;

  const __bf16* aB[2]; const __bf16* aBl[2]; bool aval[2];
  const __bf16* bB[2]; const __bf16* bBl[2];
  #pragma unroll
  for (int j=0;j<2;j++){
    int c = j*256 + w*64 + lane;
    int row = c>>2, grp = c&3;
    if (MODE==2){
      int token = tok[m0+row];
      if (token < TOK_N){ aB[j] = Ah + (size_t)token*Astride + grp*8; aval[j]=true; }
      else              { aB[j] = zbuf + grp*8;                       aval[j]=false; }
    } else {
      aB[j] = Ah + (size_t)(m0+row)*Astride + grp*8; aval[j]=true;
      if (SPLIT) aBl[j] = Al + (size_t)(m0+row)*Astride + grp*8;
    }
    bB[j] = Bh + (size_t)(n0+row)*Bstride + grp*8;
    if (SPLIT) bBl[j] = Bl + (size_t)(n0+row)*Bstride + grp*8;
  }

  auto stage = [&](int buf, int kt){
    int base = buf*(128*32);
    #pragma unroll
    for (int j=0;j<2;j++){
      int cb8 = base + (j*256 + w*64)*8;
      gl16(aB[j] + (aval[j]? kt : 0), &sAh[cb8]);
      gl16(bB[j] + kt, &sBh[cb8]);
      if constexpr (SPLIT){
        gl16(aBl[j] + kt, &sAl[cb8]);
        gl16(bBl[j] + kt, &sBl[cb8]);
      }
    }
  };

  f32x4 acc[4][4];
  #pragma unroll
  for (int mt=0;mt<4;mt++)
    #pragma unroll
    for (int nt=0;nt<4;nt++) acc[mt][nt] = (f32x4){0.f,0.f,0.f,0.f};

  stage(0, 0);
  __syncthreads();
  int nk = K >> 5;
  for (int ik=0; ik<nk; ik++){
    int cur = ik & 1;
    if (ik+1 < nk) stage(cur^1, (ik+1)<<5);
    int fb = cur*(128*32);
    bf16x8 aFh[4], bFh[4];
    #pragma unroll
    for (int mt=0;mt<4;mt++) aFh[mt] = *(const bf16x8*)&sAh[fb + (wr*64+mt*16+fr)*32 + kb*8];
    #pragma unroll
    for (int nt=0;nt<4;nt++) bFh[nt] = *(const bf16x8*)&sBh[fb + (wc*64+nt*16+fr)*32 + kb*8];
    #pragma unroll
    for (int mt=0;mt<4;mt++)
      #pragma unroll
      for (int nt=0;nt<4;nt++)
        acc[mt][nt] = MFMA16(aFh[mt], bFh[nt], acc[mt][nt]);
    if constexpr (SPLIT){
      bf16x8 aFl[4], bFl[4];
      #pragma unroll
      for (int mt=0;mt<4;mt++) aFl[mt] = *(const bf16x8*)&sAl[fb + (wr*64+mt*16+fr)*32 + kb*8];
      #pragma unroll
      for (int nt=0;nt<4;nt++) bFl[nt] = *(const bf16x8*)&sBl[fb + (wc*64+nt*16+fr)*32 + kb*8];
      #pragma unroll
      for (int mt=0;mt<4;mt++)
        #pragma unroll
        for (int nt=0;nt<4;nt++){
          acc[mt][nt] = MFMA16(aFh[mt], bFl[nt], acc[mt][nt]);
          acc[mt][nt] = MFMA16(aFl[mt], bFh[nt], acc[mt][nt]);
        }
    }
    __syncthreads();
  }

  #pragma unroll
  for (int mt=0; mt<4; mt++){
    int r0 = m0 + wr*64 + mt*16 + (lane>>4)*4;
    #pragma unroll
    for (int nt=0; nt<4; nt++){
      int col = n0 + wc*64 + nt*16 + fr;
      f32x4 v = acc[mt][nt];
      if constexpr (MODE==0){
        #pragma unroll
        for (int jj=0;jj<4;jj++){
          float val = v[jj];
          __bf16 hb = (__bf16)val;
          size_t idx = (size_t)(r0+jj)*N + col;
          Ch[idx] = hb; Cl[idx] = (__bf16)(val-(float)hb);
        }
      } else if constexpr (MODE==1){
        float bs = bias[col];
        #pragma unroll
        for (int jj=0;jj<4;jj++){
          size_t idx = (size_t)(r0+jj)*N + col;
          Cf[idx] = v[jj] + bs + resid[idx];
        }
      } else if constexpr (MODE==2){
        float bs = bias[col];
        #pragma unroll
        for (int jj=0;jj<4;jj++)
          Ch[(size_t)(r0+jj)*N + col] = (__bf16)fmaxf(v[jj]+bs, 0.f);
      } else {
        #pragma unroll
        for (int jj=0;jj<4;jj++)
          Cf[(size_t)(r0+jj)*N + col] = v[jj];
      }
    }
  }
}

// ------- per-expert scatter-reduce: out[tok[r]] += gsel[r]*(sum_z yk[z][r] + eb2) -------
__global__ __launch_bounds__(256) void sred_kernel(const float* __restrict__ yk,
    const int* __restrict__ tok, const float* __restrict__ gsel,
    const float* __restrict__ eb2, float* __restrict__ out)
{
  int r = blockIdx.x, t = threadIdx.x;
  int token = tok[r];
  if (token >= TOK_N) return;
  float g = gsel[r];
  float4 acc = ((const float4*)eb2)[t];
  #pragma unroll
  for (int z=0;z<4;z++){
    float4 p = ((const float4*)(yk + (size_t)z*CAPMAX*DMODEL + (size_t)r*DMODEL))[t];
    acc.x+=p.x; acc.y+=p.y; acc.z+=p.z; acc.w+=p.w;
  }
  float* op = out + (size_t)token*DMODEL;
  float4 o = ((float4*)op)[t];
  o.x += g*acc.x; o.y += g*acc.y; o.z += g*acc.z; o.w += g*acc.w;
  ((float4*)op)[t] = o;
}

// ---------------- MFMA causal flash attention, split-bf16, dbuf K/V ----------------
__global__ __launch_bounds__(256) void attn_mfma_kernel(
    const __bf16* __restrict__ qkvh, const __bf16* __restrict__ qkvl,
    const __bf16* __restrict__ vth, const __bf16* __restrict__ vtl,
    __bf16* __restrict__ oh, __bf16* __restrict__ ol)
{
  __shared__ __align__(16) __bf16 Kh[2][64*64], Kl[2][64*64], Vh[2][64*64], Vl[2][64*64];
  __shared__ __align__(16) __bf16 Ps[2][4][16*64];
  int qt = blockIdx.x, bh = blockIdx.y;
  int batch = bh>>4, head = bh&15;
  int t = threadIdx.x, lane = t&63, w = t>>6;
  int g = lane>>4, fr = lane&15;
  int col0 = head*64;
  size_t qbase = (size_t)(batch*1024 + qt*64);
  const int QKS = 3*DMODEL;
  const float scale = 0.03125f;              // D^-0.5 = 1/32

  // Q fragments directly from global (no LDS): frag k = ks*32 + g*8 + 0..7
  bf16x8 aQh[2], aQl[2];
  {
    int row = w*16 + fr;
    size_t rb = (qbase+row)*QKS + col0 + g*8;
    aQh[0] = *(const bf16x8*)&qkvh[rb];
    aQh[1] = *(const bf16x8*)&qkvh[rb+32];
    aQl[0] = *(const bf16x8*)&qkvl[rb];
    aQl[1] = *(const bf16x8*)&qkvl[rb+32];
  }

  auto stageKV = [&](int buf, int kt){
    size_t kbase = (size_t)(batch*1024 + kt*64);
    #pragma unroll
    for (int j=0;j<2;j++){
      int c = j*256 + t, row = c>>3, seg = c&7;
      int lb = (j*256 + w*64)*8;
      size_t gk = (kbase+row)*QKS + 1024 + col0 + ((seg^(row&7))*8);
      gl16(qkvh+gk, &Kh[buf][lb]);
      gl16(qkvl+gk, &Kl[buf][lb]);
      size_t gv = (size_t)(col0+row)*TOK_N + kbase + ((seg^(row&7))*8);
      gl16(vth+gv, &Vh[buf][lb]);
      gl16(vtl+gv, &Vl[buf][lb]);
    }
  };

  float m_[4], l_[4];
  f32x4 o_[4];
  #pragma unroll
  for (int j=0;j<4;j++){ m_[j]=-INFINITY; l_[j]=0.f; }
  #pragma unroll
  for (int nt=0;nt<4;nt++) o_[nt]=(f32x4){0.f,0.f,0.f,0.f};

  stageKV(0, 0);
  for (int kt=0; kt<=qt; kt++){
    int cur = kt&1;
    __syncthreads();                         // vmcnt drain: tile kt ready; buf cur^1 free
    if (kt < qt) stageKV(cur^1, kt+1);       // prefetch flies under compute
    // ---- S = Q K^T (split, 3 passes) ----
    f32x4 s[4];
    #pragma unroll
    for (int nt=0;nt<4;nt++) s[nt]=(f32x4){0.f,0.f,0.f,0.f};
    #pragma unroll
    for (int ks=0; ks<2; ks++){
      #pragma unroll
      for (int nt=0; nt<4; nt++){
        int kvr = nt*16 + fr;
        int sc_ = (ks*4 + g) ^ (kvr&7);
        bf16x8 bKh = *(const bf16x8*)&Kh[cur][kvr*64 + sc_*8];
        bf16x8 bKl = *(const bf16x8*)&Kl[cur][kvr*64 + sc_*8];
        s[nt] = MFMA16(aQh[ks], bKh, s[nt]);
        s[nt] = MFMA16(aQh[ks], bKl, s[nt]);
        s[nt] = MFMA16(aQl[ks], bKh, s[nt]);
      }
    }
    // ---- online softmax (wave-parallel; row = g*4+j in 16-lane group) ----
    bool diag = (kt==qt);
    #pragma unroll
    for (int j=0;j<4;j++){
      int rowg = qt*64 + w*16 + g*4 + j;
      float sv[4];
      #pragma unroll
      for (int nt=0;nt<4;nt++){
        float x = s[nt][j]*scale;
        if (diag && (kt*64 + nt*16 + fr) > rowg) x = -INFINITY;
        sv[nt] = x;
      }
      float mx = fmaxf(fmaxf(sv[0],sv[1]), fmaxf(sv[2],sv[3]));
      #pragma unroll
      for (int o2=1;o2<16;o2<<=1) mx = fmaxf(mx, __shfl_xor(mx,o2));
      float nm = fmaxf(m_[j], mx);
      float scf = __expf(m_[j]-nm);
      float p[4], ps=0.f;
      #pragma unroll
      for (int nt=0;nt<4;nt++){ p[nt]=__expf(sv[nt]-nm); ps+=p[nt]; }
      #pragma unroll
      for (int o2=1;o2<16;o2<<=1) ps += __shfl_xor(ps,o2);
      l_[j] = l_[j]*scf + ps;
      m_[j] = nm;
      o_[0][j]*=scf; o_[1][j]*=scf; o_[2][j]*=scf; o_[3][j]*=scf;
      int prow = g*4 + j;
      #pragma unroll
      for (int nt=0;nt<4;nt++){
        int col = nt*16 + fr;
        int el = prow*64 + (((col>>3)^(prow&7))*8) + (col&7);
        __bf16 phb = (__bf16)p[nt];
        Ps[0][w][el] = phb;
        Ps[1][w][el] = (__bf16)(p[nt]-(float)phb);
      }
    }
    // ---- O += P V (split, 3 passes); Ps per-wave -> no barrier needed ----
    #pragma unroll
    for (int ks=0; ks<2; ks++){
      int pc = (ks*4 + g) ^ (fr&7);
      bf16x8 aPh = *(const bf16x8*)&Ps[0][w][fr*64 + pc*8];
      bf16x8 aPl = *(const bf16x8*)&Ps[1][w][fr*64 + pc*8];
      #pragma unroll
      for (int nt=0; nt<4; nt++){
        int vr = nt*16 + fr;
        int vc = (ks*4 + g) ^ (vr&7);
        bf16x8 bVh = *(const bf16x8*)&Vh[cur][vr*64 + vc*8];
        bf16x8 bVl = *(const bf16x8*)&Vl[cur][vr*64 + vc*8];
        o_[nt] = MFMA16(aPh, bVh, o_[nt]);
        o_[nt] = MFMA16(aPh, bVl, o_[nt]);
        o_[nt] = MFMA16(aPl, bVh, o_[nt]);
      }
    }
  }
  #pragma unroll
  for (int j=0;j<4;j++){
    float inv = 1.0f/l_[j];
    size_t rofs = (qbase + w*16 + g*4 + j)*DMODEL + col0;
    #pragma unroll
    for (int nt=0;nt<4;nt++){
      float val = o_[nt][j]*inv;
      __bf16 hb = (__bf16)val;
      oh[rofs + nt*16 + fr] = hb;
      ol[rofs + nt*16 + fr] = (__bf16)(val-(float)hb);
    }
  }
}

// ---------------- capacity scan + slot assignment (+ zero pad buffer) ----------------
__global__ __launch_bounds__(256) void scan_kernel(const int* __restrict__ idx2,
    const float* __restrict__ gate2, const int* __restrict__ nskv,
    int* __restrict__ tok, float* __restrict__ gsel, float* __restrict__ zbuf)
{
  int t = threadIdx.x;
  for (int i=t; i<NEXP*CAPMAX; i+=256){ tok[i]=TOK_N; gsel[i]=0.f; }
  for (int i=t; i<1024; i+=256) zbuf[i]=0.f;
  __shared__ int cnts[256][NEXP];
  __shared__ int nns_part[256];
  __shared__ int cap_s;
  int loc[NEXP];
  #pragma unroll
  for (int e=0;e<NEXP;e++) loc[e]=0;
  int nn=0, base = t*16;
  for (int u=0;u<16;u++){
    int n = base+u;
    if (nskv[n]){ nn++; loc[idx2[n*2]]++; loc[idx2[n*2+1]]++; }
  }
  #pragma unroll
  for (int e=0;e<NEXP;e++) cnts[t][e]=loc[e];
  nns_part[t]=nn;
  __syncthreads();
  if (t < NEXP){ int run=0; for (int i=0;i<256;i++){ int c=cnts[i][t]; cnts[i][t]=run; run+=c; } }
  if (t == NEXP){ int sum=0; for (int i=0;i<256;i++) sum+=nns_part[i]; cap_s = sum/4; }
  __syncthreads();
  int capacity = cap_s;
  int run[NEXP];
  #pragma unroll
  for (int e=0;e<NEXP;e++) run[e]=cnts[t][e];
  for (int u=0;u<16;u++){
    int n = base+u;
    if (!nskv[n]) continue;
    #pragma unroll
    for (int kk=0;kk<2;kk++){
      int e = idx2[n*2+kk];
      int r = run[e]++;
      if (r < capacity){ tok[e*CAPMAX+r]=n; gsel[e*CAPMAX+r]=gate2[n*2+kk]; }
    }
  }
}

// ---------------- out = x1 + (nsk ? 0 : h2), in-place on d_out ----------------
__global__ __launch_bounds__(256) void out_init_kernel(
    const __bf16* __restrict__ h2h, const __bf16* __restrict__ h2l,
    const int* __restrict__ nskv, float* __restrict__ out)
{
  int n = blockIdx.x, t = threadIdx.x;
  float4 a = ((const float4*)(out + (size_t)n*DMODEL))[t];
  if (!nskv[n]){
    bf16x4 h4 = *(const bf16x4*)&h2h[(size_t)n*DMODEL + t*4];
    bf16x4 l4 = *(const bf16x4*)&h2l[(size_t)n*DMODEL + t*4];
    a.x += (float)h4[0]+(float)l4[0]; a.y += (float)h4[1]+(float)l4[1];
    a.z += (float)h4[2]+(float)l4[2]; a.w += (float)h4[3]+(float)l4[3];
  }
  ((float4*)(out + (size_t)n*DMODEL))[t] = a;
}

extern "C" void kernel_launch(void* const* d_in, const int* in_sizes, int n_in,
                              void* d_out, int out_size, void* d_ws, size_t ws_size,
                              hipStream_t stream) {
  const float* x      = (const float*)d_in[0];
  const float* noise  = (const float*)d_in[1];
  const float* ln1_g  = (const float*)d_in[2];
  const float* ln1_b  = (const float*)d_in[3];
  const float* wq     = (const float*)d_in[4];
  const float* wk     = (const float*)d_in[5];
  const float* wv     = (const float*)d_in[6];
  const float* w_proj = (const float*)d_in[7];
  const float* b_proj = (const float*)d_in[8];
  const float* ln2_g  = (const float*)d_in[9];
  const float* ln2_b  = (const float*)d_in[10];
  const float* w_rout = (const float*)d_in[11];
  const float* b_rout = (const float*)d_in[12];
  const float* w_noi  = (const float*)d_in[13];
  const float* b_noi  = (const float*)d_in[14];
  const float* w_skip = (const float*)d_in[15];
  const float* b_skip = (const float*)d_in[16];
  const float* ew1    = (const float*)d_in[17];
  const float* eb1    = (const float*)d_in[18];
  const float* ew2    = (const float*)d_in[19];
  const float* eb2    = (const float*)d_in[20];
  float* out = (float*)d_out;

  char* ws = (char*)d_ws;
  const size_t MB = 1024*1024;
  // ---- trunk phase ----
  __bf16* h_hi   = (__bf16*)(ws + 0*MB);     // LN out; attn out; h2
  __bf16* h_lo   = (__bf16*)(ws + 8*MB);
  __bf16* qkv_hi = (__bf16*)(ws + 16*MB);    // [4096][3072] 24MB
  __bf16* qkv_lo = (__bf16*)(ws + 40*MB);
  __bf16* wAllT_h= (__bf16*)(ws + 64*MB);    // [4096][1024]: q/k/v/proj stacked, 8MB
  __bf16* wAllT_l= (__bf16*)(ws + 72*MB);
  __bf16* vt_hi  = (__bf16*)(ws + 81*MB);    // vT [1024][4096] 8MB
  __bf16* vt_lo  = (__bf16*)(ws + 89*MB);
  // ---- metadata @96MB (inside vt_lo tail; written only after attention) ----
  int*   idx2  = (int*)  (ws + 96*MB);
  float* gate2 = (float*)(ws + 96*MB + 32*1024);
  int*   nskv  = (int*)  (ws + 96*MB + 64*1024);
  int*   tokb  = (int*)  (ws + 96*MB + 80*1024);
  float* gselb = (float*)(ws + 96*MB + 112*1024);
  float* zbuf  = (float*)(ws + 96*MB + 144*1024);
  // ---- expert phase (qkv/wAllT/vt dead) ----
  __bf16* e1T_2 = (__bf16*)(ws + 16*MB);     // [2][4096][1024] 16MB
  __bf16* e2T_2 = (__bf16*)(ws + 32*MB);     // [2][1024][4096] 16MB
  __bf16* mid_2 = (__bf16*)(ws + 48*MB);     // [2][1024][4096] 16MB
  float*  yk    = (float*) (ws + 64*MB);     // [2][4][1024][1024] f32 32MB
  __bf16* ao_hi = h_hi, *ao_lo = h_lo;

  dim3 blk(256);
  // all 4 trunk weights in one dispatch
  tconv4_kernel<<<dim3(16,16,4), blk, 0, stream>>>(wq, wk, wv, w_proj, wAllT_h, wAllT_l);
  ln_split_kernel<<<TOK_N, blk, 0, stream>>>(x, ln1_g, ln1_b, h_hi, h_lo);
  // fused QKV
  mgemm<0,true><<<dim3(24,32), blk, 0, stream>>>(h_hi, h_lo, DMODEL, wAllT_h, wAllT_l, DMODEL,
      nullptr, nullptr, nullptr, qkv_hi, qkv_lo, 3*DMODEL, DMODEL, nullptr, nullptr);
  btrans_kernel<<<dim3(64,16), blk, 0, stream>>>(qkv_hi, qkv_lo, 3*DMODEL, 2048, vt_hi, vt_lo);
  attn_mfma_kernel<<<dim3(16,64), blk, 0, stream>>>(qkv_hi, qkv_lo, vt_hi, vt_lo, ao_hi, ao_lo);
  // x1 = x + attn@w_proj + b -> d_out   (proj weights = wAllT rows 3072..4095)
  mgemm<1,true><<<dim3(8,32), blk, 0, stream>>>(ao_hi, ao_lo, DMODEL,
      wAllT_h + (size_t)3*DMODEL*DMODEL, wAllT_l + (size_t)3*DMODEL*DMODEL, DMODEL,
      b_proj, x, out, nullptr, nullptr, DMODEL, DMODEL, nullptr, nullptr);
  // LN2 + router fused
  ln_router_kernel<<<TOK_N, blk, 0, stream>>>(out, ln2_g, ln2_b, h_hi, h_lo,
      w_rout, b_rout, w_noi, b_noi, w_skip, b_skip, noise, idx2, gate2, nskv);
  scan_kernel<<<1, blk, 0, stream>>>(idx2, gate2, nskv, tokb, gselb, zbuf);
  out_init_kernel<<<TOK_N, blk, 0, stream>>>(h_hi, h_lo, nskv, out);
  // experts in pairs: batched tconv + full-GPU up/down; sred per expert (no scatter race)
  for (int p=0; p<4; p++){
    int e0 = 2*p;
    tconv_kernel<false><<<dim3(16,64,2), blk, 0, stream>>>(ew1 + (size_t)e0*DMODEL*DFFD,
        e1T_2, nullptr, DMODEL, DFFD, (size_t)DMODEL*DFFD, (size_t)DFFD*DMODEL);
    tconv_kernel<false><<<dim3(64,16,2), blk, 0, stream>>>(ew2 + (size_t)e0*DFFD*DMODEL,
        e2T_2, nullptr, DFFD, DMODEL, (size_t)DFFD*DMODEL, (size_t)DMODEL*DFFD);
    mgemm<2,false><<<dim3(32,8,2), blk, 0, stream>>>(h_hi, nullptr, DMODEL,
        e1T_2, nullptr, DMODEL, eb1 + (size_t)e0*DFFD, nullptr,
        nullptr, mid_2, nullptr, DFFD, DMODEL, tokb + e0*CAPMAX, (const __bf16*)zbuf);
    mgemm<4,false><<<dim3(8,8,8), blk, 0, stream>>>(mid_2, nullptr, DFFD,
        e2T_2, nullptr, DFFD, nullptr, nullptr,
        yk, nullptr, nullptr, DMODEL, 1024, tokb + e0*CAPMAX, nullptr);
    for (int pe=0; pe<2; pe++){
      int e = e0 + pe;
      sred_kernel<<<CAPMAX, blk, 0, stream>>>(yk + (size_t)pe*4*CAPMAX*DMODEL,
          tokb + e*CAPMAX, gselb + e*CAPMAX, eb2 + (size_t)e*DMODEL, out);
    }
  }
}

// Round 7
// 624.637 us; speedup vs baseline: 6.8706x; 1.0909x over previous
//
#include <hip/hip_runtime.h>
#include <math.h>

#define TOK_N   4096
#define DMODEL  1024
#define NEXP    8
#define DFFD    4096
#define CAPMAX  1024

typedef __bf16 bf16x8 __attribute__((ext_vector_type(8)));
typedef __bf16 bf16x4 __attribute__((ext_vector_type(4)));
typedef float  f32x4  __attribute__((ext_vector_type(4)));

__device__ __forceinline__ f32x4 MFMA16(bf16x8 a, bf16x8 b, f32x4 c){
  return __builtin_amdgcn_mfma_f32_16x16x32_bf16(a, b, c, 0, 0, 0);
}

__device__ __forceinline__ void gl16(const __bf16* g, __bf16* l){
  __builtin_amdgcn_global_load_lds(
      (const __attribute__((address_space(1))) unsigned int*)g,
      (__attribute__((address_space(3))) unsigned int*)l, 16, 0, 0);
}

__device__ __forceinline__ float wave_sum(float x){
  #pragma unroll
  for (int o=32;o;o>>=1) x += __shfl_down(x,o);
  return x;
}

// -------- prep: tconv4 (wq/wk/wv/wproj -> wAllT split) + LN1 in one dispatch --------
__global__ __launch_bounds__(256) void prep_kernel(
    const float* __restrict__ wq, const float* __restrict__ wk,
    const float* __restrict__ wv, const float* __restrict__ wp,
    __bf16* __restrict__ dh, __bf16* __restrict__ dl,
    const float* __restrict__ x, const float* __restrict__ g1,
    const float* __restrict__ b1, __bf16* __restrict__ hh, __bf16* __restrict__ hl)
{
  __shared__ float smem[64*65];
  int b = blockIdx.x, t = threadIdx.x;
  if (b < 1024){
    int z = b >> 8, rem = b & 255;
    int k0 = (rem >> 4) * 64, n0 = (rem & 15) * 64;
    const float* in = z==0?wq: z==1?wk: z==2?wv: wp;
    __bf16* oh = dh + (size_t)z*DMODEL*DMODEL;
    __bf16* ol = dl + (size_t)z*DMODEL*DMODEL;
    float (*tile)[65] = (float(*)[65])smem;
    #pragma unroll
    for (int i=0;i<4;i++){
      int row = (t>>4) + i*16, col = (t&15)*4;
      float4 f = *(const float4*)&in[(size_t)(k0+row)*DMODEL + n0 + col];
      tile[row][col]=f.x; tile[row][col+1]=f.y; tile[row][col+2]=f.z; tile[row][col+3]=f.w;
    }
    __syncthreads();
    #pragma unroll
    for (int i=0;i<2;i++){
      int c = t + i*256;
      int orow = c>>3, kg = (c&7)*8;
      bf16x8 hv, lv;
      #pragma unroll
      for (int u=0;u<8;u++){
        float xv = tile[kg+u][orow];
        __bf16 hb = (__bf16)xv;
        hv[u]=hb; lv[u]=(__bf16)(xv-(float)hb);
      }
      *(bf16x8*)&oh[(size_t)(n0+orow)*DMODEL + k0 + kg] = hv;
      *(bf16x8*)&ol[(size_t)(n0+orow)*DMODEL + k0 + kg] = lv;
    }
  } else {
    int n = b - 1024;
    float4 v = ((const float4*)(x + (size_t)n*DMODEL))[t];
    float s  = v.x+v.y+v.z+v.w;
    float sq = v.x*v.x+v.y*v.y+v.z*v.z+v.w*v.w;
    s = wave_sum(s); sq = wave_sum(sq);
    int lane = t & 63, wid = t >> 6;
    if (lane==0){ smem[wid]=s; smem[8+wid]=sq; }
    __syncthreads();
    if (t==0){
      float a = smem[0]+smem[1]+smem[2]+smem[3];
      float c = smem[8]+smem[9]+smem[10]+smem[11];
      float mean = a*(1.0f/DMODEL);
      float var  = c*(1.0f/DMODEL) - mean*mean;
      smem[16] = mean; smem[17] = 1.0f/sqrtf(var + 1e-5f);
    }
    __syncthreads();
    float mean = smem[16], rstd = smem[17];
    float4 g4 = ((const float4*)g1)[t];
    float4 b4 = ((const float4*)b1)[t];
    float o_[4];
    o_[0] = (v.x-mean)*rstd*g4.x + b4.x;
    o_[1] = (v.y-mean)*rstd*g4.y + b4.y;
    o_[2] = (v.z-mean)*rstd*g4.z + b4.z;
    o_[3] = (v.w-mean)*rstd*g4.w + b4.w;
    bf16x4 h4, l4;
    #pragma unroll
    for (int i=0;i<4;i++){ __bf16 hb=(__bf16)o_[i]; h4[i]=hb; l4[i]=(__bf16)(o_[i]-(float)hb); }
    *(bf16x4*)&hh[(size_t)n*DMODEL + t*4] = h4;
    *(bf16x4*)&hl[(size_t)n*DMODEL + t*4] = l4;
  }
}

// -------- proj-epilogue + LN2 + router fused --------
__global__ __launch_bounds__(256) void ln_router_kernel(
    const float* __restrict__ p0, const float* __restrict__ p1,
    const float* __restrict__ xres, const float* __restrict__ bproj,
    const float* __restrict__ g, const float* __restrict__ b,
    __bf16* __restrict__ oh, __bf16* __restrict__ ol, float* __restrict__ out_x1,
    const float* __restrict__ wr, const float* __restrict__ br,
    const float* __restrict__ wn, const float* __restrict__ bn,
    const float* __restrict__ wsk, const float* __restrict__ bsk,
    const float* __restrict__ noise,
    int* __restrict__ idx2, float* __restrict__ gate2, int* __restrict__ nskv)
{
  int n = blockIdx.x, t = threadIdx.x;
  size_t ro = (size_t)n*DMODEL/4 + t;
  float4 a  = ((const float4*)p0)[ro];
  float4 a1 = ((const float4*)p1)[ro];
  float4 xr = ((const float4*)xres)[ro];
  float4 bp = ((const float4*)bproj)[t];
  float4 v;
  v.x = a.x+a1.x+xr.x+bp.x; v.y = a.y+a1.y+xr.y+bp.y;
  v.z = a.z+a1.z+xr.z+bp.z; v.w = a.w+a1.w+xr.w+bp.w;
  ((float4*)out_x1)[ro] = v;
  float s  = v.x+v.y+v.z+v.w;
  float sq = v.x*v.x+v.y*v.y+v.z*v.z+v.w*v.w;
  s = wave_sum(s); sq = wave_sum(sq);
  __shared__ float r1[4], r2[4];
  __shared__ float mean_s, rstd_s;
  int lane = t & 63, wid = t >> 6;
  if (lane==0){ r1[wid]=s; r2[wid]=sq; }
  __syncthreads();
  if (t==0){
    float aa = r1[0]+r1[1]+r1[2]+r1[3];
    float cc = r2[0]+r2[1]+r2[2]+r2[3];
    float mean = aa*(1.0f/DMODEL);
    float var  = cc*(1.0f/DMODEL) - mean*mean;
    mean_s = mean; rstd_s = 1.0f/sqrtf(var + 1e-5f);
  }
  __syncthreads();
  float mean = mean_s, rstd = rstd_s;
  float4 g4 = ((const float4*)g)[t];
  float4 b4 = ((const float4*)b)[t];
  float o_[4];
  o_[0] = (v.x-mean)*rstd*g4.x + b4.x;
  o_[1] = (v.y-mean)*rstd*g4.y + b4.y;
  o_[2] = (v.z-mean)*rstd*g4.z + b4.z;
  o_[3] = (v.w-mean)*rstd*g4.w + b4.w;
  bf16x4 h4, l4;
  #pragma unroll
  for (int i=0;i<4;i++){ __bf16 hb=(__bf16)o_[i]; h4[i]=hb; l4[i]=(__bf16)(o_[i]-(float)hb); }
  *(bf16x4*)&oh[(size_t)n*DMODEL + t*4] = h4;
  *(bf16x4*)&ol[(size_t)n*DMODEL + t*4] = l4;
  // router on exact f32 h2
  int d0 = t*4;
  const float* wrp = wr + (size_t)d0*NEXP;
  const float* wnp = wn + (size_t)d0*NEXP;
  const float* wsp = wsk + d0;
  float vals[17];
  #pragma unroll
  for (int i=0;i<17;i++) vals[i]=0.f;
  #pragma unroll
  for (int i=0;i<4;i++){
    #pragma unroll
    for (int e=0;e<NEXP;e++){
      vals[e]   += o_[i]*wrp[i*NEXP+e];
      vals[8+e] += o_[i]*wnp[i*NEXP+e];
    }
    vals[16] += o_[i]*wsp[i];
  }
  __shared__ float red[4][17];
  #pragma unroll
  for (int i=0;i<17;i++){
    float xx = wave_sum(vals[i]);
    if (lane==0) red[wid][i] = xx;
  }
  __syncthreads();
  if (t==0){
    float noisy[NEXP];
    #pragma unroll
    for (int e=0;e<NEXP;e++){
      float lr = red[0][e]+red[1][e]+red[2][e]+red[3][e] + br[e];
      float pn = red[0][8+e]+red[1][8+e]+red[2][8+e]+red[3][8+e] + bn[e];
      float sp = fmaxf(pn,0.f) + log1pf(expf(-fabsf(pn)));
      noisy[e] = lr + noise[(size_t)n*NEXP + e]*sp;
    }
    float sk = red[0][16]+red[1][16]+red[2][16]+red[3][16] + bsk[0];
    nskv[n] = (sk <= 0.f) ? 1 : 0;
    int i0=0; float v0=noisy[0];
    #pragma unroll
    for (int e=1;e<NEXP;e++) if (noisy[e] > v0){ v0=noisy[e]; i0=e; }
    int i1=-1; float v1=-INFINITY;
    #pragma unroll
    for (int e=0;e<NEXP;e++) if (e!=i0 && noisy[e] > v1){ v1=noisy[e]; i1=e; }
    float tt = expf(v1 - v0);
    idx2[n*2+0]=i0; idx2[n*2+1]=i1;
    gate2[n*2+0]=1.0f/(1.0f+tt); gate2[n*2+1]=tt/(1.0f+tt);
  }
}

// -------- pair expert weight transpose-convert: z<2 -> ew1[e0+z], z>=2 -> ew2[e0+z-2] --------
__global__ __launch_bounds__(256) void tconv_pair(
    const float* __restrict__ ew1, const float* __restrict__ ew2,
    __bf16* __restrict__ e1T, __bf16* __restrict__ e2T, int e0)
{
  __shared__ float tile[64][65];
  int z = blockIdx.z, t = threadIdx.x;
  const float* in; __bf16* out; int K, N, k0, n0;
  if (z < 2){
    in = ew1 + (size_t)(e0+z)*DMODEL*DFFD; out = e1T + (size_t)z*DFFD*DMODEL;
    K = DMODEL; N = DFFD; k0 = blockIdx.y*64; n0 = blockIdx.x*64;
  } else {
    in = ew2 + (size_t)(e0+z-2)*DFFD*DMODEL; out = e2T + (size_t)(z-2)*DMODEL*DFFD;
    K = DFFD; N = DMODEL; k0 = blockIdx.x*64; n0 = blockIdx.y*64;
  }
  #pragma unroll
  for (int i=0;i<4;i++){
    int row = (t>>4) + i*16, col = (t&15)*4;
    float4 f = *(const float4*)&in[(size_t)(k0+row)*N + n0 + col];
    tile[row][col]=f.x; tile[row][col+1]=f.y; tile[row][col+2]=f.z; tile[row][col+3]=f.w;
  }
  __syncthreads();
  #pragma unroll
  for (int i=0;i<2;i++){
    int c = t + i*256;
    int orow = c>>3, kg = (c&7)*8;
    bf16x8 hv;
    #pragma unroll
    for (int u=0;u<8;u++) hv[u] = (__bf16)tile[kg+u][orow];
    *(bf16x8*)&out[(size_t)(n0+orow)*K + k0 + kg] = hv;
  }
}

// ------- bf16-pair transpose: qkv v-slice -> vT[1024][4096] -------
__global__ __launch_bounds__(256) void btrans_kernel(
    const __bf16* __restrict__ ih, const __bf16* __restrict__ il, int istride, int icol0,
    __bf16* __restrict__ oh, __bf16* __restrict__ ol){
  __shared__ __bf16 th[64][72], tl[64][72];
  int r0 = blockIdx.x*64, c0 = blockIdx.y*64;
  int t = threadIdx.x;
  {
    int r = t>>2, cg = (t&3)*16;
    size_t go = (size_t)(r0+r)*istride + icol0 + c0 + cg;
    *(bf16x8*)&th[r][cg]   = *(const bf16x8*)&ih[go];
    *(bf16x8*)&th[r][cg+8] = *(const bf16x8*)&ih[go+8];
    *(bf16x8*)&tl[r][cg]   = *(const bf16x8*)&il[go];
    *(bf16x8*)&tl[r][cg+8] = *(const bf16x8*)&il[go+8];
  }
  __syncthreads();
  {
    int c = t>>2, rg = (t&3)*16;
    bf16x8 a,b,e,f;
    #pragma unroll
    for (int u=0;u<8;u++){ a[u]=th[rg+u][c]; b[u]=th[rg+8+u][c]; e[u]=tl[rg+u][c]; f[u]=tl[rg+8+u][c]; }
    size_t go = (size_t)(c0+c)*TOK_N + r0 + rg;
    *(bf16x8*)&oh[go]   = a;
    *(bf16x8*)&oh[go+8] = b;
    *(bf16x8*)&ol[go]   = e;
    *(bf16x8*)&ol[go+8] = f;
  }
}

// ---------------- MFMA GEMM, 128x128, BK=32, dbuf-prefetch, global_load_lds ----------------
// MODE 0: QKV  -> Ch/Cl hi/lo bf16 (N=3072)
// MODE 2: UP   -> Ch = bf16(relu(acc+bias)); A gathered via tok; z = expert-in-pair
// MODE 4: DOWN -> Cf partial; z = (pair-expert<<2)|kchunk
// MODE 5: PROJK-> Cf partial; z = K-chunk of 512
template<int MODE, bool SPLIT>
__global__ __launch_bounds__(256) void mgemm(
    const __bf16* __restrict__ Ah, const __bf16* __restrict__ Al, int Astride,
    const __bf16* __restrict__ Bh, const __bf16* __restrict__ Bl, int Bstride,
    const float* __restrict__ bias,
    float* __restrict__ Cf, __bf16* __restrict__ Ch, __bf16* __restrict__ Cl,
    int N, int K,
    const int* __restrict__ tok, const __bf16* __restrict__ zbuf)
{
  if constexpr (MODE==2){
    int z = blockIdx.z;
    Bh  += (size_t)z*((size_t)DFFD*DMODEL);
    bias+= (size_t)z*DFFD;
    Ch  += (size_t)z*((size_t)CAPMAX*DFFD);
    tok += z*CAPMAX;
  }
  if constexpr (MODE==4){
    int pe = blockIdx.z>>2, kz = blockIdx.z&3;
    Ah  += (size_t)pe*((size_t)CAPMAX*DFFD) + kz*1024;
    Bh  += (size_t)pe*((size_t)DMODEL*DFFD) + kz*1024;
    Cf  += (size_t)blockIdx.z*((size_t)CAPMAX*DMODEL);
    tok += pe*CAPMAX;
  }
  if constexpr (MODE==5){
    int kz = blockIdx.z;
    Ah += kz*512; Al += kz*512; Bh += kz*512; Bl += kz*512;
    Cf += (size_t)kz*((size_t)TOK_N*DMODEL);
  }
  int m0 = blockIdx.y*128, n0 = blockIdx.x*128;
  if ((MODE==2||MODE==4) && tok[m0] >= TOK_N) return;   // valid slots are a prefix
  __shared__ __align__(16) __bf16 sAh[2*128*32], sBh[2*128*32];
  __shared__ __align__(16) __bf16 sAl[SPLIT?2*128*32:8], sBl[SPLIT?2*128*32:8];
  int t = threadIdx.x, lane = t&63, w = t>>6;
  int wr = w>>1, wc = w&1, fr = lane&15, kb = lane>>4;

  const __bf16* aB[2]; const __bf16* aBl[2]; bool aval[2];
  const __bf16* bB[2]; const __bf16* bBl[2];
  #pragma unroll
  for (int j=0;j<2;j++){
    int c = j*256 + w*64 + lane;
    int row = c>>2, grp = c&3;
    if (MODE==2){
      int token = tok[m0+row];
      if (token < TOK_N){ aB[j] = Ah + (size_t)token*Astride + grp*8; aval[j]=true; }
      else              { aB[j] = zbuf + grp*8;                       aval[j]=false; }
    } else {
      aB[j] = Ah + (size_t)(m0+row)*Astride + grp*8; aval[j]=true;
      if (SPLIT) aBl[j] = Al + (size_t)(m0+row)*Astride + grp*8;
    }
    bB[j] = Bh + (size_t)(n0+row)*Bstride + grp*8;
    if (SPLIT) bBl[j] = Bl + (size_t)(n0+row)*Bstride + grp*8;
  }

  auto stage = [&](int buf, int kt){
    int base = buf*(128*32);
    #pragma unroll
    for (int j=0;j<2;j++){
      int cb8 = base + (j*256 + w*64)*8;
      gl16(aB[j] + (aval[j]? kt : 0), &sAh[cb8]);
      gl16(bB[j] + kt, &sBh[cb8]);
      if constexpr (SPLIT){
        gl16(aBl[j] + kt, &sAl[cb8]);
        gl16(bBl[j] + kt, &sBl[cb8]);
      }
    }
  };

  f32x4 acc[4][4];
  #pragma unroll
  for (int mt=0;mt<4;mt++)
    #pragma unroll
    for (int nt=0;nt<4;nt++) acc[mt][nt] = (f32x4){0.f,0.f,0.f,0.f};

  stage(0, 0);
  __syncthreads();
  int nk = K >> 5;
  for (int ik=0; ik<nk; ik++){
    int cur = ik & 1;
    if (ik+1 < nk) stage(cur^1, (ik+1)<<5);
    int fb = cur*(128*32);
    bf16x8 aFh[4], bFh[4];
    #pragma unroll
    for (int mt=0;mt<4;mt++) aFh[mt] = *(const bf16x8*)&sAh[fb + (wr*64+mt*16+fr)*32 + kb*8];
    #pragma unroll
    for (int nt=0;nt<4;nt++) bFh[nt] = *(const bf16x8*)&sBh[fb + (wc*64+nt*16+fr)*32 + kb*8];
    __builtin_amdgcn_s_setprio(1);
    #pragma unroll
    for (int mt=0;mt<4;mt++)
      #pragma unroll
      for (int nt=0;nt<4;nt++)
        acc[mt][nt] = MFMA16(aFh[mt], bFh[nt], acc[mt][nt]);
    __builtin_amdgcn_s_setprio(0);
    if constexpr (SPLIT){
      bf16x8 aFl[4], bFl[4];
      #pragma unroll
      for (int mt=0;mt<4;mt++) aFl[mt] = *(const bf16x8*)&sAl[fb + (wr*64+mt*16+fr)*32 + kb*8];
      #pragma unroll
      for (int nt=0;nt<4;nt++) bFl[nt] = *(const bf16x8*)&sBl[fb + (wc*64+nt*16+fr)*32 + kb*8];
      __builtin_amdgcn_s_setprio(1);
      #pragma unroll
      for (int mt=0;mt<4;mt++)
        #pragma unroll
        for (int nt=0;nt<4;nt++){
          acc[mt][nt] = MFMA16(aFh[mt], bFl[nt], acc[mt][nt]);
          acc[mt][nt] = MFMA16(aFl[mt], bFh[nt], acc[mt][nt]);
        }
      __builtin_amdgcn_s_setprio(0);
    }
    __syncthreads();
  }

  #pragma unroll
  for (int mt=0; mt<4; mt++){
    int r0 = m0 + wr*64 + mt*16 + (lane>>4)*4;
    #pragma unroll
    for (int nt=0; nt<4; nt++){
      int col = n0 + wc*64 + nt*16 + fr;
      f32x4 v = acc[mt][nt];
      if constexpr (MODE==0){
        #pragma unroll
        for (int jj=0;jj<4;jj++){
          float val = v[jj];
          __bf16 hb = (__bf16)val;
          size_t idx = (size_t)(r0+jj)*N + col;
          Ch[idx] = hb; Cl[idx] = (__bf16)(val-(float)hb);
        }
      } else if constexpr (MODE==2){
        float bs = bias[col];
        #pragma unroll
        for (int jj=0;jj<4;jj++)
          Ch[(size_t)(r0+jj)*N + col] = (__bf16)fmaxf(v[jj]+bs, 0.f);
      } else {  // MODE 4 / 5: raw partial
        #pragma unroll
        for (int jj=0;jj<4;jj++)
          Cf[(size_t)(r0+jj)*N + col] = v[jj];
      }
    }
  }
}

// ------- per-expert scatter-reduce: out[tok[r]] += gsel[r]*(sum_z yk[z][r] + eb2) -------
__global__ __launch_bounds__(256) void sred_kernel(const float* __restrict__ yk,
    const int* __restrict__ tok, const float* __restrict__ gsel,
    const float* __restrict__ eb2, float* __restrict__ out)
{
  int r = blockIdx.x, t = threadIdx.x;
  int token = tok[r];
  if (token >= TOK_N) return;
  float g = gsel[r];
  float4 acc = ((const float4*)eb2)[t];
  #pragma unroll
  for (int z=0;z<4;z++){
    float4 p = ((const float4*)(yk + (size_t)z*CAPMAX*DMODEL + (size_t)r*DMODEL))[t];
    acc.x+=p.x; acc.y+=p.y; acc.z+=p.z; acc.w+=p.w;
  }
  float* op = out + (size_t)token*DMODEL;
  float4 o = ((float4*)op)[t];
  o.x += g*acc.x; o.y += g*acc.y; o.z += g*acc.z; o.w += g*acc.w;
  ((float4*)op)[t] = o;
}

// ---------------- MFMA causal flash attention, split-bf16, swapped operands ----------------
// S^T = mfma(K, Q): lane owns q = w*16+fr; s[nt][j] = S[kv=nt*16+g*4+j][q].
// O^T = mfma(V^T, P^T): o_[nt][j] = O^T[d=nt*16+g*4+j][q].
__global__ __launch_bounds__(256) void attn_mfma_kernel(
    const __bf16* __restrict__ qkvh, const __bf16* __restrict__ qkvl,
    const __bf16* __restrict__ vth, const __bf16* __restrict__ vtl,
    __bf16* __restrict__ oh, __bf16* __restrict__ ol)
{
  __shared__ __align__(16) __bf16 Kh[2][64*64], Kl[2][64*64], Vh[2][64*64], Vl[2][64*64];
  __shared__ __align__(16) __bf16 Pt[2][4][16*64];   // per-wave P^T[q=fr][kv], swizzled chunks
  int qt = blockIdx.x, bh = blockIdx.y;
  int batch = bh>>4, head = bh&15;
  int t = threadIdx.x, lane = t&63, w = t>>6;
  int g = lane>>4, fr = lane&15;
  int col0 = head*64;
  size_t qbase = (size_t)(batch*1024 + qt*64);
  const int QKS = 3*DMODEL;
  const float scale = 0.03125f;              // D^-0.5 = 1/32

  // Q as B-operand: lane fr = q col; k = ks*32 + g*8 (registers, no LDS)
  bf16x8 bQh[2], bQl[2];
  {
    int qrow = w*16 + fr;
    size_t rb = (qbase+qrow)*QKS + col0 + g*8;
    bQh[0] = *(const bf16x8*)&qkvh[rb];
    bQh[1] = *(const bf16x8*)&qkvh[rb+32];
    bQl[0] = *(const bf16x8*)&qkvl[rb];
    bQl[1] = *(const bf16x8*)&qkvl[rb+32];
  }

  auto stageKV = [&](int buf, int kt){
    size_t kbase = (size_t)(batch*1024 + kt*64);
    #pragma unroll
    for (int j=0;j<2;j++){
      int c = j*256 + t, row = c>>3, seg = c&7;
      int lb = (j*256 + w*64)*8;
      size_t gk = (kbase+row)*QKS + 1024 + col0 + ((seg^(row&7))*8);
      gl16(qkvh+gk, &Kh[buf][lb]);
      gl16(qkvl+gk, &Kl[buf][lb]);
      size_t gv = (size_t)(col0+row)*TOK_N + kbase + ((seg^(row&7))*8);
      gl16(vth+gv, &Vh[buf][lb]);
      gl16(vtl+gv, &Vl[buf][lb]);
    }
  };

  float m_ = -INFINITY, l_ = 0.f;
  f32x4 o_[4];
  #pragma unroll
  for (int nt=0;nt<4;nt++) o_[nt]=(f32x4){0.f,0.f,0.f,0.f};

  stageKV(0, 0);
  for (int kt=0; kt<=qt; kt++){
    int cur = kt&1;
    __syncthreads();                         // vmcnt drain: tile kt ready
    if (kt < qt) stageKV(cur^1, kt+1);       // prefetch flies under compute
    bool diag = (kt==qt);
    int ntmax = diag ? (w+1) : 4;
    // ---- S^T = K Q^T (split, 3 passes); diag skips nt > w ----
    f32x4 s[4];
    #pragma unroll
    for (int nt=0;nt<4;nt++) s[nt]=(f32x4){0.f,0.f,0.f,0.f};
    __builtin_amdgcn_s_setprio(1);
    #pragma unroll
    for (int ks=0; ks<2; ks++){
      #pragma unroll
      for (int nt=0; nt<4; nt++){
        if (nt < ntmax){
          int kvr = nt*16 + fr;
          int sc_ = (ks*4 + g) ^ (kvr&7);
          bf16x8 aKh = *(const bf16x8*)&Kh[cur][kvr*64 + sc_*8];
          bf16x8 aKl = *(const bf16x8*)&Kl[cur][kvr*64 + sc_*8];
          s[nt] = MFMA16(aKh, bQh[ks], s[nt]);
          s[nt] = MFMA16(aKl, bQh[ks], s[nt]);
          s[nt] = MFMA16(aKh, bQl[ks], s[nt]);
        }
      }
    }
    __builtin_amdgcn_s_setprio(0);
    // ---- online softmax: lane owns q=fr; reduce over 16 in-lane + 2 shfl ----
    float sv[4][4];
    float mx = -INFINITY;
    int ql = w*16 + fr;
    #pragma unroll
    for (int nt=0;nt<4;nt++)
      #pragma unroll
      for (int j=0;j<4;j++){
        float xv = s[nt][j]*scale;
        if (nt >= ntmax || (diag && (nt*16 + g*4 + j) > ql)) xv = -INFINITY;
        sv[nt][j] = xv;
        mx = fmaxf(mx, xv);
      }
    mx = fmaxf(mx, __shfl_xor(mx,16));
    mx = fmaxf(mx, __shfl_xor(mx,32));
    float nm = fmaxf(m_, mx);
    float scf = __expf(m_ - nm);
    float ps = 0.f;
    #pragma unroll
    for (int nt=0;nt<4;nt++)
      #pragma unroll
      for (int j=0;j<4;j++){
        float p = __expf(sv[nt][j] - nm);
        sv[nt][j] = p;
        ps += p;
      }
    ps += __shfl_xor(ps,16);
    ps += __shfl_xor(ps,32);
    l_ = l_*scf + ps;
    m_ = nm;
    #pragma unroll
    for (int nt=0;nt<4;nt++) o_[nt] = o_[nt]*scf;
    // P^T store: b64 per nt per part (swizzled chunk)
    #pragma unroll
    for (int nt=0;nt<4;nt++){
      bf16x4 hv, lv;
      #pragma unroll
      for (int j=0;j<4;j++){
        float pv = sv[nt][j];
        __bf16 hb = (__bf16)pv;
        hv[j] = hb; lv[j] = (__bf16)(pv-(float)hb);
      }
      int el = fr*64 + (((2*nt + (g>>1)) ^ (fr&7))*8) + (g&1)*4;
      *(bf16x4*)&Pt[0][w][el] = hv;
      *(bf16x4*)&Pt[1][w][el] = lv;
    }
    // ---- O^T += V^T P^T (split, 3 passes); diag w<2 skips ks=1 ----
    int ksmax = (diag && w < 2) ? 1 : 2;
    __builtin_amdgcn_s_setprio(1);
    #pragma unroll
    for (int ks=0; ks<2; ks++){
      if (ks < ksmax){
        int pc = (4*ks + g) ^ (fr&7);
        bf16x8 bPh = *(const bf16x8*)&Pt[0][w][fr*64 + pc*8];
        bf16x8 bPl = *(const bf16x8*)&Pt[1][w][fr*64 + pc*8];
        #pragma unroll
        for (int nt=0; nt<4; nt++){
          int vr = nt*16 + fr;
          int vc = (ks*4 + g) ^ (vr&7);
          bf16x8 aVh = *(const bf16x8*)&Vh[cur][vr*64 + vc*8];
          bf16x8 aVl = *(const bf16x8*)&Vl[cur][vr*64 + vc*8];
          o_[nt] = MFMA16(aVh, bPh, o_[nt]);
          o_[nt] = MFMA16(aVl, bPh, o_[nt]);
          o_[nt] = MFMA16(aVh, bPl, o_[nt]);
        }
      }
    }
    __builtin_amdgcn_s_setprio(0);
  }
  // epilogue: O^T -> (via Pt) -> row-major coalesced 16B stores
  float inv = 1.0f/l_;
  #pragma unroll
  for (int nt=0;nt<4;nt++){
    bf16x4 hv, lv;
    #pragma unroll
    for (int j=0;j<4;j++){
      float val = o_[nt][j]*inv;
      __bf16 hb = (__bf16)val;
      hv[j] = hb; lv[j] = (__bf16)(val-(float)hb);
    }
    int el = fr*64 + (((2*nt + (g>>1)) ^ (fr&7))*8) + (g&1)*4;
    *(bf16x4*)&Pt[0][w][el] = hv;
    *(bf16x4*)&Pt[1][w][el] = lv;
  }
  #pragma unroll
  for (int r=0;r<2;r++){
    int c = r*4 + g;
    int el = fr*64 + ((c ^ (fr&7))*8);
    bf16x8 vh = *(const bf16x8*)&Pt[0][w][el];
    bf16x8 vl = *(const bf16x8*)&Pt[1][w][el];
    size_t go = (qbase + w*16 + fr)*DMODEL + col0 + c*8;
    *(bf16x8*)&oh[go] = vh;
    *(bf16x8*)&ol[go] = vl;
  }
}

// ---------------- capacity scan + slot assignment (+ zero pad buffer) ----------------
__global__ __launch_bounds__(256) void scan_kernel(const int* __restrict__ idx2,
    const float* __restrict__ gate2, const int* __restrict__ nskv,
    int* __restrict__ tok, float* __restrict__ gsel, float* __restrict__ zbuf)
{
  int t = threadIdx.x;
  for (int i=t; i<NEXP*CAPMAX; i+=256){ tok[i]=TOK_N; gsel[i]=0.f; }
  for (int i=t; i<1024; i+=256) zbuf[i]=0.f;
  __shared__ int cnts[256][NEXP];
  __shared__ int nns_part[256];
  __shared__ int cap_s;
  int loc[NEXP];
  #pragma unroll
  for (int e=0;e<NEXP;e++) loc[e]=0;
  int nn=0, base = t*16;
  for (int u=0;u<16;u++){
    int n = base+u;
    if (nskv[n]){ nn++; loc[idx2[n*2]]++; loc[idx2[n*2+1]]++; }
  }
  #pragma unroll
  for (int e=0;e<NEXP;e++) cnts[t][e]=loc[e];
  nns_part[t]=nn;
  __syncthreads();
  if (t < NEXP){ int run=0; for (int i=0;i<256;i++){ int c=cnts[i][t]; cnts[i][t]=run; run+=c; } }
  if (t == NEXP){ int sum=0; for (int i=0;i<256;i++) sum+=nns_part[i]; cap_s = sum/4; }
  __syncthreads();
  int capacity = cap_s;
  int run[NEXP];
  #pragma unroll
  for (int e=0;e<NEXP;e++) run[e]=cnts[t][e];
  for (int u=0;u<16;u++){
    int n = base+u;
    if (!nskv[n]) continue;
    #pragma unroll
    for (int kk=0;kk<2;kk++){
      int e = idx2[n*2+kk];
      int r = run[e]++;
      if (r < capacity){ tok[e*CAPMAX+r]=n; gsel[e*CAPMAX+r]=gate2[n*2+kk]; }
    }
  }
}

// ---------------- out = x1 + (nsk ? 0 : h2), in-place on d_out ----------------
__global__ __launch_bounds__(256) void out_init_kernel(
    const __bf16* __restrict__ h2h, const __bf16* __restrict__ h2l,
    const int* __restrict__ nskv, float* __restrict__ out)
{
  int n = blockIdx.x, t = threadIdx.x;
  float4 a = ((const float4*)(out + (size_t)n*DMODEL))[t];
  if (!nskv[n]){
    bf16x4 h4 = *(const bf16x4*)&h2h[(size_t)n*DMODEL + t*4];
    bf16x4 l4 = *(const bf16x4*)&h2l[(size_t)n*DMODEL + t*4];
    a.x += (float)h4[0]+(float)l4[0]; a.y += (float)h4[1]+(float)l4[1];
    a.z += (float)h4[2]+(float)l4[2]; a.w += (float)h4[3]+(float)l4[3];
  }
  ((float4*)(out + (size_t)n*DMODEL))[t] = a;
}

extern "C" void kernel_launch(void* const* d_in, const int* in_sizes, int n_in,
                              void* d_out, int out_size, void* d_ws, size_t ws_size,
                              hipStream_t stream) {
  const float* x      = (const float*)d_in[0];
  const float* noise  = (const float*)d_in[1];
  const float* ln1_g  = (const float*)d_in[2];
  const float* ln1_b  = (const float*)d_in[3];
  const float* wq     = (const float*)d_in[4];
  const float* wk     = (const float*)d_in[5];
  const float* wv     = (const float*)d_in[6];
  const float* w_proj = (const float*)d_in[7];
  const float* b_proj = (const float*)d_in[8];
  const float* ln2_g  = (const float*)d_in[9];
  const float* ln2_b  = (const float*)d_in[10];
  const float* w_rout = (const float*)d_in[11];
  const float* b_rout = (const float*)d_in[12];
  const float* w_noi  = (const float*)d_in[13];
  const float* b_noi  = (const float*)d_in[14];
  const float* w_skip = (const float*)d_in[15];
  const float* b_skip = (const float*)d_in[16];
  const float* ew1    = (const float*)d_in[17];
  const float* eb1    = (const float*)d_in[18];
  const float* ew2    = (const float*)d_in[19];
  const float* eb2    = (const float*)d_in[20];
  float* out = (float*)d_out;

  char* ws = (char*)d_ws;
  const size_t MB = 1024*1024;
  // ---- trunk phase ----
  __bf16* h_hi   = (__bf16*)(ws + 0*MB);     // LN1 out; attn out; h2
  __bf16* h_lo   = (__bf16*)(ws + 8*MB);
  __bf16* qkv_hi = (__bf16*)(ws + 16*MB);    // [4096][3072] 24MB
  __bf16* qkv_lo = (__bf16*)(ws + 40*MB);
  __bf16* wAllT_h= (__bf16*)(ws + 64*MB);    // [4096][1024]: q/k/v/proj stacked, 8MB
  __bf16* wAllT_l= (__bf16*)(ws + 72*MB);
  __bf16* vt_hi  = (__bf16*)(ws + 81*MB);    // vT [1024][4096] 8MB
  __bf16* vt_lo  = (__bf16*)(ws + 89*MB);
  float*  pP     = (float*) (ws + 16*MB);    // proj partials [2][4096][1024] f32 (qkv dead)
  // ---- metadata @96MB (vt_lo tail; written only after attention) ----
  int*   idx2  = (int*)  (ws + 96*MB);
  float* gate2 = (float*)(ws + 96*MB + 32*1024);
  int*   nskv  = (int*)  (ws + 96*MB + 64*1024);
  int*   tokb  = (int*)  (ws + 96*MB + 80*1024);
  float* gselb = (float*)(ws + 96*MB + 112*1024);
  float* zbuf  = (float*)(ws + 96*MB + 144*1024);
  // ---- expert phase (qkv/wAllT/vt/pP dead) ----
  __bf16* e1T_2 = (__bf16*)(ws + 16*MB);     // [2][4096][1024] 16MB
  __bf16* e2T_2 = (__bf16*)(ws + 32*MB);     // [2][1024][4096] 16MB
  __bf16* mid_2 = (__bf16*)(ws + 48*MB);     // [2][1024][4096] 16MB
  float*  yk    = (float*) (ws + 64*MB);     // [2][4][1024][1024] f32 32MB
  __bf16* ao_hi = h_hi, *ao_lo = h_lo;

  dim3 blk(256);
  // tconv4 + LN1 in one dispatch
  prep_kernel<<<5120, blk, 0, stream>>>(wq, wk, wv, w_proj, wAllT_h, wAllT_l,
                                        x, ln1_g, ln1_b, h_hi, h_lo);
  // fused QKV
  mgemm<0,true><<<dim3(24,32), blk, 0, stream>>>(h_hi, h_lo, DMODEL, wAllT_h, wAllT_l, DMODEL,
      nullptr, nullptr, qkv_hi, qkv_lo, 3*DMODEL, DMODEL, nullptr, nullptr);
  btrans_kernel<<<dim3(64,16), blk, 0, stream>>>(qkv_hi, qkv_lo, 3*DMODEL, 2048, vt_hi, vt_lo);
  attn_mfma_kernel<<<dim3(16,64), blk, 0, stream>>>(qkv_hi, qkv_lo, vt_hi, vt_lo, ao_hi, ao_lo);
  // proj split-K partials (qkv region dead now)
  mgemm<5,true><<<dim3(8,32,2), blk, 0, stream>>>(ao_hi, ao_lo, DMODEL,
      wAllT_h + (size_t)3*DMODEL*DMODEL, wAllT_l + (size_t)3*DMODEL*DMODEL, DMODEL,
      nullptr, pP, nullptr, nullptr, DMODEL, 512, nullptr, nullptr);
  // proj epilogue + LN2 + router fused; writes x1 -> d_out
  ln_router_kernel<<<TOK_N, blk, 0, stream>>>(pP, pP + (size_t)TOK_N*DMODEL, x, b_proj,
      ln2_g, ln2_b, h_hi, h_lo, out,
      w_rout, b_rout, w_noi, b_noi, w_skip, b_skip, noise, idx2, gate2, nskv);
  scan_kernel<<<1, blk, 0, stream>>>(idx2, gate2, nskv, tokb, gselb, zbuf);
  out_init_kernel<<<TOK_N, blk, 0, stream>>>(h_hi, h_lo, nskv, out);
  // experts in pairs
  for (int p=0; p<4; p++){
    int e0 = 2*p;
    tconv_pair<<<dim3(64,16,4), blk, 0, stream>>>(ew1, ew2, e1T_2, e2T_2, e0);
    mgemm<2,false><<<dim3(32,8,2), blk, 0, stream>>>(h_hi, nullptr, DMODEL,
        e1T_2, nullptr, DMODEL, eb1 + (size_t)e0*DFFD,
        nullptr, mid_2, nullptr, DFFD, DMODEL, tokb + e0*CAPMAX, (const __bf16*)zbuf);
    mgemm<4,false><<<dim3(8,8,8), blk, 0, stream>>>(mid_2, nullptr, DFFD,
        e2T_2, nullptr, DFFD, nullptr,
        yk, nullptr, nullptr, DMODEL, 1024, tokb + e0*CAPMAX, nullptr);
    for (int pe=0; pe<2; pe++){
      int e = e0 + pe;
      sred_kernel<<<CAPMAX, blk, 0, stream>>>(yk + (size_t)pe*4*CAPMAX*DMODEL,
          tokb + e*CAPMAX, gselb + e*CAPMAX, eb2 + (size_t)e*DMODEL, out);
    }
  }
}

// Round 8
// 614.698 us; speedup vs baseline: 6.9817x; 1.0162x over previous
//
#include <hip/hip_runtime.h>
#include <math.h>

#define TOK_N   4096
#define DMODEL  1024
#define NEXP    8
#define DFFD    4096
#define CAPMAX  1024

typedef __bf16 bf16x8 __attribute__((ext_vector_type(8)));
typedef __bf16 bf16x4 __attribute__((ext_vector_type(4)));
typedef float  f32x4  __attribute__((ext_vector_type(4)));

__device__ __forceinline__ f32x4 MFMA16(bf16x8 a, bf16x8 b, f32x4 c){
  return __builtin_amdgcn_mfma_f32_16x16x32_bf16(a, b, c, 0, 0, 0);
}

__device__ __forceinline__ void gl16(const __bf16* g, __bf16* l){
  __builtin_amdgcn_global_load_lds(
      (const __attribute__((address_space(1))) unsigned int*)g,
      (__attribute__((address_space(3))) unsigned int*)l, 16, 0, 0);
}

__device__ __forceinline__ float wave_sum(float x){
  #pragma unroll
  for (int o=32;o;o>>=1) x += __shfl_down(x,o);
  return x;
}

// -------- prep: tconv4 (wq/wk/wv/wproj -> wAllT split) + LN1 in one dispatch --------
__global__ __launch_bounds__(256) void prep_kernel(
    const float* __restrict__ wq, const float* __restrict__ wk,
    const float* __restrict__ wv, const float* __restrict__ wp,
    __bf16* __restrict__ dh, __bf16* __restrict__ dl,
    const float* __restrict__ x, const float* __restrict__ g1,
    const float* __restrict__ b1, __bf16* __restrict__ hh, __bf16* __restrict__ hl)
{
  __shared__ float smem[64*65];
  int b = blockIdx.x, t = threadIdx.x;
  if (b < 1024){
    int z = b >> 8, rem = b & 255;
    int k0 = (rem >> 4) * 64, n0 = (rem & 15) * 64;
    const float* in = z==0?wq: z==1?wk: z==2?wv: wp;
    __bf16* oh = dh + (size_t)z*DMODEL*DMODEL;
    __bf16* ol = dl + (size_t)z*DMODEL*DMODEL;
    float (*tile)[65] = (float(*)[65])smem;
    #pragma unroll
    for (int i=0;i<4;i++){
      int row = (t>>4) + i*16, col = (t&15)*4;
      float4 f = *(const float4*)&in[(size_t)(k0+row)*DMODEL + n0 + col];
      tile[row][col]=f.x; tile[row][col+1]=f.y; tile[row][col+2]=f.z; tile[row][col+3]=f.w;
    }
    __syncthreads();
    #pragma unroll
    for (int i=0;i<2;i++){
      int c = t + i*256;
      int orow = c>>3, kg = (c&7)*8;
      bf16x8 hv, lv;
      #pragma unroll
      for (int u=0;u<8;u++){
        float xv = tile[kg+u][orow];
        __bf16 hb = (__bf16)xv;
        hv[u]=hb; lv[u]=(__bf16)(xv-(float)hb);
      }
      *(bf16x8*)&oh[(size_t)(n0+orow)*DMODEL + k0 + kg] = hv;
      *(bf16x8*)&ol[(size_t)(n0+orow)*DMODEL + k0 + kg] = lv;
    }
  } else {
    int n = b - 1024;
    float4 v = ((const float4*)(x + (size_t)n*DMODEL))[t];
    float s  = v.x+v.y+v.z+v.w;
    float sq = v.x*v.x+v.y*v.y+v.z*v.z+v.w*v.w;
    s = wave_sum(s); sq = wave_sum(sq);
    int lane = t & 63, wid = t >> 6;
    if (lane==0){ smem[wid]=s; smem[8+wid]=sq; }
    __syncthreads();
    if (t==0){
      float a = smem[0]+smem[1]+smem[2]+smem[3];
      float c = smem[8]+smem[9]+smem[10]+smem[11];
      float mean = a*(1.0f/DMODEL);
      float var  = c*(1.0f/DMODEL) - mean*mean;
      smem[16] = mean; smem[17] = 1.0f/sqrtf(var + 1e-5f);
    }
    __syncthreads();
    float mean = smem[16], rstd = smem[17];
    float4 g4 = ((const float4*)g1)[t];
    float4 b4 = ((const float4*)b1)[t];
    float o_[4];
    o_[0] = (v.x-mean)*rstd*g4.x + b4.x;
    o_[1] = (v.y-mean)*rstd*g4.y + b4.y;
    o_[2] = (v.z-mean)*rstd*g4.z + b4.z;
    o_[3] = (v.w-mean)*rstd*g4.w + b4.w;
    bf16x4 h4, l4;
    #pragma unroll
    for (int i=0;i<4;i++){ __bf16 hb=(__bf16)o_[i]; h4[i]=hb; l4[i]=(__bf16)(o_[i]-(float)hb); }
    *(bf16x4*)&hh[(size_t)n*DMODEL + t*4] = h4;
    *(bf16x4*)&hl[(size_t)n*DMODEL + t*4] = l4;
  }
}

// -------- proj-epilogue + LN2 + router fused --------
__global__ __launch_bounds__(256) void ln_router_kernel(
    const float* __restrict__ p0, const float* __restrict__ p1,
    const float* __restrict__ xres, const float* __restrict__ bproj,
    const float* __restrict__ g, const float* __restrict__ b,
    __bf16* __restrict__ oh, __bf16* __restrict__ ol, float* __restrict__ out_x1,
    const float* __restrict__ wr, const float* __restrict__ br,
    const float* __restrict__ wn, const float* __restrict__ bn,
    const float* __restrict__ wsk, const float* __restrict__ bsk,
    const float* __restrict__ noise,
    int* __restrict__ idx2, float* __restrict__ gate2, int* __restrict__ nskv)
{
  int n = blockIdx.x, t = threadIdx.x;
  size_t ro = (size_t)n*DMODEL/4 + t;
  float4 a  = ((const float4*)p0)[ro];
  float4 a1 = ((const float4*)p1)[ro];
  float4 xr = ((const float4*)xres)[ro];
  float4 bp = ((const float4*)bproj)[t];
  float4 v;
  v.x = a.x+a1.x+xr.x+bp.x; v.y = a.y+a1.y+xr.y+bp.y;
  v.z = a.z+a1.z+xr.z+bp.z; v.w = a.w+a1.w+xr.w+bp.w;
  ((float4*)out_x1)[ro] = v;
  float s  = v.x+v.y+v.z+v.w;
  float sq = v.x*v.x+v.y*v.y+v.z*v.z+v.w*v.w;
  s = wave_sum(s); sq = wave_sum(sq);
  __shared__ float r1[4], r2[4];
  __shared__ float mean_s, rstd_s;
  int lane = t & 63, wid = t >> 6;
  if (lane==0){ r1[wid]=s; r2[wid]=sq; }
  __syncthreads();
  if (t==0){
    float aa = r1[0]+r1[1]+r1[2]+r1[3];
    float cc = r2[0]+r2[1]+r2[2]+r2[3];
    float mean = aa*(1.0f/DMODEL);
    float var  = cc*(1.0f/DMODEL) - mean*mean;
    mean_s = mean; rstd_s = 1.0f/sqrtf(var + 1e-5f);
  }
  __syncthreads();
  float mean = mean_s, rstd = rstd_s;
  float4 g4 = ((const float4*)g)[t];
  float4 b4 = ((const float4*)b)[t];
  float o_[4];
  o_[0] = (v.x-mean)*rstd*g4.x + b4.x;
  o_[1] = (v.y-mean)*rstd*g4.y + b4.y;
  o_[2] = (v.z-mean)*rstd*g4.z + b4.z;
  o_[3] = (v.w-mean)*rstd*g4.w + b4.w;
  bf16x4 h4, l4;
  #pragma unroll
  for (int i=0;i<4;i++){ __bf16 hb=(__bf16)o_[i]; h4[i]=hb; l4[i]=(__bf16)(o_[i]-(float)hb); }
  *(bf16x4*)&oh[(size_t)n*DMODEL + t*4] = h4;
  *(bf16x4*)&ol[(size_t)n*DMODEL + t*4] = l4;
  // router on exact f32 h2
  int d0 = t*4;
  const float* wrp = wr + (size_t)d0*NEXP;
  const float* wnp = wn + (size_t)d0*NEXP;
  const float* wsp = wsk + d0;
  float vals[17];
  #pragma unroll
  for (int i=0;i<17;i++) vals[i]=0.f;
  #pragma unroll
  for (int i=0;i<4;i++){
    #pragma unroll
    for (int e=0;e<NEXP;e++){
      vals[e]   += o_[i]*wrp[i*NEXP+e];
      vals[8+e] += o_[i]*wnp[i*NEXP+e];
    }
    vals[16] += o_[i]*wsp[i];
  }
  __shared__ float red[4][17];
  #pragma unroll
  for (int i=0;i<17;i++){
    float xx = wave_sum(vals[i]);
    if (lane==0) red[wid][i] = xx;
  }
  __syncthreads();
  if (t==0){
    float noisy[NEXP];
    #pragma unroll
    for (int e=0;e<NEXP;e++){
      float lr = red[0][e]+red[1][e]+red[2][e]+red[3][e] + br[e];
      float pn = red[0][8+e]+red[1][8+e]+red[2][8+e]+red[3][8+e] + bn[e];
      float sp = fmaxf(pn,0.f) + log1pf(expf(-fabsf(pn)));
      noisy[e] = lr + noise[(size_t)n*NEXP + e]*sp;
    }
    float sk = red[0][16]+red[1][16]+red[2][16]+red[3][16] + bsk[0];
    nskv[n] = (sk <= 0.f) ? 1 : 0;
    int i0=0; float v0=noisy[0];
    #pragma unroll
    for (int e=1;e<NEXP;e++) if (noisy[e] > v0){ v0=noisy[e]; i0=e; }
    int i1=-1; float v1=-INFINITY;
    #pragma unroll
    for (int e=0;e<NEXP;e++) if (e!=i0 && noisy[e] > v1){ v1=noisy[e]; i1=e; }
    float tt = expf(v1 - v0);
    idx2[n*2+0]=i0; idx2[n*2+1]=i1;
    gate2[n*2+0]=1.0f/(1.0f+tt); gate2[n*2+1]=tt/(1.0f+tt);
  }
}

// -------- pair expert weight transpose-convert: z<2 -> ew1[e0+z], z>=2 -> ew2[e0+z-2] --------
__global__ __launch_bounds__(256) void tconv_pair(
    const float* __restrict__ ew1, const float* __restrict__ ew2,
    __bf16* __restrict__ e1T, __bf16* __restrict__ e2T, int e0)
{
  __shared__ float tile[64][65];
  int z = blockIdx.z, t = threadIdx.x;
  const float* in; __bf16* out; int K, N, k0, n0;
  if (z < 2){
    in = ew1 + (size_t)(e0+z)*DMODEL*DFFD; out = e1T + (size_t)z*DFFD*DMODEL;
    K = DMODEL; N = DFFD; k0 = blockIdx.y*64; n0 = blockIdx.x*64;
  } else {
    in = ew2 + (size_t)(e0+z-2)*DFFD*DMODEL; out = e2T + (size_t)(z-2)*DMODEL*DFFD;
    K = DFFD; N = DMODEL; k0 = blockIdx.x*64; n0 = blockIdx.y*64;
  }
  #pragma unroll
  for (int i=0;i<4;i++){
    int row = (t>>4) + i*16, col = (t&15)*4;
    float4 f = *(const float4*)&in[(size_t)(k0+row)*N + n0 + col];
    tile[row][col]=f.x; tile[row][col+1]=f.y; tile[row][col+2]=f.z; tile[row][col+3]=f.w;
  }
  __syncthreads();
  #pragma unroll
  for (int i=0;i<2;i++){
    int c = t + i*256;
    int orow = c>>3, kg = (c&7)*8;
    bf16x8 hv;
    #pragma unroll
    for (int u=0;u<8;u++) hv[u] = (__bf16)tile[kg+u][orow];
    *(bf16x8*)&out[(size_t)(n0+orow)*K + k0 + kg] = hv;
  }
}

// ------- bf16-pair transpose: qkv v-slice -> vT[1024][4096] -------
__global__ __launch_bounds__(256) void btrans_kernel(
    const __bf16* __restrict__ ih, const __bf16* __restrict__ il, int istride, int icol0,
    __bf16* __restrict__ oh, __bf16* __restrict__ ol){
  __shared__ __bf16 th[64][72], tl[64][72];
  int r0 = blockIdx.x*64, c0 = blockIdx.y*64;
  int t = threadIdx.x;
  {
    int r = t>>2, cg = (t&3)*16;
    size_t go = (size_t)(r0+r)*istride + icol0 + c0 + cg;
    *(bf16x8*)&th[r][cg]   = *(const bf16x8*)&ih[go];
    *(bf16x8*)&th[r][cg+8] = *(const bf16x8*)&ih[go+8];
    *(bf16x8*)&tl[r][cg]   = *(const bf16x8*)&il[go];
    *(bf16x8*)&tl[r][cg+8] = *(const bf16x8*)&il[go+8];
  }
  __syncthreads();
  {
    int c = t>>2, rg = (t&3)*16;
    bf16x8 a,b,e,f;
    #pragma unroll
    for (int u=0;u<8;u++){ a[u]=th[rg+u][c]; b[u]=th[rg+8+u][c]; e[u]=tl[rg+u][c]; f[u]=tl[rg+8+u][c]; }
    size_t go = (size_t)(c0+c)*TOK_N + r0 + rg;
    *(bf16x8*)&oh[go]   = a;
    *(bf16x8*)&oh[go+8] = b;
    *(bf16x8*)&ol[go]   = e;
    *(bf16x8*)&ol[go+8] = f;
  }
}

// ---------------- MFMA GEMM, 128x128, BK=32, dbuf-prefetch, global_load_lds ----------------
// LDS chunk swizzle (T2/G21): linear LDS dest; source chunk sg = grp^((row>>1)&3);
// read slot = kb^((fr>>1)&3). Banks spread 2->8 groups: 8-way conflict -> free 2-way.
// MODE 0: QKV  -> Ch/Cl hi/lo bf16 (N=3072)
// MODE 2: UP   -> Ch = bf16(relu(acc+bias)); A gathered via tok; z = expert-in-pair
// MODE 4: DOWN -> Cf partial; z = (pair-expert<<2)|kchunk
// MODE 5: PROJK-> Cf partial; z = K-chunk of 512
template<int MODE, bool SPLIT>
__global__ __launch_bounds__(256) void mgemm(
    const __bf16* __restrict__ Ah, const __bf16* __restrict__ Al, int Astride,
    const __bf16* __restrict__ Bh, const __bf16* __restrict__ Bl, int Bstride,
    const float* __restrict__ bias,
    float* __restrict__ Cf, __bf16* __restrict__ Ch, __bf16* __restrict__ Cl,
    int N, int K,
    const int* __restrict__ tok, const __bf16* __restrict__ zbuf)
{
  if constexpr (MODE==2){
    int z = blockIdx.z;
    Bh  += (size_t)z*((size_t)DFFD*DMODEL);
    bias+= (size_t)z*DFFD;
    Ch  += (size_t)z*((size_t)CAPMAX*DFFD);
    tok += z*CAPMAX;
  }
  if constexpr (MODE==4){
    int pe = blockIdx.z>>2, kz = blockIdx.z&3;
    Ah  += (size_t)pe*((size_t)CAPMAX*DFFD) + kz*1024;
    Bh  += (size_t)pe*((size_t)DMODEL*DFFD) + kz*1024;
    Cf  += (size_t)blockIdx.z*((size_t)CAPMAX*DMODEL);
    tok += pe*CAPMAX;
  }
  if constexpr (MODE==5){
    int kz = blockIdx.z;
    Ah += kz*512; Al += kz*512; Bh += kz*512; Bl += kz*512;
    Cf += (size_t)kz*((size_t)TOK_N*DMODEL);
  }
  int m0 = blockIdx.y*128, n0 = blockIdx.x*128;
  if ((MODE==2||MODE==4) && tok[m0] >= TOK_N) return;   // valid slots are a prefix
  __shared__ __align__(16) __bf16 sAh[2*128*32], sBh[2*128*32];
  __shared__ __align__(16) __bf16 sAl[SPLIT?2*128*32:8], sBl[SPLIT?2*128*32:8];
  int t = threadIdx.x, lane = t&63, w = t>>6;
  int wr = w>>1, wc = w&1, fr = lane&15, kb = lane>>4;

  const __bf16* aB[2]; const __bf16* aBl[2]; bool aval[2];
  const __bf16* bB[2]; const __bf16* bBl[2];
  #pragma unroll
  for (int j=0;j<2;j++){
    int c = j*256 + w*64 + lane;
    int row = c>>2, grp = c&3;
    int sg = grp ^ ((row>>1)&3);           // pre-swizzled source chunk (involution)
    if (MODE==2){
      int token = tok[m0+row];
      if (token < TOK_N){ aB[j] = Ah + (size_t)token*Astride + sg*8; aval[j]=true; }
      else              { aB[j] = zbuf + sg*8;                       aval[j]=false; }
    } else {
      aB[j] = Ah + (size_t)(m0+row)*Astride + sg*8; aval[j]=true;
      if (SPLIT) aBl[j] = Al + (size_t)(m0+row)*Astride + sg*8;
    }
    bB[j] = Bh + (size_t)(n0+row)*Bstride + sg*8;
    if (SPLIT) bBl[j] = Bl + (size_t)(n0+row)*Bstride + sg*8;
  }

  auto stage = [&](int buf, int kt){
    int base = buf*(128*32);
    #pragma unroll
    for (int j=0;j<2;j++){
      int cb8 = base + (j*256 + w*64)*8;
      gl16(aB[j] + (aval[j]? kt : 0), &sAh[cb8]);
      gl16(bB[j] + kt, &sBh[cb8]);
      if constexpr (SPLIT){
        gl16(aBl[j] + kt, &sAl[cb8]);
        gl16(bBl[j] + kt, &sBl[cb8]);
      }
    }
  };

  f32x4 acc[4][4];
  #pragma unroll
  for (int mt=0;mt<4;mt++)
    #pragma unroll
    for (int nt=0;nt<4;nt++) acc[mt][nt] = (f32x4){0.f,0.f,0.f,0.f};

  stage(0, 0);
  __syncthreads();
  int nk = K >> 5;
  int xk = (kb ^ ((fr>>1)&3))*8;           // swizzled read slot within row
  for (int ik=0; ik<nk; ik++){
    int cur = ik & 1;
    if (ik+1 < nk) stage(cur^1, (ik+1)<<5);
    int fb = cur*(128*32);
    bf16x8 aFh[4], bFh[4];
    #pragma unroll
    for (int mt=0;mt<4;mt++) aFh[mt] = *(const bf16x8*)&sAh[fb + (wr*64+mt*16+fr)*32 + xk];
    #pragma unroll
    for (int nt=0;nt<4;nt++) bFh[nt] = *(const bf16x8*)&sBh[fb + (wc*64+nt*16+fr)*32 + xk];
    __builtin_amdgcn_s_setprio(1);
    #pragma unroll
    for (int mt=0;mt<4;mt++)
      #pragma unroll
      for (int nt=0;nt<4;nt++)
        acc[mt][nt] = MFMA16(aFh[mt], bFh[nt], acc[mt][nt]);
    __builtin_amdgcn_s_setprio(0);
    if constexpr (SPLIT){
      bf16x8 aFl[4], bFl[4];
      #pragma unroll
      for (int mt=0;mt<4;mt++) aFl[mt] = *(const bf16x8*)&sAl[fb + (wr*64+mt*16+fr)*32 + xk];
      #pragma unroll
      for (int nt=0;nt<4;nt++) bFl[nt] = *(const bf16x8*)&sBl[fb + (wc*64+nt*16+fr)*32 + xk];
      __builtin_amdgcn_s_setprio(1);
      #pragma unroll
      for (int mt=0;mt<4;mt++)
        #pragma unroll
        for (int nt=0;nt<4;nt++){
          acc[mt][nt] = MFMA16(aFh[mt], bFl[nt], acc[mt][nt]);
          acc[mt][nt] = MFMA16(aFl[mt], bFh[nt], acc[mt][nt]);
        }
      __builtin_amdgcn_s_setprio(0);
    }
    __syncthreads();
  }

  #pragma unroll
  for (int mt=0; mt<4; mt++){
    int r0 = m0 + wr*64 + mt*16 + (lane>>4)*4;
    #pragma unroll
    for (int nt=0; nt<4; nt++){
      int col = n0 + wc*64 + nt*16 + fr;
      f32x4 v = acc[mt][nt];
      if constexpr (MODE==0){
        #pragma unroll
        for (int jj=0;jj<4;jj++){
          float val = v[jj];
          __bf16 hb = (__bf16)val;
          size_t idx = (size_t)(r0+jj)*N + col;
          Ch[idx] = hb; Cl[idx] = (__bf16)(val-(float)hb);
        }
      } else if constexpr (MODE==2){
        float bs = bias[col];
        #pragma unroll
        for (int jj=0;jj<4;jj++)
          Ch[(size_t)(r0+jj)*N + col] = (__bf16)fmaxf(v[jj]+bs, 0.f);
      } else {  // MODE 4 / 5: raw partial
        #pragma unroll
        for (int jj=0;jj<4;jj++)
          Cf[(size_t)(r0+jj)*N + col] = v[jj];
      }
    }
  }
}

// ------- per-expert scatter-reduce: out[tok[r]] += gsel[r]*(sum_z yk[z][r] + eb2) -------
__global__ __launch_bounds__(256) void sred_kernel(const float* __restrict__ yk,
    const int* __restrict__ tok, const float* __restrict__ gsel,
    const float* __restrict__ eb2, float* __restrict__ out)
{
  int r = blockIdx.x, t = threadIdx.x;
  int token = tok[r];
  if (token >= TOK_N) return;
  float g = gsel[r];
  float4 acc = ((const float4*)eb2)[t];
  #pragma unroll
  for (int z=0;z<4;z++){
    float4 p = ((const float4*)(yk + (size_t)z*CAPMAX*DMODEL + (size_t)r*DMODEL))[t];
    acc.x+=p.x; acc.y+=p.y; acc.z+=p.z; acc.w+=p.w;
  }
  float* op = out + (size_t)token*DMODEL;
  float4 o = ((float4*)op)[t];
  o.x += g*acc.x; o.y += g*acc.y; o.z += g*acc.z; o.w += g*acc.w;
  ((float4*)op)[t] = o;
}

// ---------------- MFMA causal flash attention, split-bf16, swapped operands ----------------
__global__ __launch_bounds__(256) void attn_mfma_kernel(
    const __bf16* __restrict__ qkvh, const __bf16* __restrict__ qkvl,
    const __bf16* __restrict__ vth, const __bf16* __restrict__ vtl,
    __bf16* __restrict__ oh, __bf16* __restrict__ ol)
{
  __shared__ __align__(16) __bf16 Kh[2][64*64], Kl[2][64*64], Vh[2][64*64], Vl[2][64*64];
  __shared__ __align__(16) __bf16 Pt[2][4][16*64];   // per-wave P^T[q=fr][kv], swizzled chunks
  int qt = blockIdx.x, bh = blockIdx.y;
  int batch = bh>>4, head = bh&15;
  int t = threadIdx.x, lane = t&63, w = t>>6;
  int g = lane>>4, fr = lane&15;
  int col0 = head*64;
  size_t qbase = (size_t)(batch*1024 + qt*64);
  const int QKS = 3*DMODEL;
  const float scale = 0.03125f;              // D^-0.5 = 1/32

  bf16x8 bQh[2], bQl[2];
  {
    int qrow = w*16 + fr;
    size_t rb = (qbase+qrow)*QKS + col0 + g*8;
    bQh[0] = *(const bf16x8*)&qkvh[rb];
    bQh[1] = *(const bf16x8*)&qkvh[rb+32];
    bQl[0] = *(const bf16x8*)&qkvl[rb];
    bQl[1] = *(const bf16x8*)&qkvl[rb+32];
  }

  auto stageKV = [&](int buf, int kt){
    size_t kbase = (size_t)(batch*1024 + kt*64);
    #pragma unroll
    for (int j=0;j<2;j++){
      int c = j*256 + t, row = c>>3, seg = c&7;
      int lb = (j*256 + w*64)*8;
      size_t gk = (kbase+row)*QKS + 1024 + col0 + ((seg^(row&7))*8);
      gl16(qkvh+gk, &Kh[buf][lb]);
      gl16(qkvl+gk, &Kl[buf][lb]);
      size_t gv = (size_t)(col0+row)*TOK_N + kbase + ((seg^(row&7))*8);
      gl16(vth+gv, &Vh[buf][lb]);
      gl16(vtl+gv, &Vl[buf][lb]);
    }
  };

  float m_ = -INFINITY, l_ = 0.f;
  f32x4 o_[4];
  #pragma unroll
  for (int nt=0;nt<4;nt++) o_[nt]=(f32x4){0.f,0.f,0.f,0.f};

  stageKV(0, 0);
  for (int kt=0; kt<=qt; kt++){
    int cur = kt&1;
    __syncthreads();                         // vmcnt drain: tile kt ready
    if (kt < qt) stageKV(cur^1, kt+1);       // prefetch flies under compute
    bool diag = (kt==qt);
    int ntmax = diag ? (w+1) : 4;
    f32x4 s[4];
    #pragma unroll
    for (int nt=0;nt<4;nt++) s[nt]=(f32x4){0.f,0.f,0.f,0.f};
    __builtin_amdgcn_s_setprio(1);
    #pragma unroll
    for (int ks=0; ks<2; ks++){
      #pragma unroll
      for (int nt=0; nt<4; nt++){
        if (nt < ntmax){
          int kvr = nt*16 + fr;
          int sc_ = (ks*4 + g) ^ (kvr&7);
          bf16x8 aKh = *(const bf16x8*)&Kh[cur][kvr*64 + sc_*8];
          bf16x8 aKl = *(const bf16x8*)&Kl[cur][kvr*64 + sc_*8];
          s[nt] = MFMA16(aKh, bQh[ks], s[nt]);
          s[nt] = MFMA16(aKl, bQh[ks], s[nt]);
          s[nt] = MFMA16(aKh, bQl[ks], s[nt]);
        }
      }
    }
    __builtin_amdgcn_s_setprio(0);
    float sv[4][4];
    float mx = -INFINITY;
    int ql = w*16 + fr;
    #pragma unroll
    for (int nt=0;nt<4;nt++)
      #pragma unroll
      for (int j=0;j<4;j++){
        float xv = s[nt][j]*scale;
        if (nt >= ntmax || (diag && (nt*16 + g*4 + j) > ql)) xv = -INFINITY;
        sv[nt][j] = xv;
        mx = fmaxf(mx, xv);
      }
    mx = fmaxf(mx, __shfl_xor(mx,16));
    mx = fmaxf(mx, __shfl_xor(mx,32));
    float nm = fmaxf(m_, mx);
    float scf = __expf(m_ - nm);
    float ps = 0.f;
    #pragma unroll
    for (int nt=0;nt<4;nt++)
      #pragma unroll
      for (int j=0;j<4;j++){
        float p = __expf(sv[nt][j] - nm);
        sv[nt][j] = p;
        ps += p;
      }
    ps += __shfl_xor(ps,16);
    ps += __shfl_xor(ps,32);
    l_ = l_*scf + ps;
    m_ = nm;
    #pragma unroll
    for (int nt=0;nt<4;nt++) o_[nt] = o_[nt]*scf;
    #pragma unroll
    for (int nt=0;nt<4;nt++){
      bf16x4 hv, lv;
      #pragma unroll
      for (int j=0;j<4;j++){
        float pv = sv[nt][j];
        __bf16 hb = (__bf16)pv;
        hv[j] = hb; lv[j] = (__bf16)(pv-(float)hb);
      }
      int el = fr*64 + (((2*nt + (g>>1)) ^ (fr&7))*8) + (g&1)*4;
      *(bf16x4*)&Pt[0][w][el] = hv;
      *(bf16x4*)&Pt[1][w][el] = lv;
    }
    int ksmax = (diag && w < 2) ? 1 : 2;
    __builtin_amdgcn_s_setprio(1);
    #pragma unroll
    for (int ks=0; ks<2; ks++){
      if (ks < ksmax){
        int pc = (4*ks + g) ^ (fr&7);
        bf16x8 bPh = *(const bf16x8*)&Pt[0][w][fr*64 + pc*8];
        bf16x8 bPl = *(const bf16x8*)&Pt[1][w][fr*64 + pc*8];
        #pragma unroll
        for (int nt=0; nt<4; nt++){
          int vr = nt*16 + fr;
          int vc = (ks*4 + g) ^ (vr&7);
          bf16x8 aVh = *(const bf16x8*)&Vh[cur][vr*64 + vc*8];
          bf16x8 aVl = *(const bf16x8*)&Vl[cur][vr*64 + vc*8];
          o_[nt] = MFMA16(aVh, bPh, o_[nt]);
          o_[nt] = MFMA16(aVl, bPh, o_[nt]);
          o_[nt] = MFMA16(aVh, bPl, o_[nt]);
        }
      }
    }
    __builtin_amdgcn_s_setprio(0);
  }
  float inv = 1.0f/l_;
  #pragma unroll
  for (int nt=0;nt<4;nt++){
    bf16x4 hv, lv;
    #pragma unroll
    for (int j=0;j<4;j++){
      float val = o_[nt][j]*inv;
      __bf16 hb = (__bf16)val;
      hv[j] = hb; lv[j] = (__bf16)(val-(float)hb);
    }
    int el = fr*64 + (((2*nt + (g>>1)) ^ (fr&7))*8) + (g&1)*4;
    *(bf16x4*)&Pt[0][w][el] = hv;
    *(bf16x4*)&Pt[1][w][el] = lv;
  }
  #pragma unroll
  for (int r=0;r<2;r++){
    int c = r*4 + g;
    int el = fr*64 + ((c ^ (fr&7))*8);
    bf16x8 vh = *(const bf16x8*)&Pt[0][w][el];
    bf16x8 vl = *(const bf16x8*)&Pt[1][w][el];
    size_t go = (qbase + w*16 + fr)*DMODEL + col0 + c*8;
    *(bf16x8*)&oh[go] = vh;
    *(bf16x8*)&ol[go] = vl;
  }
}

// ---------------- capacity scan + slot assignment (+ zero pad buffer) ----------------
__global__ __launch_bounds__(256) void scan_kernel(const int* __restrict__ idx2,
    const float* __restrict__ gate2, const int* __restrict__ nskv,
    int* __restrict__ tok, float* __restrict__ gsel, float* __restrict__ zbuf)
{
  int t = threadIdx.x;
  for (int i=t; i<NEXP*CAPMAX; i+=256){ tok[i]=TOK_N; gsel[i]=0.f; }
  for (int i=t; i<1024; i+=256) zbuf[i]=0.f;
  __shared__ int cnts[256][NEXP];
  __shared__ int nns_part[256];
  __shared__ int cap_s;
  int loc[NEXP];
  #pragma unroll
  for (int e=0;e<NEXP;e++) loc[e]=0;
  int nn=0, base = t*16;
  for (int u=0;u<16;u++){
    int n = base+u;
    if (nskv[n]){ nn++; loc[idx2[n*2]]++; loc[idx2[n*2+1]]++; }
  }
  #pragma unroll
  for (int e=0;e<NEXP;e++) cnts[t][e]=loc[e];
  nns_part[t]=nn;
  __syncthreads();
  if (t < NEXP){ int run=0; for (int i=0;i<256;i++){ int c=cnts[i][t]; cnts[i][t]=run; run+=c; } }
  if (t == NEXP){ int sum=0; for (int i=0;i<256;i++) sum+=nns_part[i]; cap_s = sum/4; }
  __syncthreads();
  int capacity = cap_s;
  int run[NEXP];
  #pragma unroll
  for (int e=0;e<NEXP;e++) run[e]=cnts[t][e];
  for (int u=0;u<16;u++){
    int n = base+u;
    if (!nskv[n]) continue;
    #pragma unroll
    for (int kk=0;kk<2;kk++){
      int e = idx2[n*2+kk];
      int r = run[e]++;
      if (r < capacity){ tok[e*CAPMAX+r]=n; gsel[e*CAPMAX+r]=gate2[n*2+kk]; }
    }
  }
}

// ---------------- out = x1 + (nsk ? 0 : h2), in-place on d_out ----------------
__global__ __launch_bounds__(256) void out_init_kernel(
    const __bf16* __restrict__ h2h, const __bf16* __restrict__ h2l,
    const int* __restrict__ nskv, float* __restrict__ out)
{
  int n = blockIdx.x, t = threadIdx.x;
  float4 a = ((const float4*)(out + (size_t)n*DMODEL))[t];
  if (!nskv[n]){
    bf16x4 h4 = *(const bf16x4*)&h2h[(size_t)n*DMODEL + t*4];
    bf16x4 l4 = *(const bf16x4*)&h2l[(size_t)n*DMODEL + t*4];
    a.x += (float)h4[0]+(float)l4[0]; a.y += (float)h4[1]+(float)l4[1];
    a.z += (float)h4[2]+(float)l4[2]; a.w += (float)h4[3]+(float)l4[3];
  }
  ((float4*)(out + (size_t)n*DMODEL))[t] = a;
}

extern "C" void kernel_launch(void* const* d_in, const int* in_sizes, int n_in,
                              void* d_out, int out_size, void* d_ws, size_t ws_size,
                              hipStream_t stream) {
  const float* x      = (const float*)d_in[0];
  const float* noise  = (const float*)d_in[1];
  const float* ln1_g  = (const float*)d_in[2];
  const float* ln1_b  = (const float*)d_in[3];
  const float* wq     = (const float*)d_in[4];
  const float* wk     = (const float*)d_in[5];
  const float* wv     = (const float*)d_in[6];
  const float* w_proj = (const float*)d_in[7];
  const float* b_proj = (const float*)d_in[8];
  const float* ln2_g  = (const float*)d_in[9];
  const float* ln2_b  = (const float*)d_in[10];
  const float* w_rout = (const float*)d_in[11];
  const float* b_rout = (const float*)d_in[12];
  const float* w_noi  = (const float*)d_in[13];
  const float* b_noi  = (const float*)d_in[14];
  const float* w_skip = (const float*)d_in[15];
  const float* b_skip = (const float*)d_in[16];
  const float* ew1    = (const float*)d_in[17];
  const float* eb1    = (const float*)d_in[18];
  const float* ew2    = (const float*)d_in[19];
  const float* eb2    = (const float*)d_in[20];
  float* out = (float*)d_out;

  char* ws = (char*)d_ws;
  const size_t MB = 1024*1024;
  // ---- trunk phase ----
  __bf16* h_hi   = (__bf16*)(ws + 0*MB);     // LN1 out; attn out; h2
  __bf16* h_lo   = (__bf16*)(ws + 8*MB);
  __bf16* qkv_hi = (__bf16*)(ws + 16*MB);    // [4096][3072] 24MB
  __bf16* qkv_lo = (__bf16*)(ws + 40*MB);
  __bf16* wAllT_h= (__bf16*)(ws + 64*MB);    // [4096][1024]: q/k/v/proj stacked, 8MB
  __bf16* wAllT_l= (__bf16*)(ws + 72*MB);
  __bf16* vt_hi  = (__bf16*)(ws + 81*MB);    // vT [1024][4096] 8MB
  __bf16* vt_lo  = (__bf16*)(ws + 89*MB);
  float*  pP     = (float*) (ws + 16*MB);    // proj partials [2][4096][1024] f32 (qkv dead)
  // ---- metadata @96MB (vt_lo tail; written only after attention) ----
  int*   idx2  = (int*)  (ws + 96*MB);
  float* gate2 = (float*)(ws + 96*MB + 32*1024);
  int*   nskv  = (int*)  (ws + 96*MB + 64*1024);
  int*   tokb  = (int*)  (ws + 96*MB + 80*1024);
  float* gselb = (float*)(ws + 96*MB + 112*1024);
  float* zbuf  = (float*)(ws + 96*MB + 144*1024);
  // ---- expert phase (qkv/wAllT/vt/pP dead) ----
  __bf16* e1T_2 = (__bf16*)(ws + 16*MB);     // [2][4096][1024] 16MB
  __bf16* e2T_2 = (__bf16*)(ws + 32*MB);     // [2][1024][4096] 16MB
  __bf16* mid_2 = (__bf16*)(ws + 48*MB);     // [2][1024][4096] 16MB
  float*  yk    = (float*) (ws + 64*MB);     // [2][4][1024][1024] f32 32MB
  __bf16* ao_hi = h_hi, *ao_lo = h_lo;

  dim3 blk(256);
  prep_kernel<<<5120, blk, 0, stream>>>(wq, wk, wv, w_proj, wAllT_h, wAllT_l,
                                        x, ln1_g, ln1_b, h_hi, h_lo);
  mgemm<0,true><<<dim3(24,32), blk, 0, stream>>>(h_hi, h_lo, DMODEL, wAllT_h, wAllT_l, DMODEL,
      nullptr, nullptr, qkv_hi, qkv_lo, 3*DMODEL, DMODEL, nullptr, nullptr);
  btrans_kernel<<<dim3(64,16), blk, 0, stream>>>(qkv_hi, qkv_lo, 3*DMODEL, 2048, vt_hi, vt_lo);
  attn_mfma_kernel<<<dim3(16,64), blk, 0, stream>>>(qkv_hi, qkv_lo, vt_hi, vt_lo, ao_hi, ao_lo);
  mgemm<5,true><<<dim3(8,32,2), blk, 0, stream>>>(ao_hi, ao_lo, DMODEL,
      wAllT_h + (size_t)3*DMODEL*DMODEL, wAllT_l + (size_t)3*DMODEL*DMODEL, DMODEL,
      nullptr, pP, nullptr, nullptr, DMODEL, 512, nullptr, nullptr);
  ln_router_kernel<<<TOK_N, blk, 0, stream>>>(pP, pP + (size_t)TOK_N*DMODEL, x, b_proj,
      ln2_g, ln2_b, h_hi, h_lo, out,
      w_rout, b_rout, w_noi, b_noi, w_skip, b_skip, noise, idx2, gate2, nskv);
  scan_kernel<<<1, blk, 0, stream>>>(idx2, gate2, nskv, tokb, gselb, zbuf);
  out_init_kernel<<<TOK_N, blk, 0, stream>>>(h_hi, h_lo, nskv, out);
  for (int p=0; p<4; p++){
    int e0 = 2*p;
    tconv_pair<<<dim3(64,16,4), blk, 0, stream>>>(ew1, ew2, e1T_2, e2T_2, e0);
    mgemm<2,false><<<dim3(32,8,2), blk, 0, stream>>>(h_hi, nullptr, DMODEL,
        e1T_2, nullptr, DMODEL, eb1 + (size_t)e0*DFFD,
        nullptr, mid_2, nullptr, DFFD, DMODEL, tokb + e0*CAPMAX, (const __bf16*)zbuf);
    mgemm<4,false><<<dim3(8,8,8), blk, 0, stream>>>(mid_2, nullptr, DFFD,
        e2T_2, nullptr, DFFD, nullptr,
        yk, nullptr, nullptr, DMODEL, 1024, tokb + e0*CAPMAX, nullptr);
    for (int pe=0; pe<2; pe++){
      int e = e0 + pe;
      sred_kernel<<<CAPMAX, blk, 0, stream>>>(yk + (size_t)pe*4*CAPMAX*DMODEL,
          tokb + e*CAPMAX, gselb + e*CAPMAX, eb2 + (size_t)e*DMODEL, out);
    }
  }
}

// Round 9
// 606.332 us; speedup vs baseline: 7.0780x; 1.0138x over previous
//
#include <hip/hip_runtime.h>
#include <math.h>

#define TOK_N   4096
#define DMODEL  1024
#define NEXP    8
#define DFFD    4096
#define CAPMAX  1024

typedef __bf16 bf16x8 __attribute__((ext_vector_type(8)));
typedef __bf16 bf16x4 __attribute__((ext_vector_type(4)));
typedef float  f32x4  __attribute__((ext_vector_type(4)));

__device__ __forceinline__ f32x4 MFMA16(bf16x8 a, bf16x8 b, f32x4 c){
  return __builtin_amdgcn_mfma_f32_16x16x32_bf16(a, b, c, 0, 0, 0);
}

__device__ __forceinline__ void gl16(const __bf16* g, __bf16* l){
  __builtin_amdgcn_global_load_lds(
      (const __attribute__((address_space(1))) unsigned int*)g,
      (__attribute__((address_space(3))) unsigned int*)l, 16, 0, 0);
}

__device__ __forceinline__ float wave_sum(float x){
  #pragma unroll
  for (int o=32;o;o>>=1) x += __shfl_down(x,o);
  return x;
}

// -------- prep: tconv4 (wq/wk/wv/wproj -> wAllT split) + LN1 in one dispatch --------
__global__ __launch_bounds__(256) void prep_kernel(
    const float* __restrict__ wq, const float* __restrict__ wk,
    const float* __restrict__ wv, const float* __restrict__ wp,
    __bf16* __restrict__ dh, __bf16* __restrict__ dl,
    const float* __restrict__ x, const float* __restrict__ g1,
    const float* __restrict__ b1, __bf16* __restrict__ hh, __bf16* __restrict__ hl)
{
  __shared__ float smem[64*65];
  int b = blockIdx.x, t = threadIdx.x;
  if (b < 1024){
    int z = b >> 8, rem = b & 255;
    int k0 = (rem >> 4) * 64, n0 = (rem & 15) * 64;
    const float* in = z==0?wq: z==1?wk: z==2?wv: wp;
    __bf16* oh = dh + (size_t)z*DMODEL*DMODEL;
    __bf16* ol = dl + (size_t)z*DMODEL*DMODEL;
    float (*tile)[65] = (float(*)[65])smem;
    #pragma unroll
    for (int i=0;i<4;i++){
      int row = (t>>4) + i*16, col = (t&15)*4;
      float4 f = *(const float4*)&in[(size_t)(k0+row)*DMODEL + n0 + col];
      tile[row][col]=f.x; tile[row][col+1]=f.y; tile[row][col+2]=f.z; tile[row][col+3]=f.w;
    }
    __syncthreads();
    #pragma unroll
    for (int i=0;i<2;i++){
      int c = t + i*256;
      int orow = c>>3, kg = (c&7)*8;
      bf16x8 hv, lv;
      #pragma unroll
      for (int u=0;u<8;u++){
        float xv = tile[kg+u][orow];
        __bf16 hb = (__bf16)xv;
        hv[u]=hb; lv[u]=(__bf16)(xv-(float)hb);
      }
      *(bf16x8*)&oh[(size_t)(n0+orow)*DMODEL + k0 + kg] = hv;
      *(bf16x8*)&ol[(size_t)(n0+orow)*DMODEL + k0 + kg] = lv;
    }
  } else {
    int n = b - 1024;
    float4 v = ((const float4*)(x + (size_t)n*DMODEL))[t];
    float s  = v.x+v.y+v.z+v.w;
    float sq = v.x*v.x+v.y*v.y+v.z*v.z+v.w*v.w;
    s = wave_sum(s); sq = wave_sum(sq);
    int lane = t & 63, wid = t >> 6;
    if (lane==0){ smem[wid]=s; smem[8+wid]=sq; }
    __syncthreads();
    if (t==0){
      float a = smem[0]+smem[1]+smem[2]+smem[3];
      float c = smem[8]+smem[9]+smem[10]+smem[11];
      float mean = a*(1.0f/DMODEL);
      float var  = c*(1.0f/DMODEL) - mean*mean;
      smem[16] = mean; smem[17] = 1.0f/sqrtf(var + 1e-5f);
    }
    __syncthreads();
    float mean = smem[16], rstd = smem[17];
    float4 g4 = ((const float4*)g1)[t];
    float4 b4 = ((const float4*)b1)[t];
    float o_[4];
    o_[0] = (v.x-mean)*rstd*g4.x + b4.x;
    o_[1] = (v.y-mean)*rstd*g4.y + b4.y;
    o_[2] = (v.z-mean)*rstd*g4.z + b4.z;
    o_[3] = (v.w-mean)*rstd*g4.w + b4.w;
    bf16x4 h4, l4;
    #pragma unroll
    for (int i=0;i<4;i++){ __bf16 hb=(__bf16)o_[i]; h4[i]=hb; l4[i]=(__bf16)(o_[i]-(float)hb); }
    *(bf16x4*)&hh[(size_t)n*DMODEL + t*4] = h4;
    *(bf16x4*)&hl[(size_t)n*DMODEL + t*4] = l4;
  }
}

// -------- proj-epilogue + LN2 + router + out-init fused --------
// out = x1 + (skipped ? h2 : 0); x1 never materialized.
__global__ __launch_bounds__(256) void ln_router_kernel(
    const float* __restrict__ p0, const float* __restrict__ p1,
    const float* __restrict__ xres, const float* __restrict__ bproj,
    const float* __restrict__ g, const float* __restrict__ b,
    __bf16* __restrict__ oh, __bf16* __restrict__ ol, float* __restrict__ out,
    const float* __restrict__ wr, const float* __restrict__ br,
    const float* __restrict__ wn, const float* __restrict__ bn,
    const float* __restrict__ wsk, const float* __restrict__ bsk,
    const float* __restrict__ noise,
    int* __restrict__ idx2, float* __restrict__ gate2, int* __restrict__ nskv)
{
  int n = blockIdx.x, t = threadIdx.x;
  size_t ro = (size_t)n*DMODEL/4 + t;
  float4 a  = ((const float4*)p0)[ro];
  float4 a1 = ((const float4*)p1)[ro];
  float4 xr = ((const float4*)xres)[ro];
  float4 bp = ((const float4*)bproj)[t];
  float4 v;
  v.x = a.x+a1.x+xr.x+bp.x; v.y = a.y+a1.y+xr.y+bp.y;
  v.z = a.z+a1.z+xr.z+bp.z; v.w = a.w+a1.w+xr.w+bp.w;
  float s  = v.x+v.y+v.z+v.w;
  float sq = v.x*v.x+v.y*v.y+v.z*v.z+v.w*v.w;
  s = wave_sum(s); sq = wave_sum(sq);
  __shared__ float r1[4], r2[4];
  __shared__ float mean_s, rstd_s, sk_s;
  int lane = t & 63, wid = t >> 6;
  if (lane==0){ r1[wid]=s; r2[wid]=sq; }
  __syncthreads();
  if (t==0){
    float aa = r1[0]+r1[1]+r1[2]+r1[3];
    float cc = r2[0]+r2[1]+r2[2]+r2[3];
    float mean = aa*(1.0f/DMODEL);
    float var  = cc*(1.0f/DMODEL) - mean*mean;
    mean_s = mean; rstd_s = 1.0f/sqrtf(var + 1e-5f);
  }
  __syncthreads();
  float mean = mean_s, rstd = rstd_s;
  float4 g4 = ((const float4*)g)[t];
  float4 b4 = ((const float4*)b)[t];
  float o_[4];
  o_[0] = (v.x-mean)*rstd*g4.x + b4.x;
  o_[1] = (v.y-mean)*rstd*g4.y + b4.y;
  o_[2] = (v.z-mean)*rstd*g4.z + b4.z;
  o_[3] = (v.w-mean)*rstd*g4.w + b4.w;
  bf16x4 h4, l4;
  #pragma unroll
  for (int i=0;i<4;i++){ __bf16 hb=(__bf16)o_[i]; h4[i]=hb; l4[i]=(__bf16)(o_[i]-(float)hb); }
  *(bf16x4*)&oh[(size_t)n*DMODEL + t*4] = h4;
  *(bf16x4*)&ol[(size_t)n*DMODEL + t*4] = l4;
  // router on exact f32 h2
  int d0 = t*4;
  const float* wrp = wr + (size_t)d0*NEXP;
  const float* wnp = wn + (size_t)d0*NEXP;
  const float* wsp = wsk + d0;
  float vals[17];
  #pragma unroll
  for (int i=0;i<17;i++) vals[i]=0.f;
  #pragma unroll
  for (int i=0;i<4;i++){
    #pragma unroll
    for (int e=0;e<NEXP;e++){
      vals[e]   += o_[i]*wrp[i*NEXP+e];
      vals[8+e] += o_[i]*wnp[i*NEXP+e];
    }
    vals[16] += o_[i]*wsp[i];
  }
  __shared__ float red[4][17];
  #pragma unroll
  for (int i=0;i<17;i++){
    float xx = wave_sum(vals[i]);
    if (lane==0) red[wid][i] = xx;
  }
  __syncthreads();
  if (t==0){
    float noisy[NEXP];
    #pragma unroll
    for (int e=0;e<NEXP;e++){
      float lr = red[0][e]+red[1][e]+red[2][e]+red[3][e] + br[e];
      float pn = red[0][8+e]+red[1][8+e]+red[2][8+e]+red[3][8+e] + bn[e];
      float sp = fmaxf(pn,0.f) + log1pf(expf(-fabsf(pn)));
      noisy[e] = lr + noise[(size_t)n*NEXP + e]*sp;
    }
    float sk = red[0][16]+red[1][16]+red[2][16]+red[3][16] + bsk[0];
    sk_s = sk;
    nskv[n] = (sk <= 0.f) ? 1 : 0;
    int i0=0; float v0=noisy[0];
    #pragma unroll
    for (int e=1;e<NEXP;e++) if (noisy[e] > v0){ v0=noisy[e]; i0=e; }
    int i1=-1; float v1=-INFINITY;
    #pragma unroll
    for (int e=0;e<NEXP;e++) if (e!=i0 && noisy[e] > v1){ v1=noisy[e]; i1=e; }
    float tt = expf(v1 - v0);
    idx2[n*2+0]=i0; idx2[n*2+1]=i1;
    gate2[n*2+0]=1.0f/(1.0f+tt); gate2[n*2+1]=tt/(1.0f+tt);
  }
  __syncthreads();
  // fused out-init: skipped token (sk>0) gets x1 + h2; else x1 (experts add later)
  if (sk_s > 0.f){
    v.x += o_[0]; v.y += o_[1]; v.z += o_[2]; v.w += o_[3];
  }
  ((float4*)out)[ro] = v;
}

// -------- pair expert weight transpose-convert: z<2 -> ew1[e0+z], z>=2 -> ew2[e0+z-2] --------
__global__ __launch_bounds__(256) void tconv_pair(
    const float* __restrict__ ew1, const float* __restrict__ ew2,
    __bf16* __restrict__ e1T, __bf16* __restrict__ e2T, int e0)
{
  __shared__ float tile[64][65];
  int z = blockIdx.z, t = threadIdx.x;
  const float* in; __bf16* out; int K, N, k0, n0;
  if (z < 2){
    in = ew1 + (size_t)(e0+z)*DMODEL*DFFD; out = e1T + (size_t)z*DFFD*DMODEL;
    K = DMODEL; N = DFFD; k0 = blockIdx.y*64; n0 = blockIdx.x*64;
  } else {
    in = ew2 + (size_t)(e0+z-2)*DFFD*DMODEL; out = e2T + (size_t)(z-2)*DMODEL*DFFD;
    K = DFFD; N = DMODEL; k0 = blockIdx.x*64; n0 = blockIdx.y*64;
  }
  #pragma unroll
  for (int i=0;i<4;i++){
    int row = (t>>4) + i*16, col = (t&15)*4;
    float4 f = *(const float4*)&in[(size_t)(k0+row)*N + n0 + col];
    tile[row][col]=f.x; tile[row][col+1]=f.y; tile[row][col+2]=f.z; tile[row][col+3]=f.w;
  }
  __syncthreads();
  #pragma unroll
  for (int i=0;i<2;i++){
    int c = t + i*256;
    int orow = c>>3, kg = (c&7)*8;
    bf16x8 hv;
    #pragma unroll
    for (int u=0;u<8;u++) hv[u] = (__bf16)tile[kg+u][orow];
    *(bf16x8*)&out[(size_t)(n0+orow)*K + k0 + kg] = hv;
  }
}

// ------- bf16-pair transpose: qkv v-slice -> vT[1024][4096] -------
__global__ __launch_bounds__(256) void btrans_kernel(
    const __bf16* __restrict__ ih, const __bf16* __restrict__ il, int istride, int icol0,
    __bf16* __restrict__ oh, __bf16* __restrict__ ol){
  __shared__ __bf16 th[64][72], tl[64][72];
  int r0 = blockIdx.x*64, c0 = blockIdx.y*64;
  int t = threadIdx.x;
  {
    int r = t>>2, cg = (t&3)*16;
    size_t go = (size_t)(r0+r)*istride + icol0 + c0 + cg;
    *(bf16x8*)&th[r][cg]   = *(const bf16x8*)&ih[go];
    *(bf16x8*)&th[r][cg+8] = *(const bf16x8*)&ih[go+8];
    *(bf16x8*)&tl[r][cg]   = *(const bf16x8*)&il[go];
    *(bf16x8*)&tl[r][cg+8] = *(const bf16x8*)&il[go+8];
  }
  __syncthreads();
  {
    int c = t>>2, rg = (t&3)*16;
    bf16x8 a,b,e,f;
    #pragma unroll
    for (int u=0;u<8;u++){ a[u]=th[rg+u][c]; b[u]=th[rg+8+u][c]; e[u]=tl[rg+u][c]; f[u]=tl[rg+8+u][c]; }
    size_t go = (size_t)(c0+c)*TOK_N + r0 + rg;
    *(bf16x8*)&oh[go]   = a;
    *(bf16x8*)&oh[go+8] = b;
    *(bf16x8*)&ol[go]   = e;
    *(bf16x8*)&ol[go+8] = f;
  }
}

// ---------------- MFMA GEMM, 128x128, BK=32, dbuf-prefetch, global_load_lds ----------------
// LDS chunk swizzle: linear dest; source chunk sg = grp^((row>>1)&3); read slot kb^((fr>>1)&3).
template<int MODE, bool SPLIT>
__global__ __launch_bounds__(256) void mgemm(
    const __bf16* __restrict__ Ah, const __bf16* __restrict__ Al, int Astride,
    const __bf16* __restrict__ Bh, const __bf16* __restrict__ Bl, int Bstride,
    const float* __restrict__ bias,
    float* __restrict__ Cf, __bf16* __restrict__ Ch, __bf16* __restrict__ Cl,
    int N, int K,
    const int* __restrict__ tok, const __bf16* __restrict__ zbuf)
{
  if constexpr (MODE==2){
    int z = blockIdx.z;
    Bh  += (size_t)z*((size_t)DFFD*DMODEL);
    bias+= (size_t)z*DFFD;
    Ch  += (size_t)z*((size_t)CAPMAX*DFFD);
    tok += z*CAPMAX;
  }
  if constexpr (MODE==4){
    int pe = blockIdx.z>>2, kz = blockIdx.z&3;
    Ah  += (size_t)pe*((size_t)CAPMAX*DFFD) + kz*1024;
    Bh  += (size_t)pe*((size_t)DMODEL*DFFD) + kz*1024;
    Cf  += (size_t)blockIdx.z*((size_t)CAPMAX*DMODEL);
    tok += pe*CAPMAX;
  }
  if constexpr (MODE==5){
    int kz = blockIdx.z;
    Ah += kz*512; Al += kz*512; Bh += kz*512; Bl += kz*512;
    Cf += (size_t)kz*((size_t)TOK_N*DMODEL);
  }
  int m0 = blockIdx.y*128, n0 = blockIdx.x*128;
  if ((MODE==2||MODE==4) && tok[m0] >= TOK_N) return;   // valid slots are a prefix
  __shared__ __align__(16) __bf16 sAh[2*128*32], sBh[2*128*32];
  __shared__ __align__(16) __bf16 sAl[SPLIT?2*128*32:8], sBl[SPLIT?2*128*32:8];
  int t = threadIdx.x, lane = t&63, w = t>>6;
  int wr = w>>1, wc = w&1, fr = lane&15, kb = lane>>4;

  const __bf16* aB[2]; const __bf16* aBl[2]; bool aval[2];
  const __bf16* bB[2]; const __bf16* bBl[2];
  #pragma unroll
  for (int j=0;j<2;j++){
    int c = j*256 + w*64 + lane;
    int row = c>>2, grp = c&3;
    int sg = grp ^ ((row>>1)&3);           // pre-swizzled source chunk (involution)
    if (MODE==2){
      int token = tok[m0+row];
      if (token < TOK_N){ aB[j] = Ah + (size_t)token*Astride + sg*8; aval[j]=true; }
      else              { aB[j] = zbuf + sg*8;                       aval[j]=false; }
    } else {
      aB[j] = Ah + (size_t)(m0+row)*Astride + sg*8; aval[j]=true;
      if (SPLIT) aBl[j] = Al + (size_t)(m0+row)*Astride + sg*8;
    }
    bB[j] = Bh + (size_t)(n0+row)*Bstride + sg*8;
    if (SPLIT) bBl[j] = Bl + (size_t)(n0+row)*Bstride + sg*8;
  }

  auto stage = [&](int buf, int kt){
    int base = buf*(128*32);
    #pragma unroll
    for (int j=0;j<2;j++){
      int cb8 = base + (j*256 + w*64)*8;
      gl16(aB[j] + (aval[j]? kt : 0), &sAh[cb8]);
      gl16(bB[j] + kt, &sBh[cb8]);
      if constexpr (SPLIT){
        gl16(aBl[j] + kt, &sAl[cb8]);
        gl16(bBl[j] + kt, &sBl[cb8]);
      }
    }
  };

  f32x4 acc[4][4];
  #pragma unroll
  for (int mt=0;mt<4;mt++)
    #pragma unroll
    for (int nt=0;nt<4;nt++) acc[mt][nt] = (f32x4){0.f,0.f,0.f,0.f};

  stage(0, 0);
  __syncthreads();
  int nk = K >> 5;
  int xk = (kb ^ ((fr>>1)&3))*8;           // swizzled read slot within row
  for (int ik=0; ik<nk; ik++){
    int cur = ik & 1;
    if (ik+1 < nk) stage(cur^1, (ik+1)<<5);
    int fb = cur*(128*32);
    bf16x8 aFh[4], bFh[4];
    #pragma unroll
    for (int mt=0;mt<4;mt++) aFh[mt] = *(const bf16x8*)&sAh[fb + (wr*64+mt*16+fr)*32 + xk];
    #pragma unroll
    for (int nt=0;nt<4;nt++) bFh[nt] = *(const bf16x8*)&sBh[fb + (wc*64+nt*16+fr)*32 + xk];
    __builtin_amdgcn_s_setprio(1);
    #pragma unroll
    for (int mt=0;mt<4;mt++)
      #pragma unroll
      for (int nt=0;nt<4;nt++)
        acc[mt][nt] = MFMA16(aFh[mt], bFh[nt], acc[mt][nt]);
    __builtin_amdgcn_s_setprio(0);
    if constexpr (SPLIT){
      bf16x8 aFl[4], bFl[4];
      #pragma unroll
      for (int mt=0;mt<4;mt++) aFl[mt] = *(const bf16x8*)&sAl[fb + (wr*64+mt*16+fr)*32 + xk];
      #pragma unroll
      for (int nt=0;nt<4;nt++) bFl[nt] = *(const bf16x8*)&sBl[fb + (wc*64+nt*16+fr)*32 + xk];
      __builtin_amdgcn_s_setprio(1);
      #pragma unroll
      for (int mt=0;mt<4;mt++)
        #pragma unroll
        for (int nt=0;nt<4;nt++){
          acc[mt][nt] = MFMA16(aFh[mt], bFl[nt], acc[mt][nt]);
          acc[mt][nt] = MFMA16(aFl[mt], bFh[nt], acc[mt][nt]);
        }
      __builtin_amdgcn_s_setprio(0);
    }
    __syncthreads();
  }

  #pragma unroll
  for (int mt=0; mt<4; mt++){
    int r0 = m0 + wr*64 + mt*16 + (lane>>4)*4;
    #pragma unroll
    for (int nt=0; nt<4; nt++){
      int col = n0 + wc*64 + nt*16 + fr;
      f32x4 v = acc[mt][nt];
      if constexpr (MODE==0){
        #pragma unroll
        for (int jj=0;jj<4;jj++){
          float val = v[jj];
          __bf16 hb = (__bf16)val;
          size_t idx = (size_t)(r0+jj)*N + col;
          Ch[idx] = hb; Cl[idx] = (__bf16)(val-(float)hb);
        }
      } else if constexpr (MODE==2){
        float bs = bias[col];
        #pragma unroll
        for (int jj=0;jj<4;jj++)
          Ch[(size_t)(r0+jj)*N + col] = (__bf16)fmaxf(v[jj]+bs, 0.f);
      } else {  // MODE 4 / 5: raw partial
        #pragma unroll
        for (int jj=0;jj<4;jj++)
          Cf[(size_t)(r0+jj)*N + col] = v[jj];
      }
    }
  }
}

// ------- per-expert scatter-reduce: out[tok[r]] += gsel[r]*(sum_z yk[z][r] + eb2) -------
__global__ __launch_bounds__(256) void sred_kernel(const float* __restrict__ yk,
    const int* __restrict__ tok, const float* __restrict__ gsel,
    const float* __restrict__ eb2, float* __restrict__ out)
{
  int r = blockIdx.x, t = threadIdx.x;
  int token = tok[r];
  if (token >= TOK_N) return;
  float g = gsel[r];
  float4 acc = ((const float4*)eb2)[t];
  #pragma unroll
  for (int z=0;z<4;z++){
    float4 p = ((const float4*)(yk + (size_t)z*CAPMAX*DMODEL + (size_t)r*DMODEL))[t];
    acc.x+=p.x; acc.y+=p.y; acc.z+=p.z; acc.w+=p.w;
  }
  float* op = out + (size_t)token*DMODEL;
  float4 o = ((float4*)op)[t];
  o.x += g*acc.x; o.y += g*acc.y; o.z += g*acc.z; o.w += g*acc.w;
  ((float4*)op)[t] = o;
}

// ---------------- MFMA causal flash attention, split-bf16, swapped operands ----------------
// Each block owns TWO q-tiles (qtA=blk, qtB=blk+8) of one (b,h): K/V staging shared.
__global__ __launch_bounds__(256) void attn_mfma_kernel(
    const __bf16* __restrict__ qkvh, const __bf16* __restrict__ qkvl,
    const __bf16* __restrict__ vth, const __bf16* __restrict__ vtl,
    __bf16* __restrict__ oh, __bf16* __restrict__ ol)
{
  __shared__ __align__(16) __bf16 Kh[2][64*64], Kl[2][64*64], Vh[2][64*64], Vl[2][64*64];
  __shared__ __align__(16) __bf16 Pt[2][4][16*64];   // per-wave P^T, reused per q-tile
  int qtA = blockIdx.x, qtB = qtA + 8;
  int bh = blockIdx.y;
  int batch = bh>>4, head = bh&15;
  int t = threadIdx.x, lane = t&63, w = t>>6;
  int g = lane>>4, fr = lane&15;
  int col0 = head*64;
  size_t qbaseA = (size_t)(batch*1024 + qtA*64);
  size_t qbaseB = (size_t)(batch*1024 + qtB*64);
  const int QKS = 3*DMODEL;
  const float scale = 0.03125f;              // D^-0.5 = 1/32

  bf16x8 bQhA[2], bQlA[2], bQhB[2], bQlB[2];
  {
    int qrow = w*16 + fr;
    size_t rbA = (qbaseA+qrow)*QKS + col0 + g*8;
    size_t rbB = (qbaseB+qrow)*QKS + col0 + g*8;
    bQhA[0] = *(const bf16x8*)&qkvh[rbA];
    bQhA[1] = *(const bf16x8*)&qkvh[rbA+32];
    bQlA[0] = *(const bf16x8*)&qkvl[rbA];
    bQlA[1] = *(const bf16x8*)&qkvl[rbA+32];
    bQhB[0] = *(const bf16x8*)&qkvh[rbB];
    bQhB[1] = *(const bf16x8*)&qkvh[rbB+32];
    bQlB[0] = *(const bf16x8*)&qkvl[rbB];
    bQlB[1] = *(const bf16x8*)&qkvl[rbB+32];
  }

  auto stageKV = [&](int buf, int kt){
    size_t kbase = (size_t)(batch*1024 + kt*64);
    #pragma unroll
    for (int j=0;j<2;j++){
      int c = j*256 + t, row = c>>3, seg = c&7;
      int lb = (j*256 + w*64)*8;
      size_t gk = (kbase+row)*QKS + 1024 + col0 + ((seg^(row&7))*8);
      gl16(qkvh+gk, &Kh[buf][lb]);
      gl16(qkvl+gk, &Kl[buf][lb]);
      size_t gv = (size_t)(col0+row)*TOK_N + kbase + ((seg^(row&7))*8);
      gl16(vth+gv, &Vh[buf][lb]);
      gl16(vtl+gv, &Vl[buf][lb]);
    }
  };

  float mA = -INFINITY, lA = 0.f, mB = -INFINITY, lB = 0.f;
  f32x4 oA[4], oB[4];
  #pragma unroll
  for (int nt=0;nt<4;nt++){ oA[nt]=(f32x4){0.f,0.f,0.f,0.f}; oB[nt]=(f32x4){0.f,0.f,0.f,0.f}; }

  // one tile's full pipeline for one q-tile (per-wave Pt reuse, no barrier inside)
  auto process = [&](int cur, bool diag, bf16x8* bQh, bf16x8* bQl,
                     float& m_, float& l_, f32x4* o_){
    int ntmax = diag ? (w+1) : 4;
    f32x4 s[4];
    #pragma unroll
    for (int nt=0;nt<4;nt++) s[nt]=(f32x4){0.f,0.f,0.f,0.f};
    __builtin_amdgcn_s_setprio(1);
    #pragma unroll
    for (int ks=0; ks<2; ks++){
      #pragma unroll
      for (int nt=0; nt<4; nt++){
        if (nt < ntmax){
          int kvr = nt*16 + fr;
          int sc_ = (ks*4 + g) ^ (kvr&7);
          bf16x8 aKh = *(const bf16x8*)&Kh[cur][kvr*64 + sc_*8];
          bf16x8 aKl = *(const bf16x8*)&Kl[cur][kvr*64 + sc_*8];
          s[nt] = MFMA16(aKh, bQh[ks], s[nt]);
          s[nt] = MFMA16(aKl, bQh[ks], s[nt]);
          s[nt] = MFMA16(aKh, bQl[ks], s[nt]);
        }
      }
    }
    __builtin_amdgcn_s_setprio(0);
    float sv[4][4];
    float mx = -INFINITY;
    int ql = w*16 + fr;
    #pragma unroll
    for (int nt=0;nt<4;nt++)
      #pragma unroll
      for (int j=0;j<4;j++){
        float xv = s[nt][j]*scale;
        if (nt >= ntmax || (diag && (nt*16 + g*4 + j) > ql)) xv = -INFINITY;
        sv[nt][j] = xv;
        mx = fmaxf(mx, xv);
      }
    mx = fmaxf(mx, __shfl_xor(mx,16));
    mx = fmaxf(mx, __shfl_xor(mx,32));
    float nm = fmaxf(m_, mx);
    float scf = __expf(m_ - nm);
    float ps = 0.f;
    #pragma unroll
    for (int nt=0;nt<4;nt++)
      #pragma unroll
      for (int j=0;j<4;j++){
        float p = __expf(sv[nt][j] - nm);
        sv[nt][j] = p;
        ps += p;
      }
    ps += __shfl_xor(ps,16);
    ps += __shfl_xor(ps,32);
    l_ = l_*scf + ps;
    m_ = nm;
    #pragma unroll
    for (int nt=0;nt<4;nt++) o_[nt] = o_[nt]*scf;
    #pragma unroll
    for (int nt=0;nt<4;nt++){
      bf16x4 hv, lv;
      #pragma unroll
      for (int j=0;j<4;j++){
        float pv = sv[nt][j];
        __bf16 hb = (__bf16)pv;
        hv[j] = hb; lv[j] = (__bf16)(pv-(float)hb);
      }
      int el = fr*64 + (((2*nt + (g>>1)) ^ (fr&7))*8) + (g&1)*4;
      *(bf16x4*)&Pt[0][w][el] = hv;
      *(bf16x4*)&Pt[1][w][el] = lv;
    }
    int ksmax = (diag && w < 2) ? 1 : 2;
    __builtin_amdgcn_s_setprio(1);
    #pragma unroll
    for (int ks=0; ks<2; ks++){
      if (ks < ksmax){
        int pc = (4*ks + g) ^ (fr&7);
        bf16x8 bPh = *(const bf16x8*)&Pt[0][w][fr*64 + pc*8];
        bf16x8 bPl = *(const bf16x8*)&Pt[1][w][fr*64 + pc*8];
        #pragma unroll
        for (int nt=0; nt<4; nt++){
          int vr = nt*16 + fr;
          int vc = (ks*4 + g) ^ (vr&7);
          bf16x8 aVh = *(const bf16x8*)&Vh[cur][vr*64 + vc*8];
          bf16x8 aVl = *(const bf16x8*)&Vl[cur][vr*64 + vc*8];
          o_[nt] = MFMA16(aVh, bPh, o_[nt]);
          o_[nt] = MFMA16(aVl, bPh, o_[nt]);
          o_[nt] = MFMA16(aVh, bPl, o_[nt]);
        }
      }
    }
    __builtin_amdgcn_s_setprio(0);
  };

  stageKV(0, 0);
  for (int kt=0; kt<=qtB; kt++){
    int cur = kt&1;
    __syncthreads();                         // vmcnt drain: tile kt ready; prev reads done
    if (kt < qtB) stageKV(cur^1, kt+1);      // prefetch flies under compute
    if (kt <= qtA) process(cur, kt==qtA, bQhA, bQlA, mA, lA, oA);
    process(cur, kt==qtB, bQhB, bQlB, mB, lB, oB);
  }

  auto writeOut = [&](size_t qbase, float l_, f32x4* o_){
    float inv = 1.0f/l_;
    #pragma unroll
    for (int nt=0;nt<4;nt++){
      bf16x4 hv, lv;
      #pragma unroll
      for (int j=0;j<4;j++){
        float val = o_[nt][j]*inv;
        __bf16 hb = (__bf16)val;
        hv[j] = hb; lv[j] = (__bf16)(val-(float)hb);
      }
      int el = fr*64 + (((2*nt + (g>>1)) ^ (fr&7))*8) + (g&1)*4;
      *(bf16x4*)&Pt[0][w][el] = hv;
      *(bf16x4*)&Pt[1][w][el] = lv;
    }
    #pragma unroll
    for (int r=0;r<2;r++){
      int c = r*4 + g;
      int el = fr*64 + ((c ^ (fr&7))*8);
      bf16x8 vh = *(const bf16x8*)&Pt[0][w][el];
      bf16x8 vl = *(const bf16x8*)&Pt[1][w][el];
      size_t go = (qbase + w*16 + fr)*DMODEL + col0 + c*8;
      *(bf16x8*)&oh[go] = vh;
      *(bf16x8*)&ol[go] = vl;
    }
  };
  writeOut(qbaseA, lA, oA);
  writeOut(qbaseB, lB, oB);
}

// ---------------- capacity scan + slot assignment (+ zero pad buffer) ----------------
__global__ __launch_bounds__(256) void scan_kernel(const int* __restrict__ idx2,
    const float* __restrict__ gate2, const int* __restrict__ nskv,
    int* __restrict__ tok, float* __restrict__ gsel, float* __restrict__ zbuf)
{
  int t = threadIdx.x;
  for (int i=t; i<NEXP*CAPMAX; i+=256){ tok[i]=TOK_N; gsel[i]=0.f; }
  for (int i=t; i<1024; i+=256) zbuf[i]=0.f;
  __shared__ int cnts[256][NEXP];
  __shared__ int nns_part[256];
  __shared__ int cap_s;
  int loc[NEXP];
  #pragma unroll
  for (int e=0;e<NEXP;e++) loc[e]=0;
  int nn=0, base = t*16;
  for (int u=0;u<16;u++){
    int n = base+u;
    if (nskv[n]){ nn++; loc[idx2[n*2]]++; loc[idx2[n*2+1]]++; }
  }
  #pragma unroll
  for (int e=0;e<NEXP;e++) cnts[t][e]=loc[e];
  nns_part[t]=nn;
  __syncthreads();
  if (t < NEXP){ int run=0; for (int i=0;i<256;i++){ int c=cnts[i][t]; cnts[i][t]=run; run+=c; } }
  if (t == NEXP){ int sum=0; for (int i=0;i<256;i++) sum+=nns_part[i]; cap_s = sum/4; }
  __syncthreads();
  int capacity = cap_s;
  int run[NEXP];
  #pragma unroll
  for (int e=0;e<NEXP;e++) run[e]=cnts[t][e];
  for (int u=0;u<16;u++){
    int n = base+u;
    if (!nskv[n]) continue;
    #pragma unroll
    for (int kk=0;kk<2;kk++){
      int e = idx2[n*2+kk];
      int r = run[e]++;
      if (r < capacity){ tok[e*CAPMAX+r]=n; gsel[e*CAPMAX+r]=gate2[n*2+kk]; }
    }
  }
}

extern "C" void kernel_launch(void* const* d_in, const int* in_sizes, int n_in,
                              void* d_out, int out_size, void* d_ws, size_t ws_size,
                              hipStream_t stream) {
  const float* x      = (const float*)d_in[0];
  const float* noise  = (const float*)d_in[1];
  const float* ln1_g  = (const float*)d_in[2];
  const float* ln1_b  = (const float*)d_in[3];
  const float* wq     = (const float*)d_in[4];
  const float* wk     = (const float*)d_in[5];
  const float* wv     = (const float*)d_in[6];
  const float* w_proj = (const float*)d_in[7];
  const float* b_proj = (const float*)d_in[8];
  const float* ln2_g  = (const float*)d_in[9];
  const float* ln2_b  = (const float*)d_in[10];
  const float* w_rout = (const float*)d_in[11];
  const float* b_rout = (const float*)d_in[12];
  const float* w_noi  = (const float*)d_in[13];
  const float* b_noi  = (const float*)d_in[14];
  const float* w_skip = (const float*)d_in[15];
  const float* b_skip = (const float*)d_in[16];
  const float* ew1    = (const float*)d_in[17];
  const float* eb1    = (const float*)d_in[18];
  const float* ew2    = (const float*)d_in[19];
  const float* eb2    = (const float*)d_in[20];
  float* out = (float*)d_out;

  char* ws = (char*)d_ws;
  const size_t MB = 1024*1024;
  // ---- trunk phase ----
  __bf16* h_hi   = (__bf16*)(ws + 0*MB);     // LN1 out; attn out; h2
  __bf16* h_lo   = (__bf16*)(ws + 8*MB);
  __bf16* qkv_hi = (__bf16*)(ws + 16*MB);    // [4096][3072] 24MB
  __bf16* qkv_lo = (__bf16*)(ws + 40*MB);
  __bf16* wAllT_h= (__bf16*)(ws + 64*MB);    // [4096][1024]: q/k/v/proj stacked, 8MB
  __bf16* wAllT_l= (__bf16*)(ws + 72*MB);
  __bf16* vt_hi  = (__bf16*)(ws + 81*MB);    // vT [1024][4096] 8MB
  __bf16* vt_lo  = (__bf16*)(ws + 89*MB);
  float*  pP     = (float*) (ws + 16*MB);    // proj partials [2][4096][1024] f32 (qkv dead)
  // ---- metadata @96MB (vt_lo tail; written only after attention) ----
  int*   idx2  = (int*)  (ws + 96*MB);
  float* gate2 = (float*)(ws + 96*MB + 32*1024);
  int*   nskv  = (int*)  (ws + 96*MB + 64*1024);
  int*   tokb  = (int*)  (ws + 96*MB + 80*1024);
  float* gselb = (float*)(ws + 96*MB + 112*1024);
  float* zbuf  = (float*)(ws + 96*MB + 144*1024);
  // ---- expert phase (qkv/wAllT/vt/pP dead) ----
  __bf16* e1T_2 = (__bf16*)(ws + 16*MB);     // [2][4096][1024] 16MB
  __bf16* e2T_2 = (__bf16*)(ws + 32*MB);     // [2][1024][4096] 16MB
  __bf16* mid_2 = (__bf16*)(ws + 48*MB);     // [2][1024][4096] 16MB
  float*  yk    = (float*) (ws + 64*MB);     // [2][4][1024][1024] f32 32MB
  __bf16* ao_hi = h_hi, *ao_lo = h_lo;

  dim3 blk(256);
  prep_kernel<<<5120, blk, 0, stream>>>(wq, wk, wv, w_proj, wAllT_h, wAllT_l,
                                        x, ln1_g, ln1_b, h_hi, h_lo);
  mgemm<0,true><<<dim3(24,32), blk, 0, stream>>>(h_hi, h_lo, DMODEL, wAllT_h, wAllT_l, DMODEL,
      nullptr, nullptr, qkv_hi, qkv_lo, 3*DMODEL, DMODEL, nullptr, nullptr);
  btrans_kernel<<<dim3(64,16), blk, 0, stream>>>(qkv_hi, qkv_lo, 3*DMODEL, 2048, vt_hi, vt_lo);
  attn_mfma_kernel<<<dim3(8,64), blk, 0, stream>>>(qkv_hi, qkv_lo, vt_hi, vt_lo, ao_hi, ao_lo);
  mgemm<5,true><<<dim3(8,32,2), blk, 0, stream>>>(ao_hi, ao_lo, DMODEL,
      wAllT_h + (size_t)3*DMODEL*DMODEL, wAllT_l + (size_t)3*DMODEL*DMODEL, DMODEL,
      nullptr, pP, nullptr, nullptr, DMODEL, 512, nullptr, nullptr);
  // proj epilogue + LN2 + router + out-init fused; writes out = x1 + (skip? h2 : 0)
  ln_router_kernel<<<TOK_N, blk, 0, stream>>>(pP, pP + (size_t)TOK_N*DMODEL, x, b_proj,
      ln2_g, ln2_b, h_hi, h_lo, out,
      w_rout, b_rout, w_noi, b_noi, w_skip, b_skip, noise, idx2, gate2, nskv);
  scan_kernel<<<1, blk, 0, stream>>>(idx2, gate2, nskv, tokb, gselb, zbuf);
  for (int p=0; p<4; p++){
    int e0 = 2*p;
    tconv_pair<<<dim3(64,16,4), blk, 0, stream>>>(ew1, ew2, e1T_2, e2T_2, e0);
    mgemm<2,false><<<dim3(32,8,2), blk, 0, stream>>>(h_hi, nullptr, DMODEL,
        e1T_2, nullptr, DMODEL, eb1 + (size_t)e0*DFFD,
        nullptr, mid_2, nullptr, DFFD, DMODEL, tokb + e0*CAPMAX, (const __bf16*)zbuf);
    mgemm<4,false><<<dim3(8,8,8), blk, 0, stream>>>(mid_2, nullptr, DFFD,
        e2T_2, nullptr, DFFD, nullptr,
        yk, nullptr, nullptr, DMODEL, 1024, tokb + e0*CAPMAX, nullptr);
    for (int pe=0; pe<2; pe++){
      int e = e0 + pe;
      sred_kernel<<<CAPMAX, blk, 0, stream>>>(yk + (size_t)pe*4*CAPMAX*DMODEL,
          tokb + e*CAPMAX, gselb + e*CAPMAX, eb2 + (size_t)e*DMODEL, out);
    }
  }
}

// Round 10
// 529.068 us; speedup vs baseline: 8.1117x; 1.1460x over previous
//
#include <hip/hip_runtime.h>
#include <math.h>

#define TOK_N   4096
#define DMODEL  1024
#define NEXP    8
#define DFFD    4096
#define CAPMAX  1024

typedef __bf16 bf16x8 __attribute__((ext_vector_type(8)));
typedef __bf16 bf16x4 __attribute__((ext_vector_type(4)));
typedef float  f32x4  __attribute__((ext_vector_type(4)));

__device__ __forceinline__ f32x4 MFMA16(bf16x8 a, bf16x8 b, f32x4 c){
  return __builtin_amdgcn_mfma_f32_16x16x32_bf16(a, b, c, 0, 0, 0);
}

__device__ __forceinline__ void gl16(const __bf16* g, __bf16* l){
  __builtin_amdgcn_global_load_lds(
      (const __attribute__((address_space(1))) unsigned int*)g,
      (__attribute__((address_space(3))) unsigned int*)l, 16, 0, 0);
}

__device__ __forceinline__ float wave_sum(float x){
  #pragma unroll
  for (int o=32;o;o>>=1) x += __shfl_down(x,o);
  return x;
}

// -------- prep: tconv4 (wq/wk/wv/wproj -> wAllT split) + LN1 in one dispatch --------
__global__ __launch_bounds__(256) void prep_kernel(
    const float* __restrict__ wq, const float* __restrict__ wk,
    const float* __restrict__ wv, const float* __restrict__ wp,
    __bf16* __restrict__ dh, __bf16* __restrict__ dl,
    const float* __restrict__ x, const float* __restrict__ g1,
    const float* __restrict__ b1, __bf16* __restrict__ hh, __bf16* __restrict__ hl)
{
  __shared__ float smem[64*65];
  int b = blockIdx.x, t = threadIdx.x;
  if (b < 1024){
    int z = b >> 8, rem = b & 255;
    int k0 = (rem >> 4) * 64, n0 = (rem & 15) * 64;
    const float* in = z==0?wq: z==1?wk: z==2?wv: wp;
    __bf16* oh = dh + (size_t)z*DMODEL*DMODEL;
    __bf16* ol = dl + (size_t)z*DMODEL*DMODEL;
    float (*tile)[65] = (float(*)[65])smem;
    #pragma unroll
    for (int i=0;i<4;i++){
      int row = (t>>4) + i*16, col = (t&15)*4;
      float4 f = *(const float4*)&in[(size_t)(k0+row)*DMODEL + n0 + col];
      tile[row][col]=f.x; tile[row][col+1]=f.y; tile[row][col+2]=f.z; tile[row][col+3]=f.w;
    }
    __syncthreads();
    #pragma unroll
    for (int i=0;i<2;i++){
      int c = t + i*256;
      int orow = c>>3, kg = (c&7)*8;
      bf16x8 hv, lv;
      #pragma unroll
      for (int u=0;u<8;u++){
        float xv = tile[kg+u][orow];
        __bf16 hb = (__bf16)xv;
        hv[u]=hb; lv[u]=(__bf16)(xv-(float)hb);
      }
      *(bf16x8*)&oh[(size_t)(n0+orow)*DMODEL + k0 + kg] = hv;
      *(bf16x8*)&ol[(size_t)(n0+orow)*DMODEL + k0 + kg] = lv;
    }
  } else {
    int n = b - 1024;
    float4 v = ((const float4*)(x + (size_t)n*DMODEL))[t];
    float s  = v.x+v.y+v.z+v.w;
    float sq = v.x*v.x+v.y*v.y+v.z*v.z+v.w*v.w;
    s = wave_sum(s); sq = wave_sum(sq);
    int lane = t & 63, wid = t >> 6;
    if (lane==0){ smem[wid]=s; smem[8+wid]=sq; }
    __syncthreads();
    if (t==0){
      float a = smem[0]+smem[1]+smem[2]+smem[3];
      float c = smem[8]+smem[9]+smem[10]+smem[11];
      float mean = a*(1.0f/DMODEL);
      float var  = c*(1.0f/DMODEL) - mean*mean;
      smem[16] = mean; smem[17] = 1.0f/sqrtf(var + 1e-5f);
    }
    __syncthreads();
    float mean = smem[16], rstd = smem[17];
    float4 g4 = ((const float4*)g1)[t];
    float4 b4 = ((const float4*)b1)[t];
    float o_[4];
    o_[0] = (v.x-mean)*rstd*g4.x + b4.x;
    o_[1] = (v.y-mean)*rstd*g4.y + b4.y;
    o_[2] = (v.z-mean)*rstd*g4.z + b4.z;
    o_[3] = (v.w-mean)*rstd*g4.w + b4.w;
    bf16x4 h4, l4;
    #pragma unroll
    for (int i=0;i<4;i++){ __bf16 hb=(__bf16)o_[i]; h4[i]=hb; l4[i]=(__bf16)(o_[i]-(float)hb); }
    *(bf16x4*)&hh[(size_t)n*DMODEL + t*4] = h4;
    *(bf16x4*)&hl[(size_t)n*DMODEL + t*4] = l4;
  }
}

// -------- proj-epilogue + LN2 + router + out-init fused --------
__global__ __launch_bounds__(256) void ln_router_kernel(
    const float* __restrict__ p0, const float* __restrict__ p1,
    const float* __restrict__ xres, const float* __restrict__ bproj,
    const float* __restrict__ g, const float* __restrict__ b,
    __bf16* __restrict__ oh, __bf16* __restrict__ ol, float* __restrict__ out,
    const float* __restrict__ wr, const float* __restrict__ br,
    const float* __restrict__ wn, const float* __restrict__ bn,
    const float* __restrict__ wsk, const float* __restrict__ bsk,
    const float* __restrict__ noise,
    int* __restrict__ idx2, float* __restrict__ gate2, int* __restrict__ nskv)
{
  int n = blockIdx.x, t = threadIdx.x;
  size_t ro = (size_t)n*DMODEL/4 + t;
  float4 a  = ((const float4*)p0)[ro];
  float4 a1 = ((const float4*)p1)[ro];
  float4 xr = ((const float4*)xres)[ro];
  float4 bp = ((const float4*)bproj)[t];
  float4 v;
  v.x = a.x+a1.x+xr.x+bp.x; v.y = a.y+a1.y+xr.y+bp.y;
  v.z = a.z+a1.z+xr.z+bp.z; v.w = a.w+a1.w+xr.w+bp.w;
  float s  = v.x+v.y+v.z+v.w;
  float sq = v.x*v.x+v.y*v.y+v.z*v.z+v.w*v.w;
  s = wave_sum(s); sq = wave_sum(sq);
  __shared__ float r1[4], r2[4];
  __shared__ float mean_s, rstd_s, sk_s;
  int lane = t & 63, wid = t >> 6;
  if (lane==0){ r1[wid]=s; r2[wid]=sq; }
  __syncthreads();
  if (t==0){
    float aa = r1[0]+r1[1]+r1[2]+r1[3];
    float cc = r2[0]+r2[1]+r2[2]+r2[3];
    float mean = aa*(1.0f/DMODEL);
    float var  = cc*(1.0f/DMODEL) - mean*mean;
    mean_s = mean; rstd_s = 1.0f/sqrtf(var + 1e-5f);
  }
  __syncthreads();
  float mean = mean_s, rstd = rstd_s;
  float4 g4 = ((const float4*)g)[t];
  float4 b4 = ((const float4*)b)[t];
  float o_[4];
  o_[0] = (v.x-mean)*rstd*g4.x + b4.x;
  o_[1] = (v.y-mean)*rstd*g4.y + b4.y;
  o_[2] = (v.z-mean)*rstd*g4.z + b4.z;
  o_[3] = (v.w-mean)*rstd*g4.w + b4.w;
  bf16x4 h4, l4;
  #pragma unroll
  for (int i=0;i<4;i++){ __bf16 hb=(__bf16)o_[i]; h4[i]=hb; l4[i]=(__bf16)(o_[i]-(float)hb); }
  *(bf16x4*)&oh[(size_t)n*DMODEL + t*4] = h4;
  *(bf16x4*)&ol[(size_t)n*DMODEL + t*4] = l4;
  // router on exact f32 h2
  int d0 = t*4;
  const float* wrp = wr + (size_t)d0*NEXP;
  const float* wnp = wn + (size_t)d0*NEXP;
  const float* wsp = wsk + d0;
  float vals[17];
  #pragma unroll
  for (int i=0;i<17;i++) vals[i]=0.f;
  #pragma unroll
  for (int i=0;i<4;i++){
    #pragma unroll
    for (int e=0;e<NEXP;e++){
      vals[e]   += o_[i]*wrp[i*NEXP+e];
      vals[8+e] += o_[i]*wnp[i*NEXP+e];
    }
    vals[16] += o_[i]*wsp[i];
  }
  __shared__ float red[4][17];
  #pragma unroll
  for (int i=0;i<17;i++){
    float xx = wave_sum(vals[i]);
    if (lane==0) red[wid][i] = xx;
  }
  __syncthreads();
  if (t==0){
    float noisy[NEXP];
    #pragma unroll
    for (int e=0;e<NEXP;e++){
      float lr = red[0][e]+red[1][e]+red[2][e]+red[3][e] + br[e];
      float pn = red[0][8+e]+red[1][8+e]+red[2][8+e]+red[3][8+e] + bn[e];
      float sp = fmaxf(pn,0.f) + log1pf(expf(-fabsf(pn)));
      noisy[e] = lr + noise[(size_t)n*NEXP + e]*sp;
    }
    float sk = red[0][16]+red[1][16]+red[2][16]+red[3][16] + bsk[0];
    sk_s = sk;
    nskv[n] = (sk <= 0.f) ? 1 : 0;
    int i0=0; float v0=noisy[0];
    #pragma unroll
    for (int e=1;e<NEXP;e++) if (noisy[e] > v0){ v0=noisy[e]; i0=e; }
    int i1=-1; float v1=-INFINITY;
    #pragma unroll
    for (int e=0;e<NEXP;e++) if (e!=i0 && noisy[e] > v1){ v1=noisy[e]; i1=e; }
    float tt = expf(v1 - v0);
    idx2[n*2+0]=i0; idx2[n*2+1]=i1;
    gate2[n*2+0]=1.0f/(1.0f+tt); gate2[n*2+1]=tt/(1.0f+tt);
  }
  __syncthreads();
  if (sk_s > 0.f){
    v.x += o_[0]; v.y += o_[1]; v.z += o_[2]; v.w += o_[3];
  }
  ((float4*)out)[ro] = v;
}

// -------- group expert weight transpose-convert: z<G -> ew1[e0+z], else ew2[e0+z-G] --------
__global__ __launch_bounds__(256) void tconv_group(
    const float* __restrict__ ew1, const float* __restrict__ ew2,
    __bf16* __restrict__ e1T, __bf16* __restrict__ e2T, int e0, int G)
{
  __shared__ float tile[64][65];
  int z = blockIdx.z, t = threadIdx.x;
  const float* in; __bf16* out; int K, N, k0, n0;
  if (z < G){
    in = ew1 + (size_t)(e0+z)*DMODEL*DFFD; out = e1T + (size_t)z*DFFD*DMODEL;
    K = DMODEL; N = DFFD; k0 = blockIdx.y*64; n0 = blockIdx.x*64;
  } else {
    in = ew2 + (size_t)(e0+z-G)*DFFD*DMODEL; out = e2T + (size_t)(z-G)*DMODEL*DFFD;
    K = DFFD; N = DMODEL; k0 = blockIdx.x*64; n0 = blockIdx.y*64;
  }
  #pragma unroll
  for (int i=0;i<4;i++){
    int row = (t>>4) + i*16, col = (t&15)*4;
    float4 f = *(const float4*)&in[(size_t)(k0+row)*N + n0 + col];
    tile[row][col]=f.x; tile[row][col+1]=f.y; tile[row][col+2]=f.z; tile[row][col+3]=f.w;
  }
  __syncthreads();
  #pragma unroll
  for (int i=0;i<2;i++){
    int c = t + i*256;
    int orow = c>>3, kg = (c&7)*8;
    bf16x8 hv;
    #pragma unroll
    for (int u=0;u<8;u++) hv[u] = (__bf16)tile[kg+u][orow];
    *(bf16x8*)&out[(size_t)(n0+orow)*K + k0 + kg] = hv;
  }
}

// ------- bf16-pair transpose: qkv v-slice -> vT[1024][4096] -------
__global__ __launch_bounds__(256) void btrans_kernel(
    const __bf16* __restrict__ ih, const __bf16* __restrict__ il, int istride, int icol0,
    __bf16* __restrict__ oh, __bf16* __restrict__ ol){
  __shared__ __bf16 th[64][72], tl[64][72];
  int r0 = blockIdx.x*64, c0 = blockIdx.y*64;
  int t = threadIdx.x;
  {
    int r = t>>2, cg = (t&3)*16;
    size_t go = (size_t)(r0+r)*istride + icol0 + c0 + cg;
    *(bf16x8*)&th[r][cg]   = *(const bf16x8*)&ih[go];
    *(bf16x8*)&th[r][cg+8] = *(const bf16x8*)&ih[go+8];
    *(bf16x8*)&tl[r][cg]   = *(const bf16x8*)&il[go];
    *(bf16x8*)&tl[r][cg+8] = *(const bf16x8*)&il[go+8];
  }
  __syncthreads();
  {
    int c = t>>2, rg = (t&3)*16;
    bf16x8 a,b,e,f;
    #pragma unroll
    for (int u=0;u<8;u++){ a[u]=th[rg+u][c]; b[u]=th[rg+8+u][c]; e[u]=tl[rg+u][c]; f[u]=tl[rg+8+u][c]; }
    size_t go = (size_t)(c0+c)*TOK_N + r0 + rg;
    *(bf16x8*)&oh[go]   = a;
    *(bf16x8*)&oh[go+8] = b;
    *(bf16x8*)&ol[go]   = e;
    *(bf16x8*)&ol[go+8] = f;
  }
}

// ---------------- MFMA GEMM, 128x128, BK=32, dbuf-prefetch, global_load_lds ----------------
// MODE 0: QKV  -> Ch/Cl hi/lo bf16 (N=3072)
// MODE 2: UP   -> Ch = bf16(relu(acc+bias)); A gathered via tok; z = expert-in-group
// MODE 4: DOWN -> Cf partial; z = (group-expert<<2)|kchunk
// MODE 5: PROJK-> Cf partial; z = K-chunk of 512
template<int MODE, bool SPLIT>
__global__ __launch_bounds__(256) void mgemm(
    const __bf16* __restrict__ Ah, const __bf16* __restrict__ Al, int Astride,
    const __bf16* __restrict__ Bh, const __bf16* __restrict__ Bl, int Bstride,
    const float* __restrict__ bias,
    float* __restrict__ Cf, __bf16* __restrict__ Ch, __bf16* __restrict__ Cl,
    int N, int K,
    const int* __restrict__ tok, const __bf16* __restrict__ zbuf)
{
  if constexpr (MODE==2){
    int z = blockIdx.z;
    Bh  += (size_t)z*((size_t)DFFD*DMODEL);
    bias+= (size_t)z*DFFD;
    Ch  += (size_t)z*((size_t)CAPMAX*DFFD);
    tok += z*CAPMAX;
  }
  if constexpr (MODE==4){
    int ge = blockIdx.z>>2, kz = blockIdx.z&3;
    Ah  += (size_t)ge*((size_t)CAPMAX*DFFD) + kz*1024;
    Bh  += (size_t)ge*((size_t)DMODEL*DFFD) + kz*1024;
    Cf  += (size_t)blockIdx.z*((size_t)CAPMAX*DMODEL);
    tok += ge*CAPMAX;
  }
  if constexpr (MODE==5){
    int kz = blockIdx.z;
    Ah += kz*512; Al += kz*512; Bh += kz*512; Bl += kz*512;
    Cf += (size_t)kz*((size_t)TOK_N*DMODEL);
  }
  int m0 = blockIdx.y*128, n0 = blockIdx.x*128;
  if ((MODE==2||MODE==4) && tok[m0] >= TOK_N) return;   // valid slots are a prefix
  __shared__ __align__(16) __bf16 sAh[2*128*32], sBh[2*128*32];
  __shared__ __align__(16) __bf16 sAl[SPLIT?2*128*32:8], sBl[SPLIT?2*128*32:8];
  int t = threadIdx.x, lane = t&63, w = t>>6;
  int wr = w>>1, wc = w&1, fr = lane&15, kb = lane>>4;

  const __bf16* aB[2]; const __bf16* aBl[2]; bool aval[2];
  const __bf16* bB[2]; const __bf16* bBl[2];
  #pragma unroll
  for (int j=0;j<2;j++){
    int c = j*256 + w*64 + lane;
    int row = c>>2, grp = c&3;
    int sg = grp ^ ((row>>1)&3);           // pre-swizzled source chunk (involution)
    if (MODE==2){
      int token = tok[m0+row];
      if (token < TOK_N){ aB[j] = Ah + (size_t)token*Astride + sg*8; aval[j]=true; }
      else              { aB[j] = zbuf + sg*8;                       aval[j]=false; }
    } else {
      aB[j] = Ah + (size_t)(m0+row)*Astride + sg*8; aval[j]=true;
      if (SPLIT) aBl[j] = Al + (size_t)(m0+row)*Astride + sg*8;
    }
    bB[j] = Bh + (size_t)(n0+row)*Bstride + sg*8;
    if (SPLIT) bBl[j] = Bl + (size_t)(n0+row)*Bstride + sg*8;
  }

  auto stage = [&](int buf, int kt){
    int base = buf*(128*32);
    #pragma unroll
    for (int j=0;j<2;j++){
      int cb8 = base + (j*256 + w*64)*8;
      gl16(aB[j] + (aval[j]? kt : 0), &sAh[cb8]);
      gl16(bB[j] + kt, &sBh[cb8]);
      if constexpr (SPLIT){
        gl16(aBl[j] + kt, &sAl[cb8]);
        gl16(bBl[j] + kt, &sBl[cb8]);
      }
    }
  };

  f32x4 acc[4][4];
  #pragma unroll
  for (int mt=0;mt<4;mt++)
    #pragma unroll
    for (int nt=0;nt<4;nt++) acc[mt][nt] = (f32x4){0.f,0.f,0.f,0.f};

  stage(0, 0);
  __syncthreads();
  int nk = K >> 5;
  int xk = (kb ^ ((fr>>1)&3))*8;           // swizzled read slot within row
  for (int ik=0; ik<nk; ik++){
    int cur = ik & 1;
    if (ik+1 < nk) stage(cur^1, (ik+1)<<5);
    int fb = cur*(128*32);
    bf16x8 aFh[4], bFh[4];
    #pragma unroll
    for (int mt=0;mt<4;mt++) aFh[mt] = *(const bf16x8*)&sAh[fb + (wr*64+mt*16+fr)*32 + xk];
    #pragma unroll
    for (int nt=0;nt<4;nt++) bFh[nt] = *(const bf16x8*)&sBh[fb + (wc*64+nt*16+fr)*32 + xk];
    __builtin_amdgcn_s_setprio(1);
    #pragma unroll
    for (int mt=0;mt<4;mt++)
      #pragma unroll
      for (int nt=0;nt<4;nt++)
        acc[mt][nt] = MFMA16(aFh[mt], bFh[nt], acc[mt][nt]);
    __builtin_amdgcn_s_setprio(0);
    if constexpr (SPLIT){
      bf16x8 aFl[4], bFl[4];
      #pragma unroll
      for (int mt=0;mt<4;mt++) aFl[mt] = *(const bf16x8*)&sAl[fb + (wr*64+mt*16+fr)*32 + xk];
      #pragma unroll
      for (int nt=0;nt<4;nt++) bFl[nt] = *(const bf16x8*)&sBl[fb + (wc*64+nt*16+fr)*32 + xk];
      __builtin_amdgcn_s_setprio(1);
      #pragma unroll
      for (int mt=0;mt<4;mt++)
        #pragma unroll
        for (int nt=0;nt<4;nt++){
          acc[mt][nt] = MFMA16(aFh[mt], bFl[nt], acc[mt][nt]);
          acc[mt][nt] = MFMA16(aFl[mt], bFh[nt], acc[mt][nt]);
        }
      __builtin_amdgcn_s_setprio(0);
    }
    __syncthreads();
  }

  #pragma unroll
  for (int mt=0; mt<4; mt++){
    int r0 = m0 + wr*64 + mt*16 + (lane>>4)*4;
    #pragma unroll
    for (int nt=0; nt<4; nt++){
      int col = n0 + wc*64 + nt*16 + fr;
      f32x4 v = acc[mt][nt];
      if constexpr (MODE==0){
        #pragma unroll
        for (int jj=0;jj<4;jj++){
          float val = v[jj];
          __bf16 hb = (__bf16)val;
          size_t idx = (size_t)(r0+jj)*N + col;
          Ch[idx] = hb; Cl[idx] = (__bf16)(val-(float)hb);
        }
      } else if constexpr (MODE==2){
        float bs = bias[col];
        #pragma unroll
        for (int jj=0;jj<4;jj++)
          Ch[(size_t)(r0+jj)*N + col] = (__bf16)fmaxf(v[jj]+bs, 0.f);
      } else {  // MODE 4 / 5: raw partial
        #pragma unroll
        for (int jj=0;jj<4;jj++)
          Cf[(size_t)(r0+jj)*N + col] = v[jj];
      }
    }
  }
}

// ------- per-token gather (race-free): out[n] += sum over this group's picks -------
// tsrc[n][kk] = e*CAPMAX+slot or -1. yk layout [ge*4+kz][CAPMAX][DMODEL].
__global__ __launch_bounds__(256) void gather_kernel(const float* __restrict__ yk,
    const int* __restrict__ tsrc, const float* __restrict__ gselb,
    const float* __restrict__ eb2, int e0, int G, float* __restrict__ out)
{
  int n = blockIdx.x, t = threadIdx.x;
  int s0 = tsrc[n*2], s1 = tsrc[n*2+1];
  float4 o; bool any = false;
  #pragma unroll
  for (int kk=0; kk<2; kk++){
    int src = kk ? s1 : s0;
    if (src < 0) continue;
    int e = src >> 10;
    int ge = e - e0;
    if (ge < 0 || ge >= G) continue;
    int r = src & (CAPMAX-1);
    if (!any){ o = ((const float4*)(out + (size_t)n*DMODEL))[t]; any = true; }
    float g = gselb[src];
    float4 acc = ((const float4*)(eb2 + (size_t)e*DMODEL))[t];
    #pragma unroll
    for (int z=0; z<4; z++){
      float4 p = ((const float4*)(yk + ((size_t)(ge*4+z)*CAPMAX + r)*DMODEL))[t];
      acc.x+=p.x; acc.y+=p.y; acc.z+=p.z; acc.w+=p.w;
    }
    o.x += g*acc.x; o.y += g*acc.y; o.z += g*acc.z; o.w += g*acc.w;
  }
  if (any) ((float4*)(out + (size_t)n*DMODEL))[t] = o;
}

// ---------------- MFMA causal flash attention, split-bf16, swapped operands ----------------
// Each block owns TWO q-tiles (qtA=blk, qtB=blk+8) of one (b,h): K/V staging shared.
__global__ __launch_bounds__(256) void attn_mfma_kernel(
    const __bf16* __restrict__ qkvh, const __bf16* __restrict__ qkvl,
    const __bf16* __restrict__ vth, const __bf16* __restrict__ vtl,
    __bf16* __restrict__ oh, __bf16* __restrict__ ol)
{
  __shared__ __align__(16) __bf16 Kh[2][64*64], Kl[2][64*64], Vh[2][64*64], Vl[2][64*64];
  __shared__ __align__(16) __bf16 Pt[2][4][16*64];
  int qtA = blockIdx.x, qtB = qtA + 8;
  int bh = blockIdx.y;
  int batch = bh>>4, head = bh&15;
  int t = threadIdx.x, lane = t&63, w = t>>6;
  int g = lane>>4, fr = lane&15;
  int col0 = head*64;
  size_t qbaseA = (size_t)(batch*1024 + qtA*64);
  size_t qbaseB = (size_t)(batch*1024 + qtB*64);
  const int QKS = 3*DMODEL;
  const float scale = 0.03125f;              // D^-0.5 = 1/32

  bf16x8 bQhA[2], bQlA[2], bQhB[2], bQlB[2];
  {
    int qrow = w*16 + fr;
    size_t rbA = (qbaseA+qrow)*QKS + col0 + g*8;
    size_t rbB = (qbaseB+qrow)*QKS + col0 + g*8;
    bQhA[0] = *(const bf16x8*)&qkvh[rbA];
    bQhA[1] = *(const bf16x8*)&qkvh[rbA+32];
    bQlA[0] = *(const bf16x8*)&qkvl[rbA];
    bQlA[1] = *(const bf16x8*)&qkvl[rbA+32];
    bQhB[0] = *(const bf16x8*)&qkvh[rbB];
    bQhB[1] = *(const bf16x8*)&qkvh[rbB+32];
    bQlB[0] = *(const bf16x8*)&qkvl[rbB];
    bQlB[1] = *(const bf16x8*)&qkvl[rbB+32];
  }

  auto stageKV = [&](int buf, int kt){
    size_t kbase = (size_t)(batch*1024 + kt*64);
    #pragma unroll
    for (int j=0;j<2;j++){
      int c = j*256 + t, row = c>>3, seg = c&7;
      int lb = (j*256 + w*64)*8;
      size_t gk = (kbase+row)*QKS + 1024 + col0 + ((seg^(row&7))*8);
      gl16(qkvh+gk, &Kh[buf][lb]);
      gl16(qkvl+gk, &Kl[buf][lb]);
      size_t gv = (size_t)(col0+row)*TOK_N + kbase + ((seg^(row&7))*8);
      gl16(vth+gv, &Vh[buf][lb]);
      gl16(vtl+gv, &Vl[buf][lb]);
    }
  };

  float mA = -INFINITY, lA = 0.f, mB = -INFINITY, lB = 0.f;
  f32x4 oA[4], oB[4];
  #pragma unroll
  for (int nt=0;nt<4;nt++){ oA[nt]=(f32x4){0.f,0.f,0.f,0.f}; oB[nt]=(f32x4){0.f,0.f,0.f,0.f}; }

  auto process = [&](int cur, bool diag, bf16x8* bQh, bf16x8* bQl,
                     float& m_, float& l_, f32x4* o_){
    int ntmax = diag ? (w+1) : 4;
    f32x4 s[4];
    #pragma unroll
    for (int nt=0;nt<4;nt++) s[nt]=(f32x4){0.f,0.f,0.f,0.f};
    __builtin_amdgcn_s_setprio(1);
    #pragma unroll
    for (int ks=0; ks<2; ks++){
      #pragma unroll
      for (int nt=0; nt<4; nt++){
        if (nt < ntmax){
          int kvr = nt*16 + fr;
          int sc_ = (ks*4 + g) ^ (kvr&7);
          bf16x8 aKh = *(const bf16x8*)&Kh[cur][kvr*64 + sc_*8];
          bf16x8 aKl = *(const bf16x8*)&Kl[cur][kvr*64 + sc_*8];
          s[nt] = MFMA16(aKh, bQh[ks], s[nt]);
          s[nt] = MFMA16(aKl, bQh[ks], s[nt]);
          s[nt] = MFMA16(aKh, bQl[ks], s[nt]);
        }
      }
    }
    __builtin_amdgcn_s_setprio(0);
    float sv[4][4];
    float mx = -INFINITY;
    int ql = w*16 + fr;
    #pragma unroll
    for (int nt=0;nt<4;nt++)
      #pragma unroll
      for (int j=0;j<4;j++){
        float xv = s[nt][j]*scale;
        if (nt >= ntmax || (diag && (nt*16 + g*4 + j) > ql)) xv = -INFINITY;
        sv[nt][j] = xv;
        mx = fmaxf(mx, xv);
      }
    mx = fmaxf(mx, __shfl_xor(mx,16));
    mx = fmaxf(mx, __shfl_xor(mx,32));
    float nm = fmaxf(m_, mx);
    float scf = __expf(m_ - nm);
    float ps = 0.f;
    #pragma unroll
    for (int nt=0;nt<4;nt++)
      #pragma unroll
      for (int j=0;j<4;j++){
        float p = __expf(sv[nt][j] - nm);
        sv[nt][j] = p;
        ps += p;
      }
    ps += __shfl_xor(ps,16);
    ps += __shfl_xor(ps,32);
    l_ = l_*scf + ps;
    m_ = nm;
    #pragma unroll
    for (int nt=0;nt<4;nt++) o_[nt] = o_[nt]*scf;
    #pragma unroll
    for (int nt=0;nt<4;nt++){
      bf16x4 hv, lv;
      #pragma unroll
      for (int j=0;j<4;j++){
        float pv = sv[nt][j];
        __bf16 hb = (__bf16)pv;
        hv[j] = hb; lv[j] = (__bf16)(pv-(float)hb);
      }
      int el = fr*64 + (((2*nt + (g>>1)) ^ (fr&7))*8) + (g&1)*4;
      *(bf16x4*)&Pt[0][w][el] = hv;
      *(bf16x4*)&Pt[1][w][el] = lv;
    }
    int ksmax = (diag && w < 2) ? 1 : 2;
    __builtin_amdgcn_s_setprio(1);
    #pragma unroll
    for (int ks=0; ks<2; ks++){
      if (ks < ksmax){
        int pc = (4*ks + g) ^ (fr&7);
        bf16x8 bPh = *(const bf16x8*)&Pt[0][w][fr*64 + pc*8];
        bf16x8 bPl = *(const bf16x8*)&Pt[1][w][fr*64 + pc*8];
        #pragma unroll
        for (int nt=0; nt<4; nt++){
          int vr = nt*16 + fr;
          int vc = (ks*4 + g) ^ (vr&7);
          bf16x8 aVh = *(const bf16x8*)&Vh[cur][vr*64 + vc*8];
          bf16x8 aVl = *(const bf16x8*)&Vl[cur][vr*64 + vc*8];
          o_[nt] = MFMA16(aVh, bPh, o_[nt]);
          o_[nt] = MFMA16(aVl, bPh, o_[nt]);
          o_[nt] = MFMA16(aVh, bPl, o_[nt]);
        }
      }
    }
    __builtin_amdgcn_s_setprio(0);
  };

  stageKV(0, 0);
  for (int kt=0; kt<=qtB; kt++){
    int cur = kt&1;
    __syncthreads();
    if (kt < qtB) stageKV(cur^1, kt+1);
    if (kt <= qtA) process(cur, kt==qtA, bQhA, bQlA, mA, lA, oA);
    process(cur, kt==qtB, bQhB, bQlB, mB, lB, oB);
  }

  auto writeOut = [&](size_t qbase, float l_, f32x4* o_){
    float inv = 1.0f/l_;
    #pragma unroll
    for (int nt=0;nt<4;nt++){
      bf16x4 hv, lv;
      #pragma unroll
      for (int j=0;j<4;j++){
        float val = o_[nt][j]*inv;
        __bf16 hb = (__bf16)val;
        hv[j] = hb; lv[j] = (__bf16)(val-(float)hb);
      }
      int el = fr*64 + (((2*nt + (g>>1)) ^ (fr&7))*8) + (g&1)*4;
      *(bf16x4*)&Pt[0][w][el] = hv;
      *(bf16x4*)&Pt[1][w][el] = lv;
    }
    #pragma unroll
    for (int r=0;r<2;r++){
      int c = r*4 + g;
      int el = fr*64 + ((c ^ (fr&7))*8);
      bf16x8 vh = *(const bf16x8*)&Pt[0][w][el];
      bf16x8 vl = *(const bf16x8*)&Pt[1][w][el];
      size_t go = (qbase + w*16 + fr)*DMODEL + col0 + c*8;
      *(bf16x8*)&oh[go] = vh;
      *(bf16x8*)&ol[go] = vl;
    }
  };
  writeOut(qbaseA, lA, oA);
  writeOut(qbaseB, lB, oB);
}

// ---------------- capacity scan + slot assignment (+ tsrc inverse + zero pad) ----------------
__global__ __launch_bounds__(256) void scan_kernel(const int* __restrict__ idx2,
    const float* __restrict__ gate2, const int* __restrict__ nskv,
    int* __restrict__ tok, float* __restrict__ gsel, float* __restrict__ zbuf,
    int* __restrict__ tsrc)
{
  int t = threadIdx.x;
  for (int i=t; i<NEXP*CAPMAX; i+=256){ tok[i]=TOK_N; gsel[i]=0.f; }
  for (int i=t; i<2*TOK_N; i+=256) tsrc[i] = -1;
  for (int i=t; i<1024; i+=256) zbuf[i]=0.f;
  __shared__ int cnts[256][NEXP];
  __shared__ int nns_part[256];
  __shared__ int cap_s;
  int loc[NEXP];
  #pragma unroll
  for (int e=0;e<NEXP;e++) loc[e]=0;
  int nn=0, base = t*16;
  for (int u=0;u<16;u++){
    int n = base+u;
    if (nskv[n]){ nn++; loc[idx2[n*2]]++; loc[idx2[n*2+1]]++; }
  }
  #pragma unroll
  for (int e=0;e<NEXP;e++) cnts[t][e]=loc[e];
  nns_part[t]=nn;
  __syncthreads();
  if (t < NEXP){ int run=0; for (int i=0;i<256;i++){ int c=cnts[i][t]; cnts[i][t]=run; run+=c; } }
  if (t == NEXP){ int sum=0; for (int i=0;i<256;i++) sum+=nns_part[i]; cap_s = sum/4; }
  __syncthreads();
  int capacity = cap_s;
  int run[NEXP];
  #pragma unroll
  for (int e=0;e<NEXP;e++) run[e]=cnts[t][e];
  for (int u=0;u<16;u++){
    int n = base+u;
    if (!nskv[n]) continue;
    #pragma unroll
    for (int kk=0;kk<2;kk++){
      int e = idx2[n*2+kk];
      int r = run[e]++;
      if (r < capacity){
        tok[e*CAPMAX+r]=n; gsel[e*CAPMAX+r]=gate2[n*2+kk];
        tsrc[n*2+kk] = e*CAPMAX + r;
      }
    }
  }
}

extern "C" void kernel_launch(void* const* d_in, const int* in_sizes, int n_in,
                              void* d_out, int out_size, void* d_ws, size_t ws_size,
                              hipStream_t stream) {
  const float* x      = (const float*)d_in[0];
  const float* noise  = (const float*)d_in[1];
  const float* ln1_g  = (const float*)d_in[2];
  const float* ln1_b  = (const float*)d_in[3];
  const float* wq     = (const float*)d_in[4];
  const float* wk     = (const float*)d_in[5];
  const float* wv     = (const float*)d_in[6];
  const float* w_proj = (const float*)d_in[7];
  const float* b_proj = (const float*)d_in[8];
  const float* ln2_g  = (const float*)d_in[9];
  const float* ln2_b  = (const float*)d_in[10];
  const float* w_rout = (const float*)d_in[11];
  const float* b_rout = (const float*)d_in[12];
  const float* w_noi  = (const float*)d_in[13];
  const float* b_noi  = (const float*)d_in[14];
  const float* w_skip = (const float*)d_in[15];
  const float* b_skip = (const float*)d_in[16];
  const float* ew1    = (const float*)d_in[17];
  const float* eb1    = (const float*)d_in[18];
  const float* ew2    = (const float*)d_in[19];
  const float* eb2    = (const float*)d_in[20];
  float* out = (float*)d_out;

  char* ws = (char*)d_ws;
  const size_t MB = 1024*1024;
  // ---- trunk phase (fixed) ----
  __bf16* h_hi   = (__bf16*)(ws + 0*MB);
  __bf16* h_lo   = (__bf16*)(ws + 8*MB);
  __bf16* qkv_hi = (__bf16*)(ws + 16*MB);
  __bf16* qkv_lo = (__bf16*)(ws + 40*MB);
  __bf16* wAllT_h= (__bf16*)(ws + 64*MB);
  __bf16* wAllT_l= (__bf16*)(ws + 72*MB);
  __bf16* vt_hi  = (__bf16*)(ws + 81*MB);
  __bf16* vt_lo  = (__bf16*)(ws + 89*MB);
  float*  pP     = (float*) (ws + 16*MB);    // proj partials (qkv dead)
  __bf16* ao_hi = h_hi, *ao_lo = h_lo;

  // ---- expert-phase tier by ws_size (deterministic; constant across calls) ----
  int G; size_t off_mid, off_yk, off_e1, off_e2, off_meta;
  if (ws_size >= (size_t)338*MB){
    G = 8;  off_mid = 16;  off_yk = 80;  off_e1 = 208; off_e2 = 272; off_meta = 336;
  } else if (ws_size >= (size_t)178*MB){
    G = 4;  off_mid = 16;  off_yk = 48;  off_e1 = 112; off_e2 = 144; off_meta = 176;
  } else {
    G = 2;  off_e1 = 16;  off_e2 = 32;  off_mid = 48;  off_yk = 64;  off_meta = 96;
  }
  __bf16* e1T = (__bf16*)(ws + off_e1*MB);   // [G][DFF][D]
  __bf16* e2T = (__bf16*)(ws + off_e2*MB);   // [G][D][DFF]
  __bf16* mid = (__bf16*)(ws + off_mid*MB);  // [G][CAP][DFF]
  float*  yk  = (float*) (ws + off_yk*MB);   // [4G][CAP][D]
  char* meta = ws + off_meta*MB;
  int*   idx2  = (int*)  (meta);
  float* gate2 = (float*)(meta + 32*1024);
  int*   nskv  = (int*)  (meta + 64*1024);
  int*   tokb  = (int*)  (meta + 80*1024);
  float* gselb = (float*)(meta + 112*1024);
  float* zbuf  = (float*)(meta + 144*1024);
  int*   tsrc  = (int*)  (meta + 160*1024);

  dim3 blk(256);
  prep_kernel<<<5120, blk, 0, stream>>>(wq, wk, wv, w_proj, wAllT_h, wAllT_l,
                                        x, ln1_g, ln1_b, h_hi, h_lo);
  mgemm<0,true><<<dim3(24,32), blk, 0, stream>>>(h_hi, h_lo, DMODEL, wAllT_h, wAllT_l, DMODEL,
      nullptr, nullptr, qkv_hi, qkv_lo, 3*DMODEL, DMODEL, nullptr, nullptr);
  btrans_kernel<<<dim3(64,16), blk, 0, stream>>>(qkv_hi, qkv_lo, 3*DMODEL, 2048, vt_hi, vt_lo);
  attn_mfma_kernel<<<dim3(8,64), blk, 0, stream>>>(qkv_hi, qkv_lo, vt_hi, vt_lo, ao_hi, ao_lo);
  mgemm<5,true><<<dim3(8,32,2), blk, 0, stream>>>(ao_hi, ao_lo, DMODEL,
      wAllT_h + (size_t)3*DMODEL*DMODEL, wAllT_l + (size_t)3*DMODEL*DMODEL, DMODEL,
      nullptr, pP, nullptr, nullptr, DMODEL, 512, nullptr, nullptr);
  ln_router_kernel<<<TOK_N, blk, 0, stream>>>(pP, pP + (size_t)TOK_N*DMODEL, x, b_proj,
      ln2_g, ln2_b, h_hi, h_lo, out,
      w_rout, b_rout, w_noi, b_noi, w_skip, b_skip, noise, idx2, gate2, nskv);
  scan_kernel<<<1, blk, 0, stream>>>(idx2, gate2, nskv, tokb, gselb, zbuf, tsrc);
  // experts in groups of G: tconv -> up -> down(split-K) -> per-token gather
  int ngrp = NEXP / G;
  for (int grp=0; grp<ngrp; grp++){
    int e0 = grp*G;
    tconv_group<<<dim3(64,16,2*G), blk, 0, stream>>>(ew1, ew2, e1T, e2T, e0, G);
    mgemm<2,false><<<dim3(32,8,G), blk, 0, stream>>>(h_hi, nullptr, DMODEL,
        e1T, nullptr, DMODEL, eb1 + (size_t)e0*DFFD,
        nullptr, mid, nullptr, DFFD, DMODEL, tokb + e0*CAPMAX, (const __bf16*)zbuf);
    mgemm<4,false><<<dim3(8,8,4*G), blk, 0, stream>>>(mid, nullptr, DFFD,
        e2T, nullptr, DFFD, nullptr,
        yk, nullptr, nullptr, DMODEL, 1024, tokb + e0*CAPMAX, nullptr);
    gather_kernel<<<TOK_N, blk, 0, stream>>>(yk, tsrc, gselb, eb2, e0, G, out);
  }
}

// Round 11
// 513.106 us; speedup vs baseline: 8.3640x; 1.0311x over previous
//
#include <hip/hip_runtime.h>
#include <math.h>

#define TOK_N   4096
#define DMODEL  1024
#define NEXP    8
#define DFFD    4096
#define CAPMAX  1024

typedef __bf16 bf16x8 __attribute__((ext_vector_type(8)));
typedef __bf16 bf16x4 __attribute__((ext_vector_type(4)));
typedef float  f32x4  __attribute__((ext_vector_type(4)));

__device__ __forceinline__ f32x4 MFMA16(bf16x8 a, bf16x8 b, f32x4 c){
  return __builtin_amdgcn_mfma_f32_16x16x32_bf16(a, b, c, 0, 0, 0);
}

__device__ __forceinline__ void gl16(const __bf16* g, __bf16* l){
  __builtin_amdgcn_global_load_lds(
      (const __attribute__((address_space(1))) unsigned int*)g,
      (__attribute__((address_space(3))) unsigned int*)l, 16, 0, 0);
}

__device__ __forceinline__ float wave_sum(float x){
  #pragma unroll
  for (int o=32;o;o>>=1) x += __shfl_down(x,o);
  return x;
}

// -------- prep: tconv4 (wq/wk/wv/wproj -> wAllT split) + LN1 in one dispatch --------
__global__ __launch_bounds__(256) void prep_kernel(
    const float* __restrict__ wq, const float* __restrict__ wk,
    const float* __restrict__ wv, const float* __restrict__ wp,
    __bf16* __restrict__ dh, __bf16* __restrict__ dl,
    const float* __restrict__ x, const float* __restrict__ g1,
    const float* __restrict__ b1, __bf16* __restrict__ hh, __bf16* __restrict__ hl)
{
  __shared__ float smem[64*65];
  int b = blockIdx.x, t = threadIdx.x;
  if (b < 1024){
    int z = b >> 8, rem = b & 255;
    int k0 = (rem >> 4) * 64, n0 = (rem & 15) * 64;
    const float* in = z==0?wq: z==1?wk: z==2?wv: wp;
    __bf16* oh = dh + (size_t)z*DMODEL*DMODEL;
    __bf16* ol = dl + (size_t)z*DMODEL*DMODEL;
    float (*tile)[65] = (float(*)[65])smem;
    #pragma unroll
    for (int i=0;i<4;i++){
      int row = (t>>4) + i*16, col = (t&15)*4;
      float4 f = *(const float4*)&in[(size_t)(k0+row)*DMODEL + n0 + col];
      tile[row][col]=f.x; tile[row][col+1]=f.y; tile[row][col+2]=f.z; tile[row][col+3]=f.w;
    }
    __syncthreads();
    #pragma unroll
    for (int i=0;i<2;i++){
      int c = t + i*256;
      int orow = c>>3, kg = (c&7)*8;
      bf16x8 hv, lv;
      #pragma unroll
      for (int u=0;u<8;u++){
        float xv = tile[kg+u][orow];
        __bf16 hb = (__bf16)xv;
        hv[u]=hb; lv[u]=(__bf16)(xv-(float)hb);
      }
      *(bf16x8*)&oh[(size_t)(n0+orow)*DMODEL + k0 + kg] = hv;
      *(bf16x8*)&ol[(size_t)(n0+orow)*DMODEL + k0 + kg] = lv;
    }
  } else {
    int n = b - 1024;
    float4 v = ((const float4*)(x + (size_t)n*DMODEL))[t];
    float s  = v.x+v.y+v.z+v.w;
    float sq = v.x*v.x+v.y*v.y+v.z*v.z+v.w*v.w;
    s = wave_sum(s); sq = wave_sum(sq);
    int lane = t & 63, wid = t >> 6;
    if (lane==0){ smem[wid]=s; smem[8+wid]=sq; }
    __syncthreads();
    if (t==0){
      float a = smem[0]+smem[1]+smem[2]+smem[3];
      float c = smem[8]+smem[9]+smem[10]+smem[11];
      float mean = a*(1.0f/DMODEL);
      float var  = c*(1.0f/DMODEL) - mean*mean;
      smem[16] = mean; smem[17] = 1.0f/sqrtf(var + 1e-5f);
    }
    __syncthreads();
    float mean = smem[16], rstd = smem[17];
    float4 g4 = ((const float4*)g1)[t];
    float4 b4 = ((const float4*)b1)[t];
    float o_[4];
    o_[0] = (v.x-mean)*rstd*g4.x + b4.x;
    o_[1] = (v.y-mean)*rstd*g4.y + b4.y;
    o_[2] = (v.z-mean)*rstd*g4.z + b4.z;
    o_[3] = (v.w-mean)*rstd*g4.w + b4.w;
    bf16x4 h4, l4;
    #pragma unroll
    for (int i=0;i<4;i++){ __bf16 hb=(__bf16)o_[i]; h4[i]=hb; l4[i]=(__bf16)(o_[i]-(float)hb); }
    *(bf16x4*)&hh[(size_t)n*DMODEL + t*4] = h4;
    *(bf16x4*)&hl[(size_t)n*DMODEL + t*4] = l4;
  }
}

// -------- proj-epilogue + LN2 + router + out-init fused --------
__global__ __launch_bounds__(256) void ln_router_kernel(
    const float* __restrict__ p0, const float* __restrict__ p1,
    const float* __restrict__ xres, const float* __restrict__ bproj,
    const float* __restrict__ g, const float* __restrict__ b,
    __bf16* __restrict__ oh, __bf16* __restrict__ ol, float* __restrict__ out,
    const float* __restrict__ wr, const float* __restrict__ br,
    const float* __restrict__ wn, const float* __restrict__ bn,
    const float* __restrict__ wsk, const float* __restrict__ bsk,
    const float* __restrict__ noise,
    int* __restrict__ idx2, float* __restrict__ gate2, int* __restrict__ nskv)
{
  int n = blockIdx.x, t = threadIdx.x;
  size_t ro = (size_t)n*DMODEL/4 + t;
  float4 a  = ((const float4*)p0)[ro];
  float4 a1 = ((const float4*)p1)[ro];
  float4 xr = ((const float4*)xres)[ro];
  float4 bp = ((const float4*)bproj)[t];
  float4 v;
  v.x = a.x+a1.x+xr.x+bp.x; v.y = a.y+a1.y+xr.y+bp.y;
  v.z = a.z+a1.z+xr.z+bp.z; v.w = a.w+a1.w+xr.w+bp.w;
  float s  = v.x+v.y+v.z+v.w;
  float sq = v.x*v.x+v.y*v.y+v.z*v.z+v.w*v.w;
  s = wave_sum(s); sq = wave_sum(sq);
  __shared__ float r1[4], r2[4];
  __shared__ float mean_s, rstd_s, sk_s;
  int lane = t & 63, wid = t >> 6;
  if (lane==0){ r1[wid]=s; r2[wid]=sq; }
  __syncthreads();
  if (t==0){
    float aa = r1[0]+r1[1]+r1[2]+r1[3];
    float cc = r2[0]+r2[1]+r2[2]+r2[3];
    float mean = aa*(1.0f/DMODEL);
    float var  = cc*(1.0f/DMODEL) - mean*mean;
    mean_s = mean; rstd_s = 1.0f/sqrtf(var + 1e-5f);
  }
  __syncthreads();
  float mean = mean_s, rstd = rstd_s;
  float4 g4 = ((const float4*)g)[t];
  float4 b4 = ((const float4*)b)[t];
  float o_[4];
  o_[0] = (v.x-mean)*rstd*g4.x + b4.x;
  o_[1] = (v.y-mean)*rstd*g4.y + b4.y;
  o_[2] = (v.z-mean)*rstd*g4.z + b4.z;
  o_[3] = (v.w-mean)*rstd*g4.w + b4.w;
  bf16x4 h4, l4;
  #pragma unroll
  for (int i=0;i<4;i++){ __bf16 hb=(__bf16)o_[i]; h4[i]=hb; l4[i]=(__bf16)(o_[i]-(float)hb); }
  *(bf16x4*)&oh[(size_t)n*DMODEL + t*4] = h4;
  *(bf16x4*)&ol[(size_t)n*DMODEL + t*4] = l4;
  // router on exact f32 h2
  int d0 = t*4;
  const float* wrp = wr + (size_t)d0*NEXP;
  const float* wnp = wn + (size_t)d0*NEXP;
  const float* wsp = wsk + d0;
  float vals[17];
  #pragma unroll
  for (int i=0;i<17;i++) vals[i]=0.f;
  #pragma unroll
  for (int i=0;i<4;i++){
    #pragma unroll
    for (int e=0;e<NEXP;e++){
      vals[e]   += o_[i]*wrp[i*NEXP+e];
      vals[8+e] += o_[i]*wnp[i*NEXP+e];
    }
    vals[16] += o_[i]*wsp[i];
  }
  __shared__ float red[4][17];
  #pragma unroll
  for (int i=0;i<17;i++){
    float xx = wave_sum(vals[i]);
    if (lane==0) red[wid][i] = xx;
  }
  __syncthreads();
  if (t==0){
    float noisy[NEXP];
    #pragma unroll
    for (int e=0;e<NEXP;e++){
      float lr = red[0][e]+red[1][e]+red[2][e]+red[3][e] + br[e];
      float pn = red[0][8+e]+red[1][8+e]+red[2][8+e]+red[3][8+e] + bn[e];
      float sp = fmaxf(pn,0.f) + log1pf(expf(-fabsf(pn)));
      noisy[e] = lr + noise[(size_t)n*NEXP + e]*sp;
    }
    float sk = red[0][16]+red[1][16]+red[2][16]+red[3][16] + bsk[0];
    sk_s = sk;
    nskv[n] = (sk <= 0.f) ? 1 : 0;
    int i0=0; float v0=noisy[0];
    #pragma unroll
    for (int e=1;e<NEXP;e++) if (noisy[e] > v0){ v0=noisy[e]; i0=e; }
    int i1=-1; float v1=-INFINITY;
    #pragma unroll
    for (int e=0;e<NEXP;e++) if (e!=i0 && noisy[e] > v1){ v1=noisy[e]; i1=e; }
    float tt = expf(v1 - v0);
    idx2[n*2+0]=i0; idx2[n*2+1]=i1;
    gate2[n*2+0]=1.0f/(1.0f+tt); gate2[n*2+1]=tt/(1.0f+tt);
  }
  __syncthreads();
  if (sk_s > 0.f){
    v.x += o_[0]; v.y += o_[1]; v.z += o_[2]; v.w += o_[3];
  }
  ((float4*)out)[ro] = v;
}

// -------- group expert weight transpose-convert: z<G -> ew1[e0+z], else ew2[e0+z-G] --------
__global__ __launch_bounds__(256) void tconv_group(
    const float* __restrict__ ew1, const float* __restrict__ ew2,
    __bf16* __restrict__ e1T, __bf16* __restrict__ e2T, int e0, int G)
{
  __shared__ float tile[64][65];
  int z = blockIdx.z, t = threadIdx.x;
  const float* in; __bf16* out; int K, N, k0, n0;
  if (z < G){
    in = ew1 + (size_t)(e0+z)*DMODEL*DFFD; out = e1T + (size_t)z*DFFD*DMODEL;
    K = DMODEL; N = DFFD; k0 = blockIdx.y*64; n0 = blockIdx.x*64;
  } else {
    in = ew2 + (size_t)(e0+z-G)*DFFD*DMODEL; out = e2T + (size_t)(z-G)*DMODEL*DFFD;
    K = DFFD; N = DMODEL; k0 = blockIdx.x*64; n0 = blockIdx.y*64;
  }
  #pragma unroll
  for (int i=0;i<4;i++){
    int row = (t>>4) + i*16, col = (t&15)*4;
    float4 f = *(const float4*)&in[(size_t)(k0+row)*N + n0 + col];
    tile[row][col]=f.x; tile[row][col+1]=f.y; tile[row][col+2]=f.z; tile[row][col+3]=f.w;
  }
  __syncthreads();
  #pragma unroll
  for (int i=0;i<2;i++){
    int c = t + i*256;
    int orow = c>>3, kg = (c&7)*8;
    bf16x8 hv;
    #pragma unroll
    for (int u=0;u<8;u++) hv[u] = (__bf16)tile[kg+u][orow];
    *(bf16x8*)&out[(size_t)(n0+orow)*K + k0 + kg] = hv;
  }
}

// ------- bf16-pair transpose: qkv v-slice -> vT[1024][4096] -------
__global__ __launch_bounds__(256) void btrans_kernel(
    const __bf16* __restrict__ ih, const __bf16* __restrict__ il, int istride, int icol0,
    __bf16* __restrict__ oh, __bf16* __restrict__ ol){
  __shared__ __bf16 th[64][72], tl[64][72];
  int r0 = blockIdx.x*64, c0 = blockIdx.y*64;
  int t = threadIdx.x;
  {
    int r = t>>2, cg = (t&3)*16;
    size_t go = (size_t)(r0+r)*istride + icol0 + c0 + cg;
    *(bf16x8*)&th[r][cg]   = *(const bf16x8*)&ih[go];
    *(bf16x8*)&th[r][cg+8] = *(const bf16x8*)&ih[go+8];
    *(bf16x8*)&tl[r][cg]   = *(const bf16x8*)&il[go];
    *(bf16x8*)&tl[r][cg+8] = *(const bf16x8*)&il[go+8];
  }
  __syncthreads();
  {
    int c = t>>2, rg = (t&3)*16;
    bf16x8 a,b,e,f;
    #pragma unroll
    for (int u=0;u<8;u++){ a[u]=th[rg+u][c]; b[u]=th[rg+8+u][c]; e[u]=tl[rg+u][c]; f[u]=tl[rg+8+u][c]; }
    size_t go = (size_t)(c0+c)*TOK_N + r0 + rg;
    *(bf16x8*)&oh[go]   = a;
    *(bf16x8*)&oh[go+8] = b;
    *(bf16x8*)&ol[go]   = e;
    *(bf16x8*)&ol[go+8] = f;
  }
}

// ---------------- MFMA GEMM, 128x128, BK=32, counted-vmcnt pipeline (T3/T4) ----------------
// Per K-step: waitcnt vmcnt(LOADS) -> barrier -> ds_read frags -> lgkmcnt(0) -> barrier
//             -> re-stage buf[cur] for k+2 (loads stay in flight across barriers) -> MFMA.
// MODE 0: QKV  -> Ch/Cl hi/lo bf16 (N=3072)
// MODE 2: UP   -> Ch = bf16(relu(acc+bias)); A gathered via tok; z = expert-in-group
// MODE 4: DOWN -> Cf partial; z = (group-expert<<2)|kchunk
// MODE 5: PROJK-> Cf partial; z = K-chunk of 512
template<int MODE, bool SPLIT>
__global__ __launch_bounds__(256) void mgemm(
    const __bf16* __restrict__ Ah, const __bf16* __restrict__ Al, int Astride,
    const __bf16* __restrict__ Bh, const __bf16* __restrict__ Bl, int Bstride,
    const float* __restrict__ bias,
    float* __restrict__ Cf, __bf16* __restrict__ Ch, __bf16* __restrict__ Cl,
    int N, int K,
    const int* __restrict__ tok, const __bf16* __restrict__ zbuf)
{
  if constexpr (MODE==2){
    int z = blockIdx.z;
    Bh  += (size_t)z*((size_t)DFFD*DMODEL);
    bias+= (size_t)z*DFFD;
    Ch  += (size_t)z*((size_t)CAPMAX*DFFD);
    tok += z*CAPMAX;
  }
  if constexpr (MODE==4){
    int ge = blockIdx.z>>2, kz = blockIdx.z&3;
    Ah  += (size_t)ge*((size_t)CAPMAX*DFFD) + kz*1024;
    Bh  += (size_t)ge*((size_t)DMODEL*DFFD) + kz*1024;
    Cf  += (size_t)blockIdx.z*((size_t)CAPMAX*DMODEL);
    tok += ge*CAPMAX;
  }
  if constexpr (MODE==5){
    int kz = blockIdx.z;
    Ah += kz*512; Al += kz*512; Bh += kz*512; Bl += kz*512;
    Cf += (size_t)kz*((size_t)TOK_N*DMODEL);
  }
  int m0 = blockIdx.y*128, n0 = blockIdx.x*128;
  if ((MODE==2||MODE==4) && tok[m0] >= TOK_N) return;   // valid slots are a prefix (before any barrier)
  __shared__ __align__(16) __bf16 sAh[2*128*32], sBh[2*128*32];
  __shared__ __align__(16) __bf16 sAl[SPLIT?2*128*32:8], sBl[SPLIT?2*128*32:8];
  int t = threadIdx.x, lane = t&63, w = t>>6;
  int wr = w>>1, wc = w&1, fr = lane&15, kb = lane>>4;

  const __bf16* aB[2]; const __bf16* aBl[2]; bool aval[2];
  const __bf16* bB[2]; const __bf16* bBl[2];
  #pragma unroll
  for (int j=0;j<2;j++){
    int c = j*256 + w*64 + lane;
    int row = c>>2, grp = c&3;
    int sg = grp ^ ((row>>1)&3);           // pre-swizzled source chunk (involution)
    if (MODE==2){
      int token = tok[m0+row];
      if (token < TOK_N){ aB[j] = Ah + (size_t)token*Astride + sg*8; aval[j]=true; }
      else              { aB[j] = zbuf + sg*8;                       aval[j]=false; }
    } else {
      aB[j] = Ah + (size_t)(m0+row)*Astride + sg*8; aval[j]=true;
      if (SPLIT) aBl[j] = Al + (size_t)(m0+row)*Astride + sg*8;
    }
    bB[j] = Bh + (size_t)(n0+row)*Bstride + sg*8;
    if (SPLIT) bBl[j] = Bl + (size_t)(n0+row)*Bstride + sg*8;
  }

  auto stage = [&](int buf, int kt){       // SPLIT: 8 vmem ops/wave; else 4
    int base = buf*(128*32);
    #pragma unroll
    for (int j=0;j<2;j++){
      int cb8 = base + (j*256 + w*64)*8;
      gl16(aB[j] + (aval[j]? kt : 0), &sAh[cb8]);
      gl16(bB[j] + kt, &sBh[cb8]);
      if constexpr (SPLIT){
        gl16(aBl[j] + kt, &sAl[cb8]);
        gl16(bBl[j] + kt, &sBl[cb8]);
      }
    }
  };

  f32x4 acc[4][4];
  #pragma unroll
  for (int mt=0;mt<4;mt++)
    #pragma unroll
    for (int nt=0;nt<4;nt++) acc[mt][nt] = (f32x4){0.f,0.f,0.f,0.f};

  int nk = K >> 5;
  stage(0, 0);
  stage(1, 32);                            // all shapes have nk >= 16
  int xk = (kb ^ ((fr>>1)&3))*8;           // swizzled read slot within row
  for (int ik=0; ik<nk; ik++){
    int cur = ik & 1;
    // wait for buf[cur]'s loads (oldest in the vmcnt FIFO); keep newer stage in flight
    if (ik+1 < nk){
      if constexpr (SPLIT) asm volatile("s_waitcnt vmcnt(8)" ::: "memory");
      else                 asm volatile("s_waitcnt vmcnt(4)" ::: "memory");
    } else {
      asm volatile("s_waitcnt vmcnt(0)" ::: "memory");
    }
    __builtin_amdgcn_s_barrier();          // every wave has its cur-buffer complete
    int fb = cur*(128*32);
    bf16x8 aFh[4], bFh[4];
    bf16x8 aFl[SPLIT?4:1], bFl[SPLIT?4:1];
    #pragma unroll
    for (int mt=0;mt<4;mt++) aFh[mt] = *(const bf16x8*)&sAh[fb + (wr*64+mt*16+fr)*32 + xk];
    #pragma unroll
    for (int nt=0;nt<4;nt++) bFh[nt] = *(const bf16x8*)&sBh[fb + (wc*64+nt*16+fr)*32 + xk];
    if constexpr (SPLIT){
      #pragma unroll
      for (int mt=0;mt<4;mt++) aFl[mt] = *(const bf16x8*)&sAl[fb + (wr*64+mt*16+fr)*32 + xk];
      #pragma unroll
      for (int nt=0;nt<4;nt++) bFl[nt] = *(const bf16x8*)&sBl[fb + (wc*64+nt*16+fr)*32 + xk];
    }
    asm volatile("s_waitcnt lgkmcnt(0)" ::: "memory");   // frags landed in regs
    __builtin_amdgcn_sched_barrier(0);                    // rule #18 fence
    __builtin_amdgcn_s_barrier();          // no wave still reading buf[cur]
    if (ik+2 < nk) stage(cur, (ik+2)<<5);  // refill cur; flies under MFMA + next step
    __builtin_amdgcn_s_setprio(1);
    #pragma unroll
    for (int mt=0;mt<4;mt++)
      #pragma unroll
      for (int nt=0;nt<4;nt++)
        acc[mt][nt] = MFMA16(aFh[mt], bFh[nt], acc[mt][nt]);
    if constexpr (SPLIT){
      #pragma unroll
      for (int mt=0;mt<4;mt++)
        #pragma unroll
        for (int nt=0;nt<4;nt++){
          acc[mt][nt] = MFMA16(aFh[mt], bFl[nt], acc[mt][nt]);
          acc[mt][nt] = MFMA16(aFl[mt], bFh[nt], acc[mt][nt]);
        }
    }
    __builtin_amdgcn_s_setprio(0);
  }

  #pragma unroll
  for (int mt=0; mt<4; mt++){
    int r0 = m0 + wr*64 + mt*16 + (lane>>4)*4;
    #pragma unroll
    for (int nt=0; nt<4; nt++){
      int col = n0 + wc*64 + nt*16 + fr;
      f32x4 v = acc[mt][nt];
      if constexpr (MODE==0){
        #pragma unroll
        for (int jj=0;jj<4;jj++){
          float val = v[jj];
          __bf16 hb = (__bf16)val;
          size_t idx = (size_t)(r0+jj)*N + col;
          Ch[idx] = hb; Cl[idx] = (__bf16)(val-(float)hb);
        }
      } else if constexpr (MODE==2){
        float bs = bias[col];
        #pragma unroll
        for (int jj=0;jj<4;jj++)
          Ch[(size_t)(r0+jj)*N + col] = (__bf16)fmaxf(v[jj]+bs, 0.f);
      } else {  // MODE 4 / 5: raw partial
        #pragma unroll
        for (int jj=0;jj<4;jj++)
          Cf[(size_t)(r0+jj)*N + col] = v[jj];
      }
    }
  }
}

// ------- per-token gather (race-free): out[n] += sum over this group's picks -------
__global__ __launch_bounds__(256) void gather_kernel(const float* __restrict__ yk,
    const int* __restrict__ tsrc, const float* __restrict__ gselb,
    const float* __restrict__ eb2, int e0, int G, float* __restrict__ out)
{
  int n = blockIdx.x, t = threadIdx.x;
  int s0 = tsrc[n*2], s1 = tsrc[n*2+1];
  float4 o; bool any = false;
  #pragma unroll
  for (int kk=0; kk<2; kk++){
    int src = kk ? s1 : s0;
    if (src < 0) continue;
    int e = src >> 10;
    int ge = e - e0;
    if (ge < 0 || ge >= G) continue;
    int r = src & (CAPMAX-1);
    if (!any){ o = ((const float4*)(out + (size_t)n*DMODEL))[t]; any = true; }
    float g = gselb[src];
    float4 acc = ((const float4*)(eb2 + (size_t)e*DMODEL))[t];
    #pragma unroll
    for (int z=0; z<4; z++){
      float4 p = ((const float4*)(yk + ((size_t)(ge*4+z)*CAPMAX + r)*DMODEL))[t];
      acc.x+=p.x; acc.y+=p.y; acc.z+=p.z; acc.w+=p.w;
    }
    o.x += g*acc.x; o.y += g*acc.y; o.z += g*acc.z; o.w += g*acc.w;
  }
  if (any) ((float4*)(out + (size_t)n*DMODEL))[t] = o;
}

// ---------------- MFMA causal flash attention, split-bf16, swapped operands ----------------
__global__ __launch_bounds__(256) void attn_mfma_kernel(
    const __bf16* __restrict__ qkvh, const __bf16* __restrict__ qkvl,
    const __bf16* __restrict__ vth, const __bf16* __restrict__ vtl,
    __bf16* __restrict__ oh, __bf16* __restrict__ ol)
{
  __shared__ __align__(16) __bf16 Kh[2][64*64], Kl[2][64*64], Vh[2][64*64], Vl[2][64*64];
  __shared__ __align__(16) __bf16 Pt[2][4][16*64];
  int qtA = blockIdx.x, qtB = qtA + 8;
  int bh = blockIdx.y;
  int batch = bh>>4, head = bh&15;
  int t = threadIdx.x, lane = t&63, w = t>>6;
  int g = lane>>4, fr = lane&15;
  int col0 = head*64;
  size_t qbaseA = (size_t)(batch*1024 + qtA*64);
  size_t qbaseB = (size_t)(batch*1024 + qtB*64);
  const int QKS = 3*DMODEL;
  const float scale = 0.03125f;              // D^-0.5 = 1/32

  bf16x8 bQhA[2], bQlA[2], bQhB[2], bQlB[2];
  {
    int qrow = w*16 + fr;
    size_t rbA = (qbaseA+qrow)*QKS + col0 + g*8;
    size_t rbB = (qbaseB+qrow)*QKS + col0 + g*8;
    bQhA[0] = *(const bf16x8*)&qkvh[rbA];
    bQhA[1] = *(const bf16x8*)&qkvh[rbA+32];
    bQlA[0] = *(const bf16x8*)&qkvl[rbA];
    bQlA[1] = *(const bf16x8*)&qkvl[rbA+32];
    bQhB[0] = *(const bf16x8*)&qkvh[rbB];
    bQhB[1] = *(const bf16x8*)&qkvh[rbB+32];
    bQlB[0] = *(const bf16x8*)&qkvl[rbB];
    bQlB[1] = *(const bf16x8*)&qkvl[rbB+32];
  }

  auto stageKV = [&](int buf, int kt){
    size_t kbase = (size_t)(batch*1024 + kt*64);
    #pragma unroll
    for (int j=0;j<2;j++){
      int c = j*256 + t, row = c>>3, seg = c&7;
      int lb = (j*256 + w*64)*8;
      size_t gk = (kbase+row)*QKS + 1024 + col0 + ((seg^(row&7))*8);
      gl16(qkvh+gk, &Kh[buf][lb]);
      gl16(qkvl+gk, &Kl[buf][lb]);
      size_t gv = (size_t)(col0+row)*TOK_N + kbase + ((seg^(row&7))*8);
      gl16(vth+gv, &Vh[buf][lb]);
      gl16(vtl+gv, &Vl[buf][lb]);
    }
  };

  float mA = -INFINITY, lA = 0.f, mB = -INFINITY, lB = 0.f;
  f32x4 oA[4], oB[4];
  #pragma unroll
  for (int nt=0;nt<4;nt++){ oA[nt]=(f32x4){0.f,0.f,0.f,0.f}; oB[nt]=(f32x4){0.f,0.f,0.f,0.f}; }

  auto process = [&](int cur, bool diag, bf16x8* bQh, bf16x8* bQl,
                     float& m_, float& l_, f32x4* o_){
    int ntmax = diag ? (w+1) : 4;
    f32x4 s[4];
    #pragma unroll
    for (int nt=0;nt<4;nt++) s[nt]=(f32x4){0.f,0.f,0.f,0.f};
    __builtin_amdgcn_s_setprio(1);
    #pragma unroll
    for (int ks=0; ks<2; ks++){
      #pragma unroll
      for (int nt=0; nt<4; nt++){
        if (nt < ntmax){
          int kvr = nt*16 + fr;
          int sc_ = (ks*4 + g) ^ (kvr&7);
          bf16x8 aKh = *(const bf16x8*)&Kh[cur][kvr*64 + sc_*8];
          bf16x8 aKl = *(const bf16x8*)&Kl[cur][kvr*64 + sc_*8];
          s[nt] = MFMA16(aKh, bQh[ks], s[nt]);
          s[nt] = MFMA16(aKl, bQh[ks], s[nt]);
          s[nt] = MFMA16(aKh, bQl[ks], s[nt]);
        }
      }
    }
    __builtin_amdgcn_s_setprio(0);
    float sv[4][4];
    float mx = -INFINITY;
    int ql = w*16 + fr;
    #pragma unroll
    for (int nt=0;nt<4;nt++)
      #pragma unroll
      for (int j=0;j<4;j++){
        float xv = s[nt][j]*scale;
        if (nt >= ntmax || (diag && (nt*16 + g*4 + j) > ql)) xv = -INFINITY;
        sv[nt][j] = xv;
        mx = fmaxf(mx, xv);
      }
    mx = fmaxf(mx, __shfl_xor(mx,16));
    mx = fmaxf(mx, __shfl_xor(mx,32));
    float nm = fmaxf(m_, mx);
    float scf = __expf(m_ - nm);
    float ps = 0.f;
    #pragma unroll
    for (int nt=0;nt<4;nt++)
      #pragma unroll
      for (int j=0;j<4;j++){
        float p = __expf(sv[nt][j] - nm);
        sv[nt][j] = p;
        ps += p;
      }
    ps += __shfl_xor(ps,16);
    ps += __shfl_xor(ps,32);
    l_ = l_*scf + ps;
    m_ = nm;
    #pragma unroll
    for (int nt=0;nt<4;nt++) o_[nt] = o_[nt]*scf;
    #pragma unroll
    for (int nt=0;nt<4;nt++){
      bf16x4 hv, lv;
      #pragma unroll
      for (int j=0;j<4;j++){
        float pv = sv[nt][j];
        __bf16 hb = (__bf16)pv;
        hv[j] = hb; lv[j] = (__bf16)(pv-(float)hb);
      }
      int el = fr*64 + (((2*nt + (g>>1)) ^ (fr&7))*8) + (g&1)*4;
      *(bf16x4*)&Pt[0][w][el] = hv;
      *(bf16x4*)&Pt[1][w][el] = lv;
    }
    int ksmax = (diag && w < 2) ? 1 : 2;
    __builtin_amdgcn_s_setprio(1);
    #pragma unroll
    for (int ks=0; ks<2; ks++){
      if (ks < ksmax){
        int pc = (4*ks + g) ^ (fr&7);
        bf16x8 bPh = *(const bf16x8*)&Pt[0][w][fr*64 + pc*8];
        bf16x8 bPl = *(const bf16x8*)&Pt[1][w][fr*64 + pc*8];
        #pragma unroll
        for (int nt=0; nt<4; nt++){
          int vr = nt*16 + fr;
          int vc = (ks*4 + g) ^ (vr&7);
          bf16x8 aVh = *(const bf16x8*)&Vh[cur][vr*64 + vc*8];
          bf16x8 aVl = *(const bf16x8*)&Vl[cur][vr*64 + vc*8];
          o_[nt] = MFMA16(aVh, bPh, o_[nt]);
          o_[nt] = MFMA16(aVl, bPh, o_[nt]);
          o_[nt] = MFMA16(aVh, bPl, o_[nt]);
        }
      }
    }
    __builtin_amdgcn_s_setprio(0);
  };

  stageKV(0, 0);
  for (int kt=0; kt<=qtB; kt++){
    int cur = kt&1;
    __syncthreads();
    if (kt < qtB) stageKV(cur^1, kt+1);
    if (kt <= qtA) process(cur, kt==qtA, bQhA, bQlA, mA, lA, oA);
    process(cur, kt==qtB, bQhB, bQlB, mB, lB, oB);
  }

  auto writeOut = [&](size_t qbase, float l_, f32x4* o_){
    float inv = 1.0f/l_;
    #pragma unroll
    for (int nt=0;nt<4;nt++){
      bf16x4 hv, lv;
      #pragma unroll
      for (int j=0;j<4;j++){
        float val = o_[nt][j]*inv;
        __bf16 hb = (__bf16)val;
        hv[j] = hb; lv[j] = (__bf16)(val-(float)hb);
      }
      int el = fr*64 + (((2*nt + (g>>1)) ^ (fr&7))*8) + (g&1)*4;
      *(bf16x4*)&Pt[0][w][el] = hv;
      *(bf16x4*)&Pt[1][w][el] = lv;
    }
    #pragma unroll
    for (int r=0;r<2;r++){
      int c = r*4 + g;
      int el = fr*64 + ((c ^ (fr&7))*8);
      bf16x8 vh = *(const bf16x8*)&Pt[0][w][el];
      bf16x8 vl = *(const bf16x8*)&Pt[1][w][el];
      size_t go = (qbase + w*16 + fr)*DMODEL + col0 + c*8;
      *(bf16x8*)&oh[go] = vh;
      *(bf16x8*)&ol[go] = vl;
    }
  };
  writeOut(qbaseA, lA, oA);
  writeOut(qbaseB, lB, oB);
}

// ---------------- capacity scan + slot assignment (+ tsrc inverse + zero pad) ----------------
__global__ __launch_bounds__(256) void scan_kernel(const int* __restrict__ idx2,
    const float* __restrict__ gate2, const int* __restrict__ nskv,
    int* __restrict__ tok, float* __restrict__ gsel, float* __restrict__ zbuf,
    int* __restrict__ tsrc)
{
  int t = threadIdx.x;
  for (int i=t; i<NEXP*CAPMAX; i+=256){ tok[i]=TOK_N; gsel[i]=0.f; }
  for (int i=t; i<2*TOK_N; i+=256) tsrc[i] = -1;
  for (int i=t; i<1024; i+=256) zbuf[i]=0.f;
  __shared__ int cnts[256][NEXP];
  __shared__ int nns_part[256];
  __shared__ int cap_s;
  int loc[NEXP];
  #pragma unroll
  for (int e=0;e<NEXP;e++) loc[e]=0;
  int nn=0, base = t*16;
  for (int u=0;u<16;u++){
    int n = base+u;
    if (nskv[n]){ nn++; loc[idx2[n*2]]++; loc[idx2[n*2+1]]++; }
  }
  #pragma unroll
  for (int e=0;e<NEXP;e++) cnts[t][e]=loc[e];
  nns_part[t]=nn;
  __syncthreads();
  if (t < NEXP){ int run=0; for (int i=0;i<256;i++){ int c=cnts[i][t]; cnts[i][t]=run; run+=c; } }
  if (t == NEXP){ int sum=0; for (int i=0;i<256;i++) sum+=nns_part[i]; cap_s = sum/4; }
  __syncthreads();
  int capacity = cap_s;
  int run[NEXP];
  #pragma unroll
  for (int e=0;e<NEXP;e++) run[e]=cnts[t][e];
  for (int u=0;u<16;u++){
    int n = base+u;
    if (!nskv[n]) continue;
    #pragma unroll
    for (int kk=0;kk<2;kk++){
      int e = idx2[n*2+kk];
      int r = run[e]++;
      if (r < capacity){
        tok[e*CAPMAX+r]=n; gsel[e*CAPMAX+r]=gate2[n*2+kk];
        tsrc[n*2+kk] = e*CAPMAX + r;
      }
    }
  }
}

extern "C" void kernel_launch(void* const* d_in, const int* in_sizes, int n_in,
                              void* d_out, int out_size, void* d_ws, size_t ws_size,
                              hipStream_t stream) {
  const float* x      = (const float*)d_in[0];
  const float* noise  = (const float*)d_in[1];
  const float* ln1_g  = (const float*)d_in[2];
  const float* ln1_b  = (const float*)d_in[3];
  const float* wq     = (const float*)d_in[4];
  const float* wk     = (const float*)d_in[5];
  const float* wv     = (const float*)d_in[6];
  const float* w_proj = (const float*)d_in[7];
  const float* b_proj = (const float*)d_in[8];
  const float* ln2_g  = (const float*)d_in[9];
  const float* ln2_b  = (const float*)d_in[10];
  const float* w_rout = (const float*)d_in[11];
  const float* b_rout = (const float*)d_in[12];
  const float* w_noi  = (const float*)d_in[13];
  const float* b_noi  = (const float*)d_in[14];
  const float* w_skip = (const float*)d_in[15];
  const float* b_skip = (const float*)d_in[16];
  const float* ew1    = (const float*)d_in[17];
  const float* eb1    = (const float*)d_in[18];
  const float* ew2    = (const float*)d_in[19];
  const float* eb2    = (const float*)d_in[20];
  float* out = (float*)d_out;

  char* ws = (char*)d_ws;
  const size_t MB = 1024*1024;
  // ---- trunk phase (fixed) ----
  __bf16* h_hi   = (__bf16*)(ws + 0*MB);
  __bf16* h_lo   = (__bf16*)(ws + 8*MB);
  __bf16* qkv_hi = (__bf16*)(ws + 16*MB);
  __bf16* qkv_lo = (__bf16*)(ws + 40*MB);
  __bf16* wAllT_h= (__bf16*)(ws + 64*MB);
  __bf16* wAllT_l= (__bf16*)(ws + 72*MB);
  __bf16* vt_hi  = (__bf16*)(ws + 81*MB);
  __bf16* vt_lo  = (__bf16*)(ws + 89*MB);
  float*  pP     = (float*) (ws + 16*MB);    // proj partials (qkv dead)
  __bf16* ao_hi = h_hi, *ao_lo = h_lo;

  // ---- expert-phase tier by ws_size (deterministic; constant across calls) ----
  int G; size_t off_mid, off_yk, off_e1, off_e2, off_meta;
  if (ws_size >= (size_t)338*MB){
    G = 8;  off_mid = 16;  off_yk = 80;  off_e1 = 208; off_e2 = 272; off_meta = 336;
  } else if (ws_size >= (size_t)178*MB){
    G = 4;  off_mid = 16;  off_yk = 48;  off_e1 = 112; off_e2 = 144; off_meta = 176;
  } else {
    G = 2;  off_e1 = 16;  off_e2 = 32;  off_mid = 48;  off_yk = 64;  off_meta = 96;
  }
  __bf16* e1T = (__bf16*)(ws + off_e1*MB);   // [G][DFF][D]
  __bf16* e2T = (__bf16*)(ws + off_e2*MB);   // [G][D][DFF]
  __bf16* mid = (__bf16*)(ws + off_mid*MB);  // [G][CAP][DFF]
  float*  yk  = (float*) (ws + off_yk*MB);   // [4G][CAP][D]
  char* meta = ws + off_meta*MB;
  int*   idx2  = (int*)  (meta);
  float* gate2 = (float*)(meta + 32*1024);
  int*   nskv  = (int*)  (meta + 64*1024);
  int*   tokb  = (int*)  (meta + 80*1024);
  float* gselb = (float*)(meta + 112*1024);
  float* zbuf  = (float*)(meta + 144*1024);
  int*   tsrc  = (int*)  (meta + 160*1024);

  dim3 blk(256);
  prep_kernel<<<5120, blk, 0, stream>>>(wq, wk, wv, w_proj, wAllT_h, wAllT_l,
                                        x, ln1_g, ln1_b, h_hi, h_lo);
  mgemm<0,true><<<dim3(24,32), blk, 0, stream>>>(h_hi, h_lo, DMODEL, wAllT_h, wAllT_l, DMODEL,
      nullptr, nullptr, qkv_hi, qkv_lo, 3*DMODEL, DMODEL, nullptr, nullptr);
  btrans_kernel<<<dim3(64,16), blk, 0, stream>>>(qkv_hi, qkv_lo, 3*DMODEL, 2048, vt_hi, vt_lo);
  attn_mfma_kernel<<<dim3(8,64), blk, 0, stream>>>(qkv_hi, qkv_lo, vt_hi, vt_lo, ao_hi, ao_lo);
  mgemm<5,true><<<dim3(8,32,2), blk, 0, stream>>>(ao_hi, ao_lo, DMODEL,
      wAllT_h + (size_t)3*DMODEL*DMODEL, wAllT_l + (size_t)3*DMODEL*DMODEL, DMODEL,
      nullptr, pP, nullptr, nullptr, DMODEL, 512, nullptr, nullptr);
  ln_router_kernel<<<TOK_N, blk, 0, stream>>>(pP, pP + (size_t)TOK_N*DMODEL, x, b_proj,
      ln2_g, ln2_b, h_hi, h_lo, out,
      w_rout, b_rout, w_noi, b_noi, w_skip, b_skip, noise, idx2, gate2, nskv);
  scan_kernel<<<1, blk, 0, stream>>>(idx2, gate2, nskv, tokb, gselb, zbuf, tsrc);
  // experts in groups of G: tconv -> up -> down(split-K) -> per-token gather
  int ngrp = NEXP / G;
  for (int grp=0; grp<ngrp; grp++){
    int e0 = grp*G;
    tconv_group<<<dim3(64,16,2*G), blk, 0, stream>>>(ew1, ew2, e1T, e2T, e0, G);
    mgemm<2,false><<<dim3(32,8,G), blk, 0, stream>>>(h_hi, nullptr, DMODEL,
        e1T, nullptr, DMODEL, eb1 + (size_t)e0*DFFD,
        nullptr, mid, nullptr, DFFD, DMODEL, tokb + e0*CAPMAX, (const __bf16*)zbuf);
    mgemm<4,false><<<dim3(8,8,4*G), blk, 0, stream>>>(mid, nullptr, DFFD,
        e2T, nullptr, DFFD, nullptr,
        yk, nullptr, nullptr, DMODEL, 1024, tokb + e0*CAPMAX, nullptr);
    gather_kernel<<<TOK_N, blk, 0, stream>>>(yk, tsrc, gselb, eb2, e0, G, out);
  }
}